// Round 1
// baseline (343.692 us; speedup 1.0000x reference)
//
#include <hip/hip_runtime.h>

typedef unsigned short u16;
typedef unsigned int u32;
typedef __attribute__((ext_vector_type(8))) short short8;
typedef __attribute__((ext_vector_type(4))) float f32x4;

#define H_ 16
#define L_ 2048
#define D_ 64
#define HID_ 1024

__device__ __forceinline__ u16 f2bf(float f) {
  union { float f; u32 u; } v; v.f = f;
  u32 r = v.u + 0x7FFFu + ((v.u >> 16) & 1u);
  return (u16)(r >> 16);
}

// ---------------- prep kernels ----------------

__global__ __launch_bounds__(256) void cvt_bf16_k(const float* __restrict__ in,
                                                  u16* __restrict__ out, int n) {
  int i = (blockIdx.x * 256 + threadIdx.x) * 8;
  if (i >= n) return;
  float4 a = *(const float4*)(in + i);
  float4 b = *(const float4*)(in + i + 4);
  u16 r[8] = { f2bf(a.x), f2bf(a.y), f2bf(a.z), f2bf(a.w),
               f2bf(b.x), f2bf(b.y), f2bf(b.z), f2bf(b.w) };
  *(uint4*)(out + i) = *(const uint4*)r;
}

// W [K=1024][N=1024] f32 -> Wt [N][K] bf16
__global__ __launch_bounds__(256) void transpose_bf_k(const float* __restrict__ in,
                                                      u16* __restrict__ out) {
  __shared__ float t[32][33];
  int bx = blockIdx.x & 31, by = blockIdx.x >> 5;
  int c = threadIdx.x & 31, r0 = threadIdx.x >> 5;
#pragma unroll
  for (int p = 0; p < 4; ++p) {
    int r = r0 + p * 8;
    t[r][c] = in[(size_t)(by * 32 + r) * 1024 + bx * 32 + c];
  }
  __syncthreads();
#pragma unroll
  for (int p = 0; p < 4; ++p) {
    int r = r0 + p * 8;
    out[(size_t)(bx * 32 + r) * 1024 + by * 32 + c] = f2bf(t[c][r]);
  }
}

// tab[l][i] = (cos, sin)(pos[l] * base^(-2i/64)),  l<2048, i<32
__global__ __launch_bounds__(256) void rope_tab_k(const int* __restrict__ pos,
                                                  float2* __restrict__ tab) {
  int gid = blockIdx.x * 256 + threadIdx.x;
  int l = gid >> 5, i = gid & 31;
  float p = (float)pos[l];
  float inv = expf(-((float)(2 * i) / 64.0f) * logf(10000.0f));
  float th = p * inv;
  tab[gid] = make_float2(cosf(th), sinf(th));
}

// ---------------- 128x128 tile GEMM, C = A[M,1024] * W[1024,N] via Wt[N][K] ----------------
// EPI: 0 = Q (rope + 1/8 scale -> [bh][l][d] bf16), 1 = K (rope -> [bh][l][d] bf16),
//      2 = V (-> [bh][d][l] bf16), 3 = out proj (fp32 row-major)

template<int EPI>
__global__ __launch_bounds__(256) void gemm_epi_k(
    const u16* __restrict__ A, const u16* __restrict__ Bt,
    void* __restrict__ Out, const float2* __restrict__ rope)
{
  const int K = 1024;
  __shared__ alignas(16) u16 As[128][32];
  __shared__ alignas(16) u16 Bs[128][32];
  int tid = threadIdx.x;
  int bid = blockIdx.x;
  int tm = bid >> 3, tn = bid & 7;      // grid = (M/128)*8
  int m0 = tm * 128, n0 = tn * 128;
  int lrow = tid >> 2, lk = (tid & 3) * 8;
  const uint4* gA0 = (const uint4*)(A + (size_t)(m0 + lrow) * K + lk);
  const uint4* gA1 = (const uint4*)(A + (size_t)(m0 + lrow + 64) * K + lk);
  const uint4* gB0 = (const uint4*)(Bt + (size_t)(n0 + lrow) * K + lk);
  const uint4* gB1 = (const uint4*)(Bt + (size_t)(n0 + lrow + 64) * K + lk);
  int wid = tid >> 6, lane = tid & 63, ln = lane & 15, kg = lane >> 4;
  int wm = (wid >> 1) * 64, wn = (wid & 1) * 64;
  f32x4 acc[4][4] = {};
  uint4 ra0 = *gA0, ra1 = *gA1, rb0 = *gB0, rb1 = *gB1;
  for (int kt = 0; kt < 32; ++kt) {
    __syncthreads();
    *(uint4*)&As[lrow][lk] = ra0;
    *(uint4*)&As[lrow + 64][lk] = ra1;
    *(uint4*)&Bs[lrow][lk] = rb0;
    *(uint4*)&Bs[lrow + 64][lk] = rb1;
    __syncthreads();
    if (kt < 31) {
      gA0 += 4; gA1 += 4; gB0 += 4; gB1 += 4;
      ra0 = *gA0; ra1 = *gA1; rb0 = *gB0; rb1 = *gB1;
    }
    short8 af[4], bfr[4];
#pragma unroll
    for (int i = 0; i < 4; ++i) af[i] = *(const short8*)&As[wm + i * 16 + ln][kg * 8];
#pragma unroll
    for (int i = 0; i < 4; ++i) bfr[i] = *(const short8*)&Bs[wn + i * 16 + ln][kg * 8];
#pragma unroll
    for (int mi = 0; mi < 4; ++mi)
#pragma unroll
      for (int ni = 0; ni < 4; ++ni)
        acc[mi][ni] = __builtin_amdgcn_mfma_f32_16x16x32_bf16(af[mi], bfr[ni], acc[mi][ni], 0, 0, 0);
  }

  if (EPI == 0 || EPI == 1) {
    int h = (n0 + wn) >> 6;             // wave covers exactly one 64-col head
    u16* Qo = (u16*)Out;
#pragma unroll
    for (int mi = 0; mi < 4; ++mi) {
#pragma unroll
      for (int j = 0; j < 4; ++j) {
        int m = m0 + wm + mi * 16 + kg * 4 + j;
        int l = m & (L_ - 1), b = m >> 11;
        const float2* tl = rope + l * 32;
#pragma unroll
        for (int ni = 0; ni < 2; ++ni) {
          int dA = ni * 16 + ln;        // dA < 32, pairs with dA+32 (acc ni <-> ni+2)
          float xa = acc[mi][ni][j], xb = acc[mi][ni + 2][j];
          float2 fA = tl[dA >> 1];
          float2 fB = tl[16 + (dA >> 1)];
          float oA = fA.x * xa - fA.y * xb;
          float oB = fB.x * xb + fB.y * xa;
          if (EPI == 0) { oA *= 0.125f; oB *= 0.125f; }   // fold 1/sqrt(D) into Q
          size_t base = ((size_t)(b * H_ + h) * L_ + l) * D_;
          Qo[base + dA] = f2bf(oA);
          Qo[base + dA + 32] = f2bf(oB);
        }
      }
    }
  } else if (EPI == 2) {
    int h = (n0 + wn) >> 6;
    u16* Vo = (u16*)Out;
#pragma unroll
    for (int mi = 0; mi < 4; ++mi)
#pragma unroll
      for (int j = 0; j < 4; ++j) {
        int m = m0 + wm + mi * 16 + kg * 4 + j;
        int l = m & (L_ - 1), b = m >> 11;
#pragma unroll
        for (int ni = 0; ni < 4; ++ni) {
          int d = ni * 16 + ln;
          Vo[((size_t)(b * H_ + h) * D_ + d) * L_ + l] = f2bf(acc[mi][ni][j]);
        }
      }
  } else {
    float* Oo = (float*)Out;
#pragma unroll
    for (int mi = 0; mi < 4; ++mi)
#pragma unroll
      for (int j = 0; j < 4; ++j) {
        int m = m0 + wm + mi * 16 + kg * 4 + j;
#pragma unroll
        for (int ni = 0; ni < 4; ++ni)
          Oo[(size_t)m * 1024 + n0 + wn + ni * 16 + ln] = acc[mi][ni][j];
      }
  }
}

// ---------------- flash attention ----------------
// grid (L/64, B*H), 4 waves/block, 16 q-rows per wave, 32-wide KV chunks.
__global__ __launch_bounds__(256) void attn_k(
    const u16* __restrict__ Q, const u16* __restrict__ K,
    const u16* __restrict__ V, u16* __restrict__ AO)
{
  __shared__ alignas(16) u16 P_s[4][16][32];   // per-wave P tile
  int tid = threadIdx.x;
  int wid = tid >> 6, lane = tid & 63, ln = lane & 15, kg = lane >> 4;
  int bh = blockIdx.y;
  int qt = blockIdx.x * 64 + wid * 16;
  const u16* Qh = Q + (size_t)bh * L_ * D_;
  const u16* Kh = K + (size_t)bh * L_ * D_;
  const u16* Vh = V + (size_t)bh * D_ * L_;
  short8 qf[2];
#pragma unroll
  for (int kc = 0; kc < 2; ++kc)
    qf[kc] = *(const short8*)(Qh + (size_t)(qt + ln) * D_ + kc * 32 + kg * 8);
  f32x4 o[4] = {};
  float mrun[4], lrun[4];
#pragma unroll
  for (int j = 0; j < 4; ++j) { mrun[j] = -1e30f; lrun[j] = 0.f; }

  for (int kv0 = 0; kv0 <= qt + 15; kv0 += 32) {
    f32x4 s[2] = {};
#pragma unroll
    for (int nt = 0; nt < 2; ++nt) {
      short8 kf0 = *(const short8*)(Kh + (size_t)(kv0 + nt * 16 + ln) * D_ + kg * 8);
      short8 kf1 = *(const short8*)(Kh + (size_t)(kv0 + nt * 16 + ln) * D_ + 32 + kg * 8);
      s[nt] = __builtin_amdgcn_mfma_f32_16x16x32_bf16(qf[0], kf0, s[nt], 0, 0, 0);
      s[nt] = __builtin_amdgcn_mfma_f32_16x16x32_bf16(qf[1], kf1, s[nt], 0, 0, 0);
    }
    // causal mask: C layout col = kv (lane&15), rows = kg*4+j
#pragma unroll
    for (int nt = 0; nt < 2; ++nt) {
      int kv = kv0 + nt * 16 + ln;
#pragma unroll
      for (int j = 0; j < 4; ++j) {
        int q = qt + kg * 4 + j;
        if (kv > q) s[nt][j] = -1e30f;
      }
    }
    // online softmax (16-lane groups hold one row set)
#pragma unroll
    for (int j = 0; j < 4; ++j) {
      float mx = fmaxf(s[0][j], s[1][j]);
#pragma unroll
      for (int off = 1; off < 16; off <<= 1) mx = fmaxf(mx, __shfl_xor(mx, off));
      float mnew = fmaxf(mrun[j], mx);
      float al = __expf(mrun[j] - mnew);
      mrun[j] = mnew;
      float p0 = __expf(s[0][j] - mnew);
      float p1 = __expf(s[1][j] - mnew);
      float sm = p0 + p1;
#pragma unroll
      for (int off = 1; off < 16; off <<= 1) sm += __shfl_xor(sm, off);
      lrun[j] = lrun[j] * al + sm;
      P_s[wid][kg * 4 + j][ln] = f2bf(p0);
      P_s[wid][kg * 4 + j][16 + ln] = f2bf(p1);
#pragma unroll
      for (int dt = 0; dt < 4; ++dt) o[dt][j] *= al;
    }
    asm volatile("s_waitcnt lgkmcnt(0)" ::: "memory");
    short8 pf = *(const short8*)&P_s[wid][ln][kg * 8];
#pragma unroll
    for (int dt = 0; dt < 4; ++dt) {
      short8 vf = *(const short8*)(Vh + (size_t)(dt * 16 + ln) * L_ + kv0 + kg * 8);
      o[dt] = __builtin_amdgcn_mfma_f32_16x16x32_bf16(pf, vf, o[dt], 0, 0, 0);
    }
  }
  int b = bh >> 4, h = bh & 15;
#pragma unroll
  for (int j = 0; j < 4; ++j) {
    float inv = 1.0f / lrun[j];
    int lq = qt + kg * 4 + j;
    size_t base = ((size_t)(b * L_ + lq) * H_ + h) * D_;
#pragma unroll
    for (int dt = 0; dt < 4; ++dt)
      AO[base + dt * 16 + ln] = f2bf(o[dt][j] * inv);
  }
}

// ---------------- launch ----------------

extern "C" void kernel_launch(void* const* d_in, const int* in_sizes, int n_in,
                              void* d_out, int out_size, void* d_ws, size_t ws_size,
                              hipStream_t stream) {
  (void)in_sizes; (void)n_in; (void)out_size; (void)ws_size;
  const float* x   = (const float*)d_in[0];
  const int*   pos = (const int*)d_in[1];
  // d_in[2] = additive causal mask (we apply causal masking directly)
  const float* Wq  = (const float*)d_in[3];
  const float* Wk  = (const float*)d_in[4];
  const float* Wv  = (const float*)d_in[5];
  const float* Wo  = (const float*)d_in[6];

  char* ws = (char*)d_ws;
  u16* xbf = (u16*)ws;                        // 8 MB
  u16* Wtq = (u16*)(ws + (size_t)( 8 << 20)); // 2 MB each
  u16* Wtk = (u16*)(ws + (size_t)(10 << 20));
  u16* Wtv = (u16*)(ws + (size_t)(12 << 20));
  u16* Wto = (u16*)(ws + (size_t)(14 << 20));
  u16* Qb  = (u16*)(ws + (size_t)(16 << 20)); // 8 MB each
  u16* Kb  = (u16*)(ws + (size_t)(24 << 20));
  u16* Vt  = (u16*)(ws + (size_t)(32 << 20));
  u16* AO  = (u16*)(ws + (size_t)(40 << 20));
  float2* tab = (float2*)(ws + (size_t)(48 << 20)); // 512 KB

  cvt_bf16_k<<<2048, 256, 0, stream>>>(x, xbf, 4096 * 1024);
  transpose_bf_k<<<1024, 256, 0, stream>>>(Wq, Wtq);
  transpose_bf_k<<<1024, 256, 0, stream>>>(Wk, Wtk);
  transpose_bf_k<<<1024, 256, 0, stream>>>(Wv, Wtv);
  transpose_bf_k<<<1024, 256, 0, stream>>>(Wo, Wto);
  rope_tab_k<<<256, 256, 0, stream>>>(pos, tab);
  gemm_epi_k<0><<<256, 256, 0, stream>>>(xbf, Wtq, (void*)Qb, tab);
  gemm_epi_k<1><<<256, 256, 0, stream>>>(xbf, Wtk, (void*)Kb, tab);
  gemm_epi_k<2><<<256, 256, 0, stream>>>(xbf, Wtv, (void*)Vt, tab);
  attn_k<<<dim3(32, 32), 256, 0, stream>>>(Qb, Kb, Vt, AO);
  gemm_epi_k<3><<<256, 256, 0, stream>>>(AO, Wto, d_out, tab);
}

// Round 4
// 265.162 us; speedup vs baseline: 1.2962x; 1.2962x over previous
//
#include <hip/hip_runtime.h>

typedef unsigned short u16;
typedef unsigned int u32;
typedef __attribute__((ext_vector_type(8))) short short8;
typedef __attribute__((ext_vector_type(4))) float f32x4;

#define H_ 16
#define L_ 2048
#define D_ 64
#define HID_ 1024

__device__ __forceinline__ u16 f2bf(float f) {
  union { float f; u32 u; } v; v.f = f;
  u32 r = v.u + 0x7FFFu + ((v.u >> 16) & 1u);
  return (u16)(r >> 16);
}

// ---------------- prep kernels ----------------

__global__ __launch_bounds__(256) void cvt_bf16_k(const float* __restrict__ in,
                                                  u16* __restrict__ out, int n) {
  int i = (blockIdx.x * 256 + threadIdx.x) * 8;
  if (i >= n) return;
  float4 a = *(const float4*)(in + i);
  float4 b = *(const float4*)(in + i + 4);
  u16 r[8] = { f2bf(a.x), f2bf(a.y), f2bf(a.z), f2bf(a.w),
               f2bf(b.x), f2bf(b.y), f2bf(b.z), f2bf(b.w) };
  *(uint4*)(out + i) = *(const uint4*)r;
}

// W [K=1024][N=1024] f32 -> Wt [N][K] bf16
__global__ __launch_bounds__(256) void transpose_bf_k(const float* __restrict__ in,
                                                      u16* __restrict__ out) {
  __shared__ float t[32][33];
  int bx = blockIdx.x & 31, by = blockIdx.x >> 5;
  int c = threadIdx.x & 31, r0 = threadIdx.x >> 5;
#pragma unroll
  for (int p = 0; p < 4; ++p) {
    int r = r0 + p * 8;
    t[r][c] = in[(size_t)(by * 32 + r) * 1024 + bx * 32 + c];
  }
  __syncthreads();
#pragma unroll
  for (int p = 0; p < 4; ++p) {
    int r = r0 + p * 8;
    out[(size_t)(bx * 32 + r) * 1024 + by * 32 + c] = f2bf(t[c][r]);
  }
}

// tab[l][i] = (cos, sin)(pos[l] * base^(-2i/64)),  l<2048, i<32
__global__ __launch_bounds__(256) void rope_tab_k(const int* __restrict__ pos,
                                                  float2* __restrict__ tab) {
  int gid = blockIdx.x * 256 + threadIdx.x;
  int l = gid >> 5, i = gid & 31;
  float p = (float)pos[l];
  float inv = expf(-((float)(2 * i) / 64.0f) * logf(10000.0f));
  float th = p * inv;
  tab[gid] = make_float2(cosf(th), sinf(th));
}

// ---------------- 128x128 tile GEMM, C = A[M,1024] * W[1024,N] via Wt[N][K] ----------------
// EPI: 0 = Q (rope + 1/8 scale -> [bh][l][d] bf16), 1 = K (rope -> [bh][l][d] bf16),
//      2 = V (-> [bh][d][l] bf16), 3 = out proj (fp32 row-major)

template<int EPI>
__global__ __launch_bounds__(256) void gemm_epi_k(
    const u16* __restrict__ A, const u16* __restrict__ Bt,
    void* __restrict__ Out, const float2* __restrict__ rope)
{
  const int K = 1024;
  __shared__ alignas(16) u16 As[128][32];
  __shared__ alignas(16) u16 Bs[128][32];
  int tid = threadIdx.x;
  int bid = blockIdx.x;
  int tm = bid >> 3, tn = bid & 7;      // grid = (M/128)*8
  int m0 = tm * 128, n0 = tn * 128;
  int lrow = tid >> 2, lk = (tid & 3) * 8;
  const uint4* gA0 = (const uint4*)(A + (size_t)(m0 + lrow) * K + lk);
  const uint4* gA1 = (const uint4*)(A + (size_t)(m0 + lrow + 64) * K + lk);
  const uint4* gB0 = (const uint4*)(Bt + (size_t)(n0 + lrow) * K + lk);
  const uint4* gB1 = (const uint4*)(Bt + (size_t)(n0 + lrow + 64) * K + lk);
  int wid = tid >> 6, lane = tid & 63, ln = lane & 15, kg = lane >> 4;
  int wm = (wid >> 1) * 64, wn = (wid & 1) * 64;
  f32x4 acc[4][4] = {};
  uint4 ra0 = *gA0, ra1 = *gA1, rb0 = *gB0, rb1 = *gB1;
  for (int kt = 0; kt < 32; ++kt) {
    __syncthreads();
    *(uint4*)&As[lrow][lk] = ra0;
    *(uint4*)&As[lrow + 64][lk] = ra1;
    *(uint4*)&Bs[lrow][lk] = rb0;
    *(uint4*)&Bs[lrow + 64][lk] = rb1;
    __syncthreads();
    if (kt < 31) {
      gA0 += 4; gA1 += 4; gB0 += 4; gB1 += 4;
      ra0 = *gA0; ra1 = *gA1; rb0 = *gB0; rb1 = *gB1;
    }
    short8 af[4], bfr[4];
#pragma unroll
    for (int i = 0; i < 4; ++i) af[i] = *(const short8*)&As[wm + i * 16 + ln][kg * 8];
#pragma unroll
    for (int i = 0; i < 4; ++i) bfr[i] = *(const short8*)&Bs[wn + i * 16 + ln][kg * 8];
#pragma unroll
    for (int mi = 0; mi < 4; ++mi)
#pragma unroll
      for (int ni = 0; ni < 4; ++ni)
        acc[mi][ni] = __builtin_amdgcn_mfma_f32_16x16x32_bf16(af[mi], bfr[ni], acc[mi][ni], 0, 0, 0);
  }

  if (EPI == 0 || EPI == 1) {
    int h = (n0 + wn) >> 6;             // wave covers exactly one 64-col head
    u16* Qo = (u16*)Out;
#pragma unroll
    for (int mi = 0; mi < 4; ++mi) {
#pragma unroll
      for (int j = 0; j < 4; ++j) {
        int m = m0 + wm + mi * 16 + kg * 4 + j;
        int l = m & (L_ - 1), b = m >> 11;
        const float2* tl = rope + l * 32;
#pragma unroll
        for (int ni = 0; ni < 2; ++ni) {
          int dA = ni * 16 + ln;        // dA < 32, pairs with dA+32 (acc ni <-> ni+2)
          float xa = acc[mi][ni][j], xb = acc[mi][ni + 2][j];
          float2 fA = tl[dA >> 1];
          float2 fB = tl[16 + (dA >> 1)];
          float oA = fA.x * xa - fA.y * xb;
          float oB = fB.x * xb + fB.y * xa;
          if (EPI == 0) { oA *= 0.125f; oB *= 0.125f; }   // fold 1/sqrt(D) into Q
          size_t base = ((size_t)(b * H_ + h) * L_ + l) * D_;
          Qo[base + dA] = f2bf(oA);
          Qo[base + dA + 32] = f2bf(oB);
        }
      }
    }
  } else if (EPI == 2) {
    int h = (n0 + wn) >> 6;
    u16* Vo = (u16*)Out;
#pragma unroll
    for (int mi = 0; mi < 4; ++mi)
#pragma unroll
      for (int j = 0; j < 4; ++j) {
        int m = m0 + wm + mi * 16 + kg * 4 + j;
        int l = m & (L_ - 1), b = m >> 11;
#pragma unroll
        for (int ni = 0; ni < 4; ++ni) {
          int d = ni * 16 + ln;
          Vo[((size_t)(b * H_ + h) * D_ + d) * L_ + l] = f2bf(acc[mi][ni][j]);
        }
      }
  } else {
    float* Oo = (float*)Out;
#pragma unroll
    for (int mi = 0; mi < 4; ++mi)
#pragma unroll
      for (int j = 0; j < 4; ++j) {
        int m = m0 + wm + mi * 16 + kg * 4 + j;
#pragma unroll
        for (int ni = 0; ni < 4; ++ni)
          Oo[(size_t)m * 1024 + n0 + wn + ni * 16 + ln] = acc[mi][ni][j];
      }
  }
}

// ---------------- flash attention v3 (all 16x16x32, round-1-verified layouts) ----------------
// One wave = one 16-row q-strip. Swapped QK^T: S^T tile (16kv x 16q) = mfma(K_frag, Q_frag).
// Lane (ln = lane&15, kg = lane>>4) holds S^T[kv = tile0 + kg*4+r][q = q0+ln] (verified C layout).
// Softmax column spread over 4 lane-groups -> shfl_xor(16)+shfl_xor(32) reductions.
// PV: O^T (16d x 16q) = mfma(V^T_frag, P^T_frag) over K=32 kv.
// P^T B-fragment for lane (ln,kg): kv rows 8kg..8kg+7 gathered from lanes kg'=(2kg)&3,(2kg+1)&3,
// tile t'=kg>>1, via 8 __shfl + 4 selects. No LDS, no barriers.
__global__ __launch_bounds__(256) void attn_k(
    const u16* __restrict__ Q, const u16* __restrict__ K,
    const u16* __restrict__ V, u16* __restrict__ AO)
{
  int tid = threadIdx.x;
  int wid = tid >> 6, lane = tid & 63;
  int ln = lane & 15, kg = lane >> 4;
  int bh = blockIdx.y;
  int strip = wid * 32 + blockIdx.x;   // 0..127, balanced causal load across blocks
  int q0 = strip * 16;
  const u16* Qh = Q + (size_t)bh * L_ * D_;
  const u16* Kh = K + (size_t)bh * L_ * D_;
  const u16* Vh = V + (size_t)bh * D_ * L_;

  short8 qf[2];
#pragma unroll
  for (int dh = 0; dh < 2; ++dh)
    qf[dh] = *(const short8*)(Qh + (size_t)(q0 + ln) * D_ + dh * 32 + kg * 8);

  f32x4 o[4] = {};
  float m = -1e30f, l = 0.f;
  int srcA = ln + (((2 * kg) & 3) << 4);
  int srcB = ln + (((2 * kg + 1) & 3) << 4);
  bool thi = (kg >= 2);   // need tile-1 words of source lanes

  // mode: 0 = both tiles full, 1 = tile0 full + tile1 diag, 2 = tile0 diag + tile1 skip
  auto chunk = [&](int kv0, int mode) {
    f32x4 s0 = {}, s1 = {};
#pragma unroll
    for (int dh = 0; dh < 2; ++dh) {
      short8 kf = *(const short8*)(Kh + (size_t)(kv0 + ln) * D_ + dh * 32 + kg * 8);
      s0 = __builtin_amdgcn_mfma_f32_16x16x32_bf16(kf, qf[dh], s0, 0, 0, 0);
    }
    if (mode != 2) {
#pragma unroll
      for (int dh = 0; dh < 2; ++dh) {
        short8 kf = *(const short8*)(Kh + (size_t)(kv0 + 16 + ln) * D_ + dh * 32 + kg * 8);
        s1 = __builtin_amdgcn_mfma_f32_16x16x32_bf16(kf, qf[dh], s1, 0, 0, 0);
      }
    } else {
      s1[0] = s1[1] = s1[2] = s1[3] = -1e30f;   // p -> 0 for unused half-chunk
    }
    // prefetch V fragments (independent of softmax)
    short8 vf[4];
#pragma unroll
    for (int dt = 0; dt < 4; ++dt)
      vf[dt] = *(const short8*)(Vh + (size_t)(dt * 16 + ln) * L_ + kv0 + kg * 8);
    // causal mask on diag tile: kv_local = kg*4+r vs q_local = ln
    if (mode == 2) {
#pragma unroll
      for (int r = 0; r < 4; ++r) if (kg * 4 + r > ln) s0[r] = -1e30f;
    } else if (mode == 1) {
#pragma unroll
      for (int r = 0; r < 4; ++r) if (kg * 4 + r > ln) s1[r] = -1e30f;
    }
    // online softmax (column spread over 4 lane-groups)
    float cmax = fmaxf(fmaxf(fmaxf(s0[0], s0[1]), fmaxf(s0[2], s0[3])),
                       fmaxf(fmaxf(s1[0], s1[1]), fmaxf(s1[2], s1[3])));
    cmax = fmaxf(cmax, __shfl_xor(cmax, 16));
    cmax = fmaxf(cmax, __shfl_xor(cmax, 32));
    float mnew = fmaxf(m, cmax);
    float al = __expf(m - mnew);
    m = mnew;
    float p0[4], p1[4];
    float psum = 0.f;
#pragma unroll
    for (int r = 0; r < 4; ++r) {
      p0[r] = __expf(s0[r] - mnew);
      p1[r] = __expf(s1[r] - mnew);
      psum += p0[r] + p1[r];
    }
    psum += __shfl_xor(psum, 16);
    psum += __shfl_xor(psum, 32);
    l = l * al + psum;
#pragma unroll
    for (int dt = 0; dt < 4; ++dt) o[dt] *= al;
    // pack own p (verified f2bf), gather P^T fragment
    u32 wA0 = (u32)f2bf(p0[0]) | ((u32)f2bf(p0[1]) << 16);
    u32 wB0 = (u32)f2bf(p0[2]) | ((u32)f2bf(p0[3]) << 16);
    u32 wA1 = (u32)f2bf(p1[0]) | ((u32)f2bf(p1[1]) << 16);
    u32 wB1 = (u32)f2bf(p1[2]) | ((u32)f2bf(p1[3]) << 16);
    u32 a0 = __shfl((int)wA0, srcA), a1 = __shfl((int)wA1, srcA);
    u32 b0 = __shfl((int)wB0, srcA), b1 = __shfl((int)wB1, srcA);
    u32 c0 = __shfl((int)wA0, srcB), c1 = __shfl((int)wA1, srcB);
    u32 e0 = __shfl((int)wB0, srcB), e1 = __shfl((int)wB1, srcB);
    union { u32 u[4]; short8 s8; } pu;
    pu.u[0] = thi ? a1 : a0;   // kv 8kg+0,1
    pu.u[1] = thi ? b1 : b0;   // kv 8kg+2,3
    pu.u[2] = thi ? c1 : c0;   // kv 8kg+4,5
    pu.u[3] = thi ? e1 : e0;   // kv 8kg+6,7
#pragma unroll
    for (int dt = 0; dt < 4; ++dt)
      o[dt] = __builtin_amdgcn_mfma_f32_16x16x32_bf16(vf[dt], pu.s8, o[dt], 0, 0, 0);
  };

  int kv0 = 0;
  for (; kv0 + 32 <= q0; kv0 += 32) chunk(kv0, 0);
  chunk(kv0, (q0 - kv0 == 16) ? 1 : 2);

  // ---- epilogue: O^T[d][q] -> AO[b][q][h][d], d = dt*16 + kg*4 + r ----
  float inv = 1.0f / l;
  int q = q0 + ln;
  int b = bh >> 4, h = bh & 15;
  u16* row = AO + ((size_t)(b * L_ + q) * H_ + h) * D_;
#pragma unroll
  for (int dt = 0; dt < 4; ++dt) {
    union { u16 pk[4]; uint2 v; } u;
#pragma unroll
    for (int r = 0; r < 4; ++r) u.pk[r] = f2bf(o[dt][r] * inv);
    *(uint2*)(row + dt * 16 + kg * 4) = u.v;
  }
}

// ---------------- launch ----------------

extern "C" void kernel_launch(void* const* d_in, const int* in_sizes, int n_in,
                              void* d_out, int out_size, void* d_ws, size_t ws_size,
                              hipStream_t stream) {
  (void)in_sizes; (void)n_in; (void)out_size; (void)ws_size;
  const float* x   = (const float*)d_in[0];
  const int*   pos = (const int*)d_in[1];
  // d_in[2] = additive causal mask (we apply causal masking directly)
  const float* Wq  = (const float*)d_in[3];
  const float* Wk  = (const float*)d_in[4];
  const float* Wv  = (const float*)d_in[5];
  const float* Wo  = (const float*)d_in[6];

  char* ws = (char*)d_ws;
  u16* xbf = (u16*)ws;                        // 8 MB
  u16* Wtq = (u16*)(ws + (size_t)( 8 << 20)); // 2 MB each
  u16* Wtk = (u16*)(ws + (size_t)(10 << 20));
  u16* Wtv = (u16*)(ws + (size_t)(12 << 20));
  u16* Wto = (u16*)(ws + (size_t)(14 << 20));
  u16* Qb  = (u16*)(ws + (size_t)(16 << 20)); // 8 MB each
  u16* Kb  = (u16*)(ws + (size_t)(24 << 20));
  u16* Vt  = (u16*)(ws + (size_t)(32 << 20));
  u16* AO  = (u16*)(ws + (size_t)(40 << 20));
  float2* tab = (float2*)(ws + (size_t)(48 << 20)); // 512 KB

  cvt_bf16_k<<<2048, 256, 0, stream>>>(x, xbf, 4096 * 1024);
  transpose_bf_k<<<1024, 256, 0, stream>>>(Wq, Wtq);
  transpose_bf_k<<<1024, 256, 0, stream>>>(Wk, Wtk);
  transpose_bf_k<<<1024, 256, 0, stream>>>(Wv, Wtv);
  transpose_bf_k<<<1024, 256, 0, stream>>>(Wo, Wto);
  rope_tab_k<<<256, 256, 0, stream>>>(pos, tab);
  gemm_epi_k<0><<<256, 256, 0, stream>>>(xbf, Wtq, (void*)Qb, tab);
  gemm_epi_k<1><<<256, 256, 0, stream>>>(xbf, Wtk, (void*)Kb, tab);
  gemm_epi_k<2><<<256, 256, 0, stream>>>(xbf, Wtv, (void*)Vt, tab);
  attn_k<<<dim3(32, 32), 256, 0, stream>>>(Qb, Kb, Vt, AO);
  gemm_epi_k<3><<<256, 256, 0, stream>>>(AO, Wto, d_out, tab);
}

// Round 5
// 263.020 us; speedup vs baseline: 1.3067x; 1.0081x over previous
//
#include <hip/hip_runtime.h>

typedef unsigned short u16;
typedef unsigned int u32;
typedef __attribute__((ext_vector_type(8))) short short8;
typedef __attribute__((ext_vector_type(4))) float f32x4;

#define H_ 16
#define L_ 2048
#define D_ 64
#define HID_ 1024

__device__ __forceinline__ u16 f2bf(float f) {
  union { float f; u32 u; } v; v.f = f;
  u32 r = v.u + 0x7FFFu + ((v.u >> 16) & 1u);
  return (u16)(r >> 16);
}

// async global->LDS, 16B per lane (guide m97/m193 pattern)
__device__ __forceinline__ void gl16(const u16* g, u16* l) {
  __builtin_amdgcn_global_load_lds(
      (const __attribute__((address_space(1))) void*)g,
      (__attribute__((address_space(3))) void*)l, 16, 0, 0);
}

// ---------------- prep kernels ----------------

__global__ __launch_bounds__(256) void cvt_bf16_k(const float* __restrict__ in,
                                                  u16* __restrict__ out, int n) {
  int i = (blockIdx.x * 256 + threadIdx.x) * 8;
  if (i >= n) return;
  float4 a = *(const float4*)(in + i);
  float4 b = *(const float4*)(in + i + 4);
  u16 r[8] = { f2bf(a.x), f2bf(a.y), f2bf(a.z), f2bf(a.w),
               f2bf(b.x), f2bf(b.y), f2bf(b.z), f2bf(b.w) };
  *(uint4*)(out + i) = *(const uint4*)r;
}

// W [K=1024][N=1024] f32 -> Wt [N][K] bf16
__global__ __launch_bounds__(256) void transpose_bf_k(const float* __restrict__ in,
                                                      u16* __restrict__ out) {
  __shared__ float t[32][33];
  int bx = blockIdx.x & 31, by = blockIdx.x >> 5;
  int c = threadIdx.x & 31, r0 = threadIdx.x >> 5;
#pragma unroll
  for (int p = 0; p < 4; ++p) {
    int r = r0 + p * 8;
    t[r][c] = in[(size_t)(by * 32 + r) * 1024 + bx * 32 + c];
  }
  __syncthreads();
#pragma unroll
  for (int p = 0; p < 4; ++p) {
    int r = r0 + p * 8;
    out[(size_t)(bx * 32 + r) * 1024 + by * 32 + c] = f2bf(t[c][r]);
  }
}

// tab[l][i] = (cos, sin)(pos[l] * base^(-2i/64)),  l<2048, i<32
__global__ __launch_bounds__(256) void rope_tab_k(const int* __restrict__ pos,
                                                  float2* __restrict__ tab) {
  int gid = blockIdx.x * 256 + threadIdx.x;
  int l = gid >> 5, i = gid & 31;
  float p = (float)pos[l];
  float inv = expf(-((float)(2 * i) / 64.0f) * logf(10000.0f));
  float th = p * inv;
  tab[gid] = make_float2(cosf(th), sinf(th));
}

// ---------------- 128x128 tile GEMM, C = A[M,1024] * W[1024,N] via Wt[N][K] ----------------
// global_load_lds staging, double-buffered LDS, one barrier per K-step (T3 2-phase).
// EPI: 0 = Q (rope + 1/8 scale -> [bh][l][d] bf16), 1 = K (rope -> [bh][l][d] bf16),
//      2 = V (-> [bh][d][l] bf16), 3 = out proj (fp32 row-major)

template<int EPI>
__global__ __launch_bounds__(256) void gemm_epi_k(
    const u16* __restrict__ A, const u16* __restrict__ Bt,
    void* __restrict__ Out, const float2* __restrict__ rope)
{
  const int K = 1024;
  __shared__ alignas(16) u16 As[2][128][32];   // 16 KB
  __shared__ alignas(16) u16 Bs[2][128][32];   // 16 KB
  int tid = threadIdx.x;
  int bid = blockIdx.x;
  int tm = bid >> 3, tn = bid & 7;      // grid = (M/128)*8
  int m0 = tm * 128, n0 = tn * 128;
  int lrow = tid >> 2, lk = (tid & 3) * 8;
  const u16* gA = A + (size_t)(m0 + lrow) * K + lk;
  const u16* gB = Bt + (size_t)(n0 + lrow) * K + lk;
  int wid = tid >> 6, lane = tid & 63, ln = lane & 15, kg = lane >> 4;
  int wm = (wid >> 1) * 64, wn = (wid & 1) * 64;
  f32x4 acc[4][4] = {};

  auto stage = [&](int buf, int kt) {
    const u16* ga = gA + kt * 32;
    gl16(ga, &As[buf][lrow][lk]);
    gl16(ga + 64 * K, &As[buf][lrow + 64][lk]);
    const u16* gb = gB + kt * 32;
    gl16(gb, &Bs[buf][lrow][lk]);
    gl16(gb + 64 * K, &Bs[buf][lrow + 64][lk]);
  };

  stage(0, 0);
  asm volatile("s_waitcnt vmcnt(0)" ::: "memory");
  __syncthreads();
  int cur = 0;
  for (int kt = 0; kt < 32; ++kt) {
    if (kt < 31) stage(cur ^ 1, kt + 1);
    short8 af[4], bfr[4];
#pragma unroll
    for (int i = 0; i < 4; ++i) af[i] = *(const short8*)&As[cur][wm + i * 16 + ln][kg * 8];
#pragma unroll
    for (int i = 0; i < 4; ++i) bfr[i] = *(const short8*)&Bs[cur][wn + i * 16 + ln][kg * 8];
#pragma unroll
    for (int mi = 0; mi < 4; ++mi)
#pragma unroll
      for (int ni = 0; ni < 4; ++ni)
        acc[mi][ni] = __builtin_amdgcn_mfma_f32_16x16x32_bf16(af[mi], bfr[ni], acc[mi][ni], 0, 0, 0);
    __syncthreads();   // compiler drains vmcnt+lgkmcnt before s_barrier
    cur ^= 1;
  }

  if (EPI == 0 || EPI == 1) {
    int h = (n0 + wn) >> 6;             // wave covers exactly one 64-col head
    u16* Qo = (u16*)Out;
#pragma unroll
    for (int mi = 0; mi < 4; ++mi) {
#pragma unroll
      for (int j = 0; j < 4; ++j) {
        int m = m0 + wm + mi * 16 + kg * 4 + j;
        int l = m & (L_ - 1), b = m >> 11;
        const float2* tl = rope + l * 32;
#pragma unroll
        for (int ni = 0; ni < 2; ++ni) {
          int dA = ni * 16 + ln;        // dA < 32, pairs with dA+32 (acc ni <-> ni+2)
          float xa = acc[mi][ni][j], xb = acc[mi][ni + 2][j];
          float2 fA = tl[dA >> 1];
          float2 fB = tl[16 + (dA >> 1)];
          float oA = fA.x * xa - fA.y * xb;
          float oB = fB.x * xb + fB.y * xa;
          if (EPI == 0) { oA *= 0.125f; oB *= 0.125f; }   // fold 1/sqrt(D) into Q
          size_t base = ((size_t)(b * H_ + h) * L_ + l) * D_;
          Qo[base + dA] = f2bf(oA);
          Qo[base + dA + 32] = f2bf(oB);
        }
      }
    }
  } else if (EPI == 2) {
    int h = (n0 + wn) >> 6;
    u16* Vo = (u16*)Out;
#pragma unroll
    for (int mi = 0; mi < 4; ++mi)
#pragma unroll
      for (int j = 0; j < 4; ++j) {
        int m = m0 + wm + mi * 16 + kg * 4 + j;
        int l = m & (L_ - 1), b = m >> 11;
#pragma unroll
        for (int ni = 0; ni < 4; ++ni) {
          int d = ni * 16 + ln;
          Vo[((size_t)(b * H_ + h) * D_ + d) * L_ + l] = f2bf(acc[mi][ni][j]);
        }
      }
  } else {
    float* Oo = (float*)Out;
#pragma unroll
    for (int mi = 0; mi < 4; ++mi)
#pragma unroll
      for (int j = 0; j < 4; ++j) {
        int m = m0 + wm + mi * 16 + kg * 4 + j;
#pragma unroll
        for (int ni = 0; ni < 4; ++ni)
          Oo[(size_t)m * 1024 + n0 + wn + ni * 16 + ln] = acc[mi][ni][j];
      }
  }
}

// ---------------- flash attention v4 (16x16x32 verified layouts + prefetch pipeline) ----------------
// One wave = one 16-row q-strip. Swapped QK^T; lane-group softmax (2 shfl hops);
// P^T gathered in-register (8 shfl + selects). K(next) issued before QK(cur),
// V(next) issued after PV(cur) -> global latency hidden under compute.
// Strip map balances trip counts per-SIMD and per-CU.
__global__ __launch_bounds__(256) void attn_k(
    const u16* __restrict__ Q, const u16* __restrict__ K,
    const u16* __restrict__ V, u16* __restrict__ AO)
{
  int tid = threadIdx.x;
  int wid = tid >> 6, lane = tid & 63;
  int ln = lane & 15, kg = lane >> 4;
  int bx = blockIdx.x, by = blockIdx.y;
  int bh = by;
  int strip = ((wid + (by >> 3)) & 3) * 32 + ((bx ^ by) & 31);  // 0..127
  int q0 = strip * 16;
  const u16* Qh = Q + (size_t)bh * L_ * D_;
  const u16* Kh = K + (size_t)bh * L_ * D_;
  const u16* Vh = V + (size_t)bh * D_ * L_;

  short8 qf0 = *(const short8*)(Qh + (size_t)(q0 + ln) * D_ + kg * 8);
  short8 qf1 = *(const short8*)(Qh + (size_t)(q0 + ln) * D_ + 32 + kg * 8);

  f32x4 o[4] = {};
  float m = -1e30f, l = 0.f;
  int srcA = ln + (((2 * kg) & 3) << 4);
  int srcB = ln + (((2 * kg + 1) & 3) << 4);
  bool thi = (kg >= 2);   // need tile-1 words of source lanes

  const u16* kp0 = Kh + (size_t)ln * D_ + kg * 8;
  const u16* vp0 = Vh + (size_t)ln * L_ + kg * 8;

  short8 k0a, k0b, k1a, k1b;   // current K chunk (2 tiles x 2 d-halves)
  short8 v0, v1, v2, v3;       // current V chunk
  short8 nk0a, nk0b, nk1a, nk1b;

#define LOADK_INTO(kv, a, b, c, d)                          \
  { const u16* kp = kp0 + (size_t)(kv) * D_;                \
    a = *(const short8*)(kp);                               \
    b = *(const short8*)(kp + 32);                          \
    c = *(const short8*)(kp + 16 * D_);                     \
    d = *(const short8*)(kp + 16 * D_ + 32); }
#define LOADV_CUR(kv)                                       \
  { const u16* vp = vp0 + (kv);                             \
    v0 = *(const short8*)(vp);                              \
    v1 = *(const short8*)(vp + 16 * L_);                    \
    v2 = *(const short8*)(vp + 32 * L_);                    \
    v3 = *(const short8*)(vp + 48 * L_); }

  // softmax + PV on s0/s1 (math identical to round-4 verified kernel)
  auto soft_pv = [&](f32x4 s0, f32x4 s1) {
    float cmax = fmaxf(fmaxf(fmaxf(s0[0], s0[1]), fmaxf(s0[2], s0[3])),
                       fmaxf(fmaxf(s1[0], s1[1]), fmaxf(s1[2], s1[3])));
    cmax = fmaxf(cmax, __shfl_xor(cmax, 16));
    cmax = fmaxf(cmax, __shfl_xor(cmax, 32));
    float mnew = fmaxf(m, cmax);
    float al = __expf(m - mnew);
    m = mnew;
    float p0[4], p1[4];
    float psum = 0.f;
#pragma unroll
    for (int r = 0; r < 4; ++r) {
      p0[r] = __expf(s0[r] - mnew);
      p1[r] = __expf(s1[r] - mnew);
      psum += p0[r] + p1[r];
    }
    psum += __shfl_xor(psum, 16);
    psum += __shfl_xor(psum, 32);
    l = l * al + psum;
#pragma unroll
    for (int dt = 0; dt < 4; ++dt) o[dt] *= al;
    u32 wA0 = (u32)f2bf(p0[0]) | ((u32)f2bf(p0[1]) << 16);
    u32 wB0 = (u32)f2bf(p0[2]) | ((u32)f2bf(p0[3]) << 16);
    u32 wA1 = (u32)f2bf(p1[0]) | ((u32)f2bf(p1[1]) << 16);
    u32 wB1 = (u32)f2bf(p1[2]) | ((u32)f2bf(p1[3]) << 16);
    u32 a0 = __shfl((int)wA0, srcA), a1 = __shfl((int)wA1, srcA);
    u32 b0 = __shfl((int)wB0, srcA), b1 = __shfl((int)wB1, srcA);
    u32 c0 = __shfl((int)wA0, srcB), c1 = __shfl((int)wA1, srcB);
    u32 e0 = __shfl((int)wB0, srcB), e1 = __shfl((int)wB1, srcB);
    union { u32 u[4]; short8 s8; } pu;
    pu.u[0] = thi ? a1 : a0;   // kv 8kg+0,1
    pu.u[1] = thi ? b1 : b0;   // kv 8kg+2,3
    pu.u[2] = thi ? c1 : c0;   // kv 8kg+4,5
    pu.u[3] = thi ? e1 : e0;   // kv 8kg+6,7
    o[0] = __builtin_amdgcn_mfma_f32_16x16x32_bf16(v0, pu.s8, o[0], 0, 0, 0);
    o[1] = __builtin_amdgcn_mfma_f32_16x16x32_bf16(v1, pu.s8, o[1], 0, 0, 0);
    o[2] = __builtin_amdgcn_mfma_f32_16x16x32_bf16(v2, pu.s8, o[2], 0, 0, 0);
    o[3] = __builtin_amdgcn_mfma_f32_16x16x32_bf16(v3, pu.s8, o[3], 0, 0, 0);
  };

  LOADK_INTO(0, k0a, k0b, k1a, k1b);
  LOADV_CUR(0);

  int kv0 = 0;
  for (; kv0 + 32 <= q0; kv0 += 32) {
    // issue next-chunk K loads first (hidden under this chunk's compute)
    LOADK_INTO(kv0 + 32, nk0a, nk0b, nk1a, nk1b);
    f32x4 s0 = {}, s1 = {};
    s0 = __builtin_amdgcn_mfma_f32_16x16x32_bf16(k0a, qf0, s0, 0, 0, 0);
    s0 = __builtin_amdgcn_mfma_f32_16x16x32_bf16(k0b, qf1, s0, 0, 0, 0);
    s1 = __builtin_amdgcn_mfma_f32_16x16x32_bf16(k1a, qf0, s1, 0, 0, 0);
    s1 = __builtin_amdgcn_mfma_f32_16x16x32_bf16(k1b, qf1, s1, 0, 0, 0);
    soft_pv(s0, s1);
    k0a = nk0a; k0b = nk0b; k1a = nk1a; k1b = nk1b;
    LOADV_CUR(kv0 + 32);   // V for next chunk, consumed after next softmax
  }

  // tail: regs hold chunk at kv0. mode 1 (q0-kv0==16): tile0 full, tile1 diag.
  //       mode 2 (q0==kv0): tile0 diag, tile1 dead.
  {
    f32x4 s0 = {}, s1 = {};
    s0 = __builtin_amdgcn_mfma_f32_16x16x32_bf16(k0a, qf0, s0, 0, 0, 0);
    s0 = __builtin_amdgcn_mfma_f32_16x16x32_bf16(k0b, qf1, s0, 0, 0, 0);
    s1 = __builtin_amdgcn_mfma_f32_16x16x32_bf16(k1a, qf0, s1, 0, 0, 0);
    s1 = __builtin_amdgcn_mfma_f32_16x16x32_bf16(k1b, qf1, s1, 0, 0, 0);
    if (q0 - kv0 == 16) {
#pragma unroll
      for (int r = 0; r < 4; ++r) if (kg * 4 + r > ln) s1[r] = -1e30f;
    } else {
#pragma unroll
      for (int r = 0; r < 4; ++r) {
        if (kg * 4 + r > ln) s0[r] = -1e30f;
        s1[r] = -1e30f;   // tile1 fully dead (garbage K) -> p=0
      }
    }
    soft_pv(s0, s1);
  }

  // ---- epilogue: O^T[d][q] -> AO[b][q][h][d], d = dt*16 + kg*4 + r ----
  float inv = 1.0f / l;
  int q = q0 + ln;
  int b = bh >> 4, h = bh & 15;
  u16* row = AO + ((size_t)(b * L_ + q) * H_ + h) * D_;
#pragma unroll
  for (int dt = 0; dt < 4; ++dt) {
    union { u16 pk[4]; uint2 v; } u;
#pragma unroll
    for (int r = 0; r < 4; ++r) u.pk[r] = f2bf(o[dt][r] * inv);
    *(uint2*)(row + dt * 16 + kg * 4) = u.v;
  }
#undef LOADK_INTO
#undef LOADV_CUR
}

// ---------------- launch ----------------

extern "C" void kernel_launch(void* const* d_in, const int* in_sizes, int n_in,
                              void* d_out, int out_size, void* d_ws, size_t ws_size,
                              hipStream_t stream) {
  (void)in_sizes; (void)n_in; (void)out_size; (void)ws_size;
  const float* x   = (const float*)d_in[0];
  const int*   pos = (const int*)d_in[1];
  // d_in[2] = additive causal mask (we apply causal masking directly)
  const float* Wq  = (const float*)d_in[3];
  const float* Wk  = (const float*)d_in[4];
  const float* Wv  = (const float*)d_in[5];
  const float* Wo  = (const float*)d_in[6];

  char* ws = (char*)d_ws;
  u16* xbf = (u16*)ws;                        // 8 MB
  u16* Wtq = (u16*)(ws + (size_t)( 8 << 20)); // 2 MB each
  u16* Wtk = (u16*)(ws + (size_t)(10 << 20));
  u16* Wtv = (u16*)(ws + (size_t)(12 << 20));
  u16* Wto = (u16*)(ws + (size_t)(14 << 20));
  u16* Qb  = (u16*)(ws + (size_t)(16 << 20)); // 8 MB each
  u16* Kb  = (u16*)(ws + (size_t)(24 << 20));
  u16* Vt  = (u16*)(ws + (size_t)(32 << 20));
  u16* AO  = (u16*)(ws + (size_t)(40 << 20));
  float2* tab = (float2*)(ws + (size_t)(48 << 20)); // 512 KB

  cvt_bf16_k<<<2048, 256, 0, stream>>>(x, xbf, 4096 * 1024);
  transpose_bf_k<<<1024, 256, 0, stream>>>(Wq, Wtq);
  transpose_bf_k<<<1024, 256, 0, stream>>>(Wk, Wtk);
  transpose_bf_k<<<1024, 256, 0, stream>>>(Wv, Wtv);
  transpose_bf_k<<<1024, 256, 0, stream>>>(Wo, Wto);
  rope_tab_k<<<256, 256, 0, stream>>>(pos, tab);
  gemm_epi_k<0><<<256, 256, 0, stream>>>(xbf, Wtq, (void*)Qb, tab);
  gemm_epi_k<1><<<256, 256, 0, stream>>>(xbf, Wtk, (void*)Kb, tab);
  gemm_epi_k<2><<<256, 256, 0, stream>>>(xbf, Wtv, (void*)Vt, tab);
  attn_k<<<dim3(32, 32), 256, 0, stream>>>(Qb, Kb, Vt, AO);
  gemm_epi_k<3><<<256, 256, 0, stream>>>(AO, Wto, d_out, tab);
}

// Round 7
// 202.016 us; speedup vs baseline: 1.7013x; 1.3020x over previous
//
#include <hip/hip_runtime.h>

typedef unsigned short u16;
typedef unsigned int u32;
typedef __attribute__((ext_vector_type(8))) short short8;
typedef __attribute__((ext_vector_type(4))) float f32x4;

#define H_ 16
#define L_ 2048
#define D_ 64
#define HID_ 1024

__device__ __forceinline__ u16 f2bf(float f) {
  union { float f; u32 u; } v; v.f = f;
  u32 r = v.u + 0x7FFFu + ((v.u >> 16) & 1u);
  return (u16)(r >> 16);
}

// async global->LDS, 16B per lane
__device__ __forceinline__ void gl16(const u16* g, u16* l) {
  __builtin_amdgcn_global_load_lds(
      (const __attribute__((address_space(1))) void*)g,
      (__attribute__((address_space(3))) void*)l, 16, 0, 0);
}

// ---------------- prep kernels ----------------

__global__ __launch_bounds__(256) void cvt_bf16_k(const float* __restrict__ in,
                                                  u16* __restrict__ out, int n) {
  int i = (blockIdx.x * 256 + threadIdx.x) * 8;
  if (i >= n) return;
  float4 a = *(const float4*)(in + i);
  float4 b = *(const float4*)(in + i + 4);
  u16 r[8] = { f2bf(a.x), f2bf(a.y), f2bf(a.z), f2bf(a.w),
               f2bf(b.x), f2bf(b.y), f2bf(b.z), f2bf(b.w) };
  *(uint4*)(out + i) = *(const uint4*)r;
}

// W [K=1024][N=1024] f32 -> Wt [N][K] bf16
__global__ __launch_bounds__(256) void transpose_bf_k(const float* __restrict__ in,
                                                      u16* __restrict__ out) {
  __shared__ float t[32][33];
  int bx = blockIdx.x & 31, by = blockIdx.x >> 5;
  int c = threadIdx.x & 31, r0 = threadIdx.x >> 5;
#pragma unroll
  for (int p = 0; p < 4; ++p) {
    int r = r0 + p * 8;
    t[r][c] = in[(size_t)(by * 32 + r) * 1024 + bx * 32 + c];
  }
  __syncthreads();
#pragma unroll
  for (int p = 0; p < 4; ++p) {
    int r = r0 + p * 8;
    out[(size_t)(bx * 32 + r) * 1024 + by * 32 + c] = f2bf(t[c][r]);
  }
}

// tab[l][i] = (cos, sin)(pos[l] * base^(-2i/64)),  l<2048, i<32
__global__ __launch_bounds__(256) void rope_tab_k(const int* __restrict__ pos,
                                                  float2* __restrict__ tab) {
  int gid = blockIdx.x * 256 + threadIdx.x;
  int l = gid >> 5, i = gid & 31;
  float p = (float)pos[l];
  float inv = expf(-((float)(2 * i) / 64.0f) * logf(10000.0f));
  float th = p * inv;
  tab[gid] = make_float2(cosf(th), sinf(th));
}

// ---------------- fused QKV GEMM: C = x[4096,1024] * [Wq|Wk|Wv] (N=3072) ----------------
// 128x128 tiles, grid (24,32) = 768 blocks (3/CU). global_load_lds dbuf staging.
// Epilogue by section: 0 = Q (rope, 1/8 scale), 1 = K (rope), 2 = V (chunk-tiled [l/32][64][32]).

__global__ __launch_bounds__(256) void qkv_gemm_k(
    const u16* __restrict__ A, const u16* __restrict__ Bt,
    u16* __restrict__ Qo, u16* __restrict__ Ko, u16* __restrict__ Vo,
    const float2* __restrict__ rope)
{
  const int K = 1024;
  __shared__ alignas(16) u16 As[2][128][32];
  __shared__ alignas(16) u16 Bs[2][128][32];
  int tid = threadIdx.x;
  int tn = blockIdx.x, tm = blockIdx.y;
  int m0 = tm * 128, n0 = tn * 128;
  int lrow = tid >> 2, lk = (tid & 3) * 8;
  const u16* gA = A + (size_t)(m0 + lrow) * K + lk;
  const u16* gB = Bt + (size_t)(n0 + lrow) * K + lk;
  int wid = tid >> 6, lane = tid & 63, ln = lane & 15, kg = lane >> 4;
  int wm = (wid >> 1) * 64, wn = (wid & 1) * 64;
  f32x4 acc[4][4] = {};

  auto stage = [&](int buf, int kt) {
    const u16* ga = gA + kt * 32;
    gl16(ga, &As[buf][lrow][lk]);
    gl16(ga + 64 * K, &As[buf][lrow + 64][lk]);
    const u16* gb = gB + kt * 32;
    gl16(gb, &Bs[buf][lrow][lk]);
    gl16(gb + 64 * K, &Bs[buf][lrow + 64][lk]);
  };

  stage(0, 0);
  asm volatile("s_waitcnt vmcnt(0)" ::: "memory");
  __syncthreads();
  int cur = 0;
  for (int kt = 0; kt < 32; ++kt) {
    if (kt < 31) stage(cur ^ 1, kt + 1);
    short8 af[4], bfr[4];
#pragma unroll
    for (int i = 0; i < 4; ++i) af[i] = *(const short8*)&As[cur][wm + i * 16 + ln][kg * 8];
#pragma unroll
    for (int i = 0; i < 4; ++i) bfr[i] = *(const short8*)&Bs[cur][wn + i * 16 + ln][kg * 8];
#pragma unroll
    for (int mi = 0; mi < 4; ++mi)
#pragma unroll
      for (int ni = 0; ni < 4; ++ni)
        acc[mi][ni] = __builtin_amdgcn_mfma_f32_16x16x32_bf16(af[mi], bfr[ni], acc[mi][ni], 0, 0, 0);
    __syncthreads();
    cur ^= 1;
  }

  int sec = n0 >> 10;                 // 0=Q 1=K 2=V
  int col0 = (n0 & 1023) + wn;        // head-aligned 64-col wave
  int h = col0 >> 6;
  if (sec < 2) {
    u16* Out = (sec == 0) ? Qo : Ko;
    float sc = (sec == 0) ? 0.125f : 1.0f;
#pragma unroll
    for (int mi = 0; mi < 4; ++mi) {
#pragma unroll
      for (int j = 0; j < 4; ++j) {
        int mm = m0 + wm + mi * 16 + kg * 4 + j;
        int l = mm & (L_ - 1), b = mm >> 11;
        const float2* tl = rope + l * 32;
#pragma unroll
        for (int ni = 0; ni < 2; ++ni) {
          int dA = ni * 16 + ln;
          float xa = acc[mi][ni][j], xb = acc[mi][ni + 2][j];
          float2 fA = tl[dA >> 1];
          float2 fB = tl[16 + (dA >> 1)];
          float oA = (fA.x * xa - fA.y * xb) * sc;
          float oB = (fB.x * xb + fB.y * xa) * sc;
          size_t base = ((size_t)(b * H_ + h) * L_ + l) * D_;
          Out[base + dA] = f2bf(oA);
          Out[base + dA + 32] = f2bf(oB);
        }
      }
    }
  } else {
    // V -> chunk-tiled: Vo[bh][l>>5][d][l&31]
#pragma unroll
    for (int mi = 0; mi < 4; ++mi)
#pragma unroll
      for (int j = 0; j < 4; ++j) {
        int mm = m0 + wm + mi * 16 + kg * 4 + j;
        int l = mm & (L_ - 1), b = mm >> 11;
        size_t base = (size_t)(b * H_ + h) * (L_ * D_) + (size_t)(l >> 5) * 2048 + (l & 31);
#pragma unroll
        for (int ni = 0; ni < 4; ++ni) {
          int d = ni * 16 + ln;
          Vo[base + (size_t)d * 32] = f2bf(acc[mi][ni][j]);
        }
      }
  }
}

// ---------------- out-projection GEMM: 64x128 tiles, grid (8,64) = 512 blocks ----------------

__global__ __launch_bounds__(256) void oproj_k(
    const u16* __restrict__ A, const u16* __restrict__ Bt, float* __restrict__ Out)
{
  const int K = 1024;
  __shared__ alignas(16) u16 As[2][64][32];
  __shared__ alignas(16) u16 Bs[2][128][32];
  int tid = threadIdx.x;
  int tn = blockIdx.x, tm = blockIdx.y;
  int m0 = tm * 64, n0 = tn * 128;
  int lrow = tid >> 2, lk = (tid & 3) * 8;
  const u16* gA = A + (size_t)(m0 + lrow) * K + lk;
  const u16* gB = Bt + (size_t)(n0 + lrow) * K + lk;
  int wid = tid >> 6, lane = tid & 63, ln = lane & 15, kg = lane >> 4;
  int wm = (wid >> 1) * 32, wn = (wid & 1) * 64;
  f32x4 acc[2][4] = {};

  auto stage = [&](int buf, int kt) {
    gl16(gA + kt * 32, &As[buf][lrow][lk]);
    const u16* gb = gB + kt * 32;
    gl16(gb, &Bs[buf][lrow][lk]);
    gl16(gb + 64 * K, &Bs[buf][lrow + 64][lk]);
  };

  stage(0, 0);
  asm volatile("s_waitcnt vmcnt(0)" ::: "memory");
  __syncthreads();
  int cur = 0;
  for (int kt = 0; kt < 32; ++kt) {
    if (kt < 31) stage(cur ^ 1, kt + 1);
    short8 af[2], bfr[4];
#pragma unroll
    for (int i = 0; i < 2; ++i) af[i] = *(const short8*)&As[cur][wm + i * 16 + ln][kg * 8];
#pragma unroll
    for (int i = 0; i < 4; ++i) bfr[i] = *(const short8*)&Bs[cur][wn + i * 16 + ln][kg * 8];
#pragma unroll
    for (int mi = 0; mi < 2; ++mi)
#pragma unroll
      for (int ni = 0; ni < 4; ++ni)
        acc[mi][ni] = __builtin_amdgcn_mfma_f32_16x16x32_bf16(af[mi], bfr[ni], acc[mi][ni], 0, 0, 0);
    __syncthreads();
    cur ^= 1;
  }
#pragma unroll
  for (int mi = 0; mi < 2; ++mi)
#pragma unroll
    for (int j = 0; j < 4; ++j) {
      int mm = m0 + wm + mi * 16 + kg * 4 + j;
#pragma unroll
      for (int ni = 0; ni < 4; ++ni)
        Out[(size_t)mm * 1024 + n0 + wn + ni * 16 + ln] = acc[mi][ni][j];
    }
}

// ---------------- flash attention v5: block-shared LDS K/V staging ----------------
// Block = (bh, 64-q tile); 4 waves x 16 q-rows march over kv chunks together.
// K chunk [32kv][64d] staged with XOR-swizzled SOURCE (linear LDS dest, m173 pattern);
// V chunk [64d][32kv] contiguous from chunk-tiled Vt. Double-buffered, 1 barrier/chunk.
// Swapped QK^T + lane-group softmax + register P^T gather (rounds 4/5 verified math).
__global__ __launch_bounds__(256) void attn_k(
    const u16* __restrict__ Q, const u16* __restrict__ K,
    const u16* __restrict__ V, u16* __restrict__ AO)
{
  __shared__ alignas(16) u16 Ks[2][32 * 64];
  __shared__ alignas(16) u16 Vs[2][64 * 32];
  int tid = threadIdx.x;
  int wid = tid >> 6, lane = tid & 63;
  int ln = lane & 15, kg = lane >> 4;
  int bh = blockIdx.y;
  int qt = 31 - blockIdx.x;            // heavy tiles dispatch first
  int q0 = qt * 64 + wid * 16;
  const u16* Qh = Q + (size_t)bh * L_ * D_;
  const u16* Kh = K + (size_t)bh * L_ * D_;
  const u16* Vt = V + (size_t)bh * L_ * D_;   // chunk-tiled [l/32][64][32]

  // staging sources: K pre-swizzled (dest row=tid>>3, blk=tid&7 gets K[row][blk^(row&7)])
  int srow = tid >> 3, sblk = tid & 7;
  const u16* kb = Kh + (size_t)srow * 64 + ((sblk ^ (srow & 7)) << 3);
  const u16* vb = Vt + tid * 8;

  short8 qf0 = *(const short8*)(Qh + (size_t)(q0 + ln) * D_ + kg * 8);
  short8 qf1 = *(const short8*)(Qh + (size_t)(q0 + ln) * D_ + 32 + kg * 8);

  f32x4 o[4] = {};
  float m = -1e30f, l = 0.f;
  int srcA = ln + (((2 * kg) & 3) << 4);
  int srcB = ln + (((2 * kg + 1) & 3) << 4);
  bool thi = (kg >= 2);

  int nchunks = 2 * qt + 2;
  int mask_from = 2 * qt;

  auto stage = [&](int c, int buf) {
    gl16(kb + (size_t)c * 2048, &Ks[buf][tid * 8]);
    gl16(vb + (size_t)c * 2048, &Vs[buf][tid * 8]);
  };

  stage(0, 0);
  asm volatile("s_waitcnt vmcnt(0)" ::: "memory");
  __syncthreads();
  int cur = 0;
  int sw0 = (kg ^ (ln & 7)) * 8;
  int sw1 = ((4 + kg) ^ (ln & 7)) * 8;

  for (int c = 0; c < nchunks; ++c) {
    if (c + 1 < nchunks) stage(c + 1, cur ^ 1);
    short8 k0a = *(const short8*)&Ks[cur][ln * 64 + sw0];
    short8 k0b = *(const short8*)&Ks[cur][ln * 64 + sw1];
    short8 k1a = *(const short8*)&Ks[cur][(ln + 16) * 64 + sw0];
    short8 k1b = *(const short8*)&Ks[cur][(ln + 16) * 64 + sw1];
    f32x4 s0 = {}, s1 = {};
    s0 = __builtin_amdgcn_mfma_f32_16x16x32_bf16(k0a, qf0, s0, 0, 0, 0);
    s0 = __builtin_amdgcn_mfma_f32_16x16x32_bf16(k0b, qf1, s0, 0, 0, 0);
    s1 = __builtin_amdgcn_mfma_f32_16x16x32_bf16(k1a, qf0, s1, 0, 0, 0);
    s1 = __builtin_amdgcn_mfma_f32_16x16x32_bf16(k1b, qf1, s1, 0, 0, 0);
    short8 vf0 = *(const short8*)&Vs[cur][ln * 32 + kg * 8];
    short8 vf1 = *(const short8*)&Vs[cur][(16 + ln) * 32 + kg * 8];
    short8 vf2 = *(const short8*)&Vs[cur][(32 + ln) * 32 + kg * 8];
    short8 vf3 = *(const short8*)&Vs[cur][(48 + ln) * 32 + kg * 8];
    if (c >= mask_from) {
      int kvb = c * 32 + kg * 4;
      int q = q0 + ln;
#pragma unroll
      for (int r = 0; r < 4; ++r) {
        if (kvb + r > q) s0[r] = -1e30f;
        if (kvb + 16 + r > q) s1[r] = -1e30f;
      }
    }
    // ---- online softmax + P^T gather + PV (verified math) ----
    {
      float cmax = fmaxf(fmaxf(fmaxf(s0[0], s0[1]), fmaxf(s0[2], s0[3])),
                         fmaxf(fmaxf(s1[0], s1[1]), fmaxf(s1[2], s1[3])));
      cmax = fmaxf(cmax, __shfl_xor(cmax, 16));
      cmax = fmaxf(cmax, __shfl_xor(cmax, 32));
      float mnew = fmaxf(m, cmax);
      float al = __expf(m - mnew);
      m = mnew;
      float p0[4], p1[4];
      float psum = 0.f;
#pragma unroll
      for (int r = 0; r < 4; ++r) {
        p0[r] = __expf(s0[r] - mnew);
        p1[r] = __expf(s1[r] - mnew);
        psum += p0[r] + p1[r];
      }
      psum += __shfl_xor(psum, 16);
      psum += __shfl_xor(psum, 32);
      l = l * al + psum;
#pragma unroll
      for (int dt = 0; dt < 4; ++dt) o[dt] *= al;
      u32 wA0 = (u32)f2bf(p0[0]) | ((u32)f2bf(p0[1]) << 16);
      u32 wB0 = (u32)f2bf(p0[2]) | ((u32)f2bf(p0[3]) << 16);
      u32 wA1 = (u32)f2bf(p1[0]) | ((u32)f2bf(p1[1]) << 16);
      u32 wB1 = (u32)f2bf(p1[2]) | ((u32)f2bf(p1[3]) << 16);
      u32 a0 = __shfl((int)wA0, srcA), a1 = __shfl((int)wA1, srcA);
      u32 b0 = __shfl((int)wB0, srcA), b1 = __shfl((int)wB1, srcA);
      u32 c0 = __shfl((int)wA0, srcB), c1 = __shfl((int)wA1, srcB);
      u32 e0 = __shfl((int)wB0, srcB), e1 = __shfl((int)wB1, srcB);
      union { u32 u[4]; short8 s8; } pu;
      pu.u[0] = thi ? a1 : a0;
      pu.u[1] = thi ? b1 : b0;
      pu.u[2] = thi ? c1 : c0;
      pu.u[3] = thi ? e1 : e0;
      o[0] = __builtin_amdgcn_mfma_f32_16x16x32_bf16(vf0, pu.s8, o[0], 0, 0, 0);
      o[1] = __builtin_amdgcn_mfma_f32_16x16x32_bf16(vf1, pu.s8, o[1], 0, 0, 0);
      o[2] = __builtin_amdgcn_mfma_f32_16x16x32_bf16(vf2, pu.s8, o[2], 0, 0, 0);
      o[3] = __builtin_amdgcn_mfma_f32_16x16x32_bf16(vf3, pu.s8, o[3], 0, 0, 0);
    }
    __syncthreads();
    cur ^= 1;
  }

  // ---- epilogue: O^T[d][q] -> AO[b][q][h][d], d = dt*16 + kg*4 + r ----
  float inv = 1.0f / l;
  int q = q0 + ln;
  int b = bh >> 4, h = bh & 15;
  u16* row = AO + ((size_t)(b * L_ + q) * H_ + h) * D_;
#pragma unroll
  for (int dt = 0; dt < 4; ++dt) {
    union { u16 pk[4]; uint2 v; } u;
#pragma unroll
    for (int r = 0; r < 4; ++r) u.pk[r] = f2bf(o[dt][r] * inv);
    *(uint2*)(row + dt * 16 + kg * 4) = u.v;
  }
}

// ---------------- launch ----------------

extern "C" void kernel_launch(void* const* d_in, const int* in_sizes, int n_in,
                              void* d_out, int out_size, void* d_ws, size_t ws_size,
                              hipStream_t stream) {
  (void)in_sizes; (void)n_in; (void)out_size; (void)ws_size;
  const float* x   = (const float*)d_in[0];
  const int*   pos = (const int*)d_in[1];
  // d_in[2] = additive causal mask (we apply causal masking directly)
  const float* Wq  = (const float*)d_in[3];
  const float* Wk  = (const float*)d_in[4];
  const float* Wv  = (const float*)d_in[5];
  const float* Wo  = (const float*)d_in[6];

  char* ws = (char*)d_ws;
  u16* xbf = (u16*)ws;                        // 8 MB
  u16* Wt3 = (u16*)(ws + (size_t)( 8 << 20)); // 6 MB ([Wq|Wk|Wv]^T stacked)
  u16* Wto = (u16*)(ws + (size_t)(14 << 20)); // 2 MB
  u16* Qb  = (u16*)(ws + (size_t)(16 << 20)); // 8 MB each
  u16* Kb  = (u16*)(ws + (size_t)(24 << 20));
  u16* Vt  = (u16*)(ws + (size_t)(32 << 20)); // chunk-tiled
  u16* AO  = (u16*)(ws + (size_t)(40 << 20));
  float2* tab = (float2*)(ws + (size_t)(48 << 20)); // 512 KB

  cvt_bf16_k<<<2048, 256, 0, stream>>>(x, xbf, 4096 * 1024);
  transpose_bf_k<<<1024, 256, 0, stream>>>(Wq, Wt3);
  transpose_bf_k<<<1024, 256, 0, stream>>>(Wk, Wt3 + (size_t)1048576);
  transpose_bf_k<<<1024, 256, 0, stream>>>(Wv, Wt3 + (size_t)2097152);
  transpose_bf_k<<<1024, 256, 0, stream>>>(Wo, Wto);
  rope_tab_k<<<256, 256, 0, stream>>>(pos, tab);
  qkv_gemm_k<<<dim3(24, 32), 256, 0, stream>>>(xbf, Wt3, Qb, Kb, Vt, tab);
  attn_k<<<dim3(32, 32), 256, 0, stream>>>(Qb, Kb, Vt, AO);
  oproj_k<<<dim3(8, 64), 256, 0, stream>>>(AO, Wto, (float*)d_out);
}

// Round 8
// 188.448 us; speedup vs baseline: 1.8238x; 1.0720x over previous
//
#include <hip/hip_runtime.h>

typedef unsigned short u16;
typedef unsigned int u32;
typedef __attribute__((ext_vector_type(8))) short short8;
typedef __attribute__((ext_vector_type(4))) float f32x4;

#define H_ 16
#define L_ 2048
#define D_ 64
#define HID_ 1024

__device__ __forceinline__ u16 f2bf(float f) {
  union { float f; u32 u; } v; v.f = f;
  u32 r = v.u + 0x7FFFu + ((v.u >> 16) & 1u);
  return (u16)(r >> 16);
}

// async global->LDS, 16B per lane
__device__ __forceinline__ void gl16(const u16* g, u16* l) {
  __builtin_amdgcn_global_load_lds(
      (const __attribute__((address_space(1))) void*)g,
      (__attribute__((address_space(3))) void*)l, 16, 0, 0);
}

// ---------------- prep kernels ----------------

__global__ __launch_bounds__(256) void cvt_bf16_k(const float* __restrict__ in,
                                                  u16* __restrict__ out, int n) {
  int i = (blockIdx.x * 256 + threadIdx.x) * 8;
  if (i >= n) return;
  float4 a = *(const float4*)(in + i);
  float4 b = *(const float4*)(in + i + 4);
  u16 r[8] = { f2bf(a.x), f2bf(a.y), f2bf(a.z), f2bf(a.w),
               f2bf(b.x), f2bf(b.y), f2bf(b.z), f2bf(b.w) };
  *(uint4*)(out + i) = *(const uint4*)r;
}

// W [K=1024][N=1024] f32 -> Wt [N][K] bf16
__global__ __launch_bounds__(256) void transpose_bf_k(const float* __restrict__ in,
                                                      u16* __restrict__ out) {
  __shared__ float t[32][33];
  int bx = blockIdx.x & 31, by = blockIdx.x >> 5;
  int c = threadIdx.x & 31, r0 = threadIdx.x >> 5;
#pragma unroll
  for (int p = 0; p < 4; ++p) {
    int r = r0 + p * 8;
    t[r][c] = in[(size_t)(by * 32 + r) * 1024 + bx * 32 + c];
  }
  __syncthreads();
#pragma unroll
  for (int p = 0; p < 4; ++p) {
    int r = r0 + p * 8;
    out[(size_t)(bx * 32 + r) * 1024 + by * 32 + c] = f2bf(t[c][r]);
  }
}

// tab[l][i] = (cos, sin)(pos[l] * base^(-2i/64)),  l<2048, i<32
__global__ __launch_bounds__(256) void rope_tab_k(const int* __restrict__ pos,
                                                  float2* __restrict__ tab) {
  int gid = blockIdx.x * 256 + threadIdx.x;
  int l = gid >> 5, i = gid & 31;
  float p = (float)pos[l];
  float inv = expf(-((float)(2 * i) / 64.0f) * logf(10000.0f));
  float th = p * inv;
  tab[gid] = make_float2(cosf(th), sinf(th));
}

// ---------------- fused QKV GEMM: C = x[4096,1024] * [Wq|Wk|Wv] (N=3072) ----------------

__global__ __launch_bounds__(256) void qkv_gemm_k(
    const u16* __restrict__ A, const u16* __restrict__ Bt,
    u16* __restrict__ Qo, u16* __restrict__ Ko, u16* __restrict__ Vo,
    const float2* __restrict__ rope)
{
  const int K = 1024;
  __shared__ alignas(16) u16 As[2][128][32];
  __shared__ alignas(16) u16 Bs[2][128][32];
  int tid = threadIdx.x;
  int tn = blockIdx.x, tm = blockIdx.y;
  int m0 = tm * 128, n0 = tn * 128;
  int lrow = tid >> 2, lk = (tid & 3) * 8;
  const u16* gA = A + (size_t)(m0 + lrow) * K + lk;
  const u16* gB = Bt + (size_t)(n0 + lrow) * K + lk;
  int wid = tid >> 6, lane = tid & 63, ln = lane & 15, kg = lane >> 4;
  int wm = (wid >> 1) * 64, wn = (wid & 1) * 64;
  f32x4 acc[4][4] = {};

  auto stage = [&](int buf, int kt) {
    const u16* ga = gA + kt * 32;
    gl16(ga, &As[buf][lrow][lk]);
    gl16(ga + 64 * K, &As[buf][lrow + 64][lk]);
    const u16* gb = gB + kt * 32;
    gl16(gb, &Bs[buf][lrow][lk]);
    gl16(gb + 64 * K, &Bs[buf][lrow + 64][lk]);
  };

  stage(0, 0);
  asm volatile("s_waitcnt vmcnt(0)" ::: "memory");
  __syncthreads();
  int cur = 0;
  for (int kt = 0; kt < 32; ++kt) {
    if (kt < 31) stage(cur ^ 1, kt + 1);
    short8 af[4], bfr[4];
#pragma unroll
    for (int i = 0; i < 4; ++i) af[i] = *(const short8*)&As[cur][wm + i * 16 + ln][kg * 8];
#pragma unroll
    for (int i = 0; i < 4; ++i) bfr[i] = *(const short8*)&Bs[cur][wn + i * 16 + ln][kg * 8];
#pragma unroll
    for (int mi = 0; mi < 4; ++mi)
#pragma unroll
      for (int ni = 0; ni < 4; ++ni)
        acc[mi][ni] = __builtin_amdgcn_mfma_f32_16x16x32_bf16(af[mi], bfr[ni], acc[mi][ni], 0, 0, 0);
    __syncthreads();
    cur ^= 1;
  }

  int sec = n0 >> 10;                 // 0=Q 1=K 2=V
  int col0 = (n0 & 1023) + wn;        // head-aligned 64-col wave
  int h = col0 >> 6;
  if (sec < 2) {
    u16* Out = (sec == 0) ? Qo : Ko;
    float sc = (sec == 0) ? 0.125f : 1.0f;
#pragma unroll
    for (int mi = 0; mi < 4; ++mi) {
#pragma unroll
      for (int j = 0; j < 4; ++j) {
        int mm = m0 + wm + mi * 16 + kg * 4 + j;
        int l = mm & (L_ - 1), b = mm >> 11;
        const float2* tl = rope + l * 32;
#pragma unroll
        for (int ni = 0; ni < 2; ++ni) {
          int dA = ni * 16 + ln;
          float xa = acc[mi][ni][j], xb = acc[mi][ni + 2][j];
          float2 fA = tl[dA >> 1];
          float2 fB = tl[16 + (dA >> 1)];
          float oA = (fA.x * xa - fA.y * xb) * sc;
          float oB = (fB.x * xb + fB.y * xa) * sc;
          size_t base = ((size_t)(b * H_ + h) * L_ + l) * D_;
          Out[base + dA] = f2bf(oA);
          Out[base + dA + 32] = f2bf(oB);
        }
      }
    }
  } else {
    // V -> chunk-tiled: Vo[bh][l>>5][d][l&31]
#pragma unroll
    for (int mi = 0; mi < 4; ++mi)
#pragma unroll
      for (int j = 0; j < 4; ++j) {
        int mm = m0 + wm + mi * 16 + kg * 4 + j;
        int l = mm & (L_ - 1), b = mm >> 11;
        size_t base = (size_t)(b * H_ + h) * (L_ * D_) + (size_t)(l >> 5) * 2048 + (l & 31);
#pragma unroll
        for (int ni = 0; ni < 4; ++ni) {
          int d = ni * 16 + ln;
          Vo[base + (size_t)d * 32] = f2bf(acc[mi][ni][j]);
        }
      }
  }
}

// ---------------- out-projection GEMM: 64x128 tiles, grid (8,64) = 512 blocks ----------------

__global__ __launch_bounds__(256) void oproj_k(
    const u16* __restrict__ A, const u16* __restrict__ Bt, float* __restrict__ Out)
{
  const int K = 1024;
  __shared__ alignas(16) u16 As[2][64][32];
  __shared__ alignas(16) u16 Bs[2][128][32];
  int tid = threadIdx.x;
  int tn = blockIdx.x, tm = blockIdx.y;
  int m0 = tm * 64, n0 = tn * 128;
  int lrow = tid >> 2, lk = (tid & 3) * 8;
  const u16* gA = A + (size_t)(m0 + lrow) * K + lk;
  const u16* gB = Bt + (size_t)(n0 + lrow) * K + lk;
  int wid = tid >> 6, lane = tid & 63, ln = lane & 15, kg = lane >> 4;
  int wm = (wid >> 1) * 32, wn = (wid & 1) * 64;
  f32x4 acc[2][4] = {};

  auto stage = [&](int buf, int kt) {
    gl16(gA + kt * 32, &As[buf][lrow][lk]);
    const u16* gb = gB + kt * 32;
    gl16(gb, &Bs[buf][lrow][lk]);
    gl16(gb + 64 * K, &Bs[buf][lrow + 64][lk]);
  };

  stage(0, 0);
  asm volatile("s_waitcnt vmcnt(0)" ::: "memory");
  __syncthreads();
  int cur = 0;
  for (int kt = 0; kt < 32; ++kt) {
    if (kt < 31) stage(cur ^ 1, kt + 1);
    short8 af[2], bfr[4];
#pragma unroll
    for (int i = 0; i < 2; ++i) af[i] = *(const short8*)&As[cur][wm + i * 16 + ln][kg * 8];
#pragma unroll
    for (int i = 0; i < 4; ++i) bfr[i] = *(const short8*)&Bs[cur][wn + i * 16 + ln][kg * 8];
#pragma unroll
    for (int mi = 0; mi < 2; ++mi)
#pragma unroll
      for (int ni = 0; ni < 4; ++ni)
        acc[mi][ni] = __builtin_amdgcn_mfma_f32_16x16x32_bf16(af[mi], bfr[ni], acc[mi][ni], 0, 0, 0);
    __syncthreads();
    cur ^= 1;
  }
#pragma unroll
  for (int mi = 0; mi < 2; ++mi)
#pragma unroll
    for (int j = 0; j < 4; ++j) {
      int mm = m0 + wm + mi * 16 + kg * 4 + j;
#pragma unroll
      for (int ni = 0; ni < 4; ++ni)
        Out[(size_t)mm * 1024 + n0 + wn + ni * 16 + ln] = acc[mi][ni][j];
    }
}

// ---------------- flash attention v6: defer-max + lane-partial l + cvt_pk + 2x TLP ----------------
// Block = (bh, 32-q tile), 2 waves x 16 q-rows; grid (64,32) = 2048 blocks -> 16 waves/CU.
// K chunk XOR-swizzled via pre-swizzled global source; V chunk-tiled contiguous.
// Defer-max (thr=8): skip cross-lane max reduce + o-rescale when __all(local_max <= m+8).
// l kept as per-lane partial, reduced once at the end. P packed via v_cvt_pk_bf16_f32.
__global__ __launch_bounds__(128) void attn_k(
    const u16* __restrict__ Q, const u16* __restrict__ K,
    const u16* __restrict__ V, u16* __restrict__ AO)
{
  __shared__ alignas(16) u16 Ks[2][32 * 64];
  __shared__ alignas(16) u16 Vs[2][64 * 32];
  int tid = threadIdx.x;
  int wid = tid >> 6, lane = tid & 63;
  int ln = lane & 15, kg = lane >> 4;
  int bh = blockIdx.y;
  int qt = 63 - blockIdx.x;            // heavy q-tiles dispatch first
  int q0 = qt * 32 + wid * 16;
  const u16* Qh = Q + (size_t)bh * L_ * D_;
  const u16* Kh = K + (size_t)bh * L_ * D_;
  const u16* Vt = V + (size_t)bh * L_ * D_;   // chunk-tiled [l/32][64][32]

  // staging sources (128 threads; 2 passes of 2KB for each of K and V)
  int srow = tid >> 3, sblk = tid & 7;
  const u16* kb = Kh + (size_t)srow * 64 + ((sblk ^ (srow & 7)) << 3);
  const u16* vb = Vt + tid * 8;

  short8 qf0 = *(const short8*)(Qh + (size_t)(q0 + ln) * D_ + kg * 8);
  short8 qf1 = *(const short8*)(Qh + (size_t)(q0 + ln) * D_ + 32 + kg * 8);

  f32x4 o[4] = {};
  float m = -1e30f, lsum = 0.f;
  int srcA = ln + (((2 * kg) & 3) << 4);
  int srcB = ln + (((2 * kg + 1) & 3) << 4);
  bool thi = (kg >= 2);

  int nchunks = qt + 1;                // chunk qt is the diagonal chunk

  auto stage = [&](int c, int buf) {
    const u16* kc = kb + (size_t)c * 2048;
    const u16* vc = vb + (size_t)c * 2048;
    gl16(kc, &Ks[buf][tid * 8]);
    gl16(kc + 1024, &Ks[buf][1024 + tid * 8]);
    gl16(vc, &Vs[buf][tid * 8]);
    gl16(vc + 1024, &Vs[buf][1024 + tid * 8]);
  };

  stage(0, 0);
  asm volatile("s_waitcnt vmcnt(0)" ::: "memory");
  __syncthreads();
  int cur = 0;
  int sw0 = (kg ^ (ln & 7)) * 8;
  int sw1 = ((4 + kg) ^ (ln & 7)) * 8;

  for (int c = 0; c < nchunks; ++c) {
    if (c + 1 < nchunks) stage(c + 1, cur ^ 1);
    short8 k0a = *(const short8*)&Ks[cur][ln * 64 + sw0];
    short8 k0b = *(const short8*)&Ks[cur][ln * 64 + sw1];
    short8 k1a = *(const short8*)&Ks[cur][(ln + 16) * 64 + sw0];
    short8 k1b = *(const short8*)&Ks[cur][(ln + 16) * 64 + sw1];
    f32x4 s0 = {}, s1 = {};
    __builtin_amdgcn_s_setprio(1);
    s0 = __builtin_amdgcn_mfma_f32_16x16x32_bf16(k0a, qf0, s0, 0, 0, 0);
    s0 = __builtin_amdgcn_mfma_f32_16x16x32_bf16(k0b, qf1, s0, 0, 0, 0);
    s1 = __builtin_amdgcn_mfma_f32_16x16x32_bf16(k1a, qf0, s1, 0, 0, 0);
    s1 = __builtin_amdgcn_mfma_f32_16x16x32_bf16(k1b, qf1, s1, 0, 0, 0);
    __builtin_amdgcn_s_setprio(0);
    short8 vf0 = *(const short8*)&Vs[cur][ln * 32 + kg * 8];
    short8 vf1 = *(const short8*)&Vs[cur][(16 + ln) * 32 + kg * 8];
    short8 vf2 = *(const short8*)&Vs[cur][(32 + ln) * 32 + kg * 8];
    short8 vf3 = *(const short8*)&Vs[cur][(48 + ln) * 32 + kg * 8];
    if (c == qt) {                     // diagonal chunk: mask kv > q
      int kvb = c * 32 + kg * 4;
      int q = q0 + ln;
#pragma unroll
      for (int r = 0; r < 4; ++r) {
        if (kvb + r > q) s0[r] = -1e30f;
        if (kvb + 16 + r > q) s1[r] = -1e30f;
      }
    }
    // ---- online softmax with defer-max ----
    float lc = fmaxf(fmaxf(fmaxf(s0[0], s0[1]), fmaxf(s0[2], s0[3])),
                     fmaxf(fmaxf(s1[0], s1[1]), fmaxf(s1[2], s1[3])));
    if (!__all(lc <= m + 8.f)) {
      float cmax = fmaxf(lc, __shfl_xor(lc, 16));
      cmax = fmaxf(cmax, __shfl_xor(cmax, 32));
      float mnew = fmaxf(m, cmax);
      float al = __expf(m - mnew);
      m = mnew;
      lsum *= al;
#pragma unroll
      for (int dt = 0; dt < 4; ++dt) o[dt] *= al;
    }
    float p0[4], p1[4];
    float ps = 0.f;
#pragma unroll
    for (int r = 0; r < 4; ++r) {
      p0[r] = __expf(s0[r] - m);
      p1[r] = __expf(s1[r] - m);
      ps += p0[r] + p1[r];
    }
    lsum += ps;                        // lane-partial; reduced once at end
    u32 wA0, wB0, wA1, wB1;
    asm("v_cvt_pk_bf16_f32 %0, %1, %2" : "=v"(wA0) : "v"(p0[0]), "v"(p0[1]));
    asm("v_cvt_pk_bf16_f32 %0, %1, %2" : "=v"(wB0) : "v"(p0[2]), "v"(p0[3]));
    asm("v_cvt_pk_bf16_f32 %0, %1, %2" : "=v"(wA1) : "v"(p1[0]), "v"(p1[1]));
    asm("v_cvt_pk_bf16_f32 %0, %1, %2" : "=v"(wB1) : "v"(p1[2]), "v"(p1[3]));
    u32 a0 = __shfl((int)wA0, srcA), a1 = __shfl((int)wA1, srcA);
    u32 b0 = __shfl((int)wB0, srcA), b1 = __shfl((int)wB1, srcA);
    u32 c0 = __shfl((int)wA0, srcB), c1 = __shfl((int)wA1, srcB);
    u32 e0 = __shfl((int)wB0, srcB), e1 = __shfl((int)wB1, srcB);
    union { u32 u[4]; short8 s8; } pu;
    pu.u[0] = thi ? a1 : a0;           // kv rows 8kg+0,1
    pu.u[1] = thi ? b1 : b0;           // kv rows 8kg+2,3
    pu.u[2] = thi ? c1 : c0;           // kv rows 8kg+4,5
    pu.u[3] = thi ? e1 : e0;           // kv rows 8kg+6,7
    __builtin_amdgcn_s_setprio(1);
    o[0] = __builtin_amdgcn_mfma_f32_16x16x32_bf16(vf0, pu.s8, o[0], 0, 0, 0);
    o[1] = __builtin_amdgcn_mfma_f32_16x16x32_bf16(vf1, pu.s8, o[1], 0, 0, 0);
    o[2] = __builtin_amdgcn_mfma_f32_16x16x32_bf16(vf2, pu.s8, o[2], 0, 0, 0);
    o[3] = __builtin_amdgcn_mfma_f32_16x16x32_bf16(vf3, pu.s8, o[3], 0, 0, 0);
    __builtin_amdgcn_s_setprio(0);
    __syncthreads();
    cur ^= 1;
  }

  // ---- final l reduction (per q-column across the 4 lane-groups) ----
  lsum += __shfl_xor(lsum, 16);
  lsum += __shfl_xor(lsum, 32);
  float inv = 1.0f / lsum;
  int q = q0 + ln;
  int b = bh >> 4, h = bh & 15;
  u16* row = AO + ((size_t)(b * L_ + q) * H_ + h) * D_;
#pragma unroll
  for (int dt = 0; dt < 4; ++dt) {
    union { u16 pk[4]; uint2 v; } u;
#pragma unroll
    for (int r = 0; r < 4; ++r) u.pk[r] = f2bf(o[dt][r] * inv);
    *(uint2*)(row + dt * 16 + kg * 4) = u.v;
  }
}

// ---------------- launch ----------------

extern "C" void kernel_launch(void* const* d_in, const int* in_sizes, int n_in,
                              void* d_out, int out_size, void* d_ws, size_t ws_size,
                              hipStream_t stream) {
  (void)in_sizes; (void)n_in; (void)out_size; (void)ws_size;
  const float* x   = (const float*)d_in[0];
  const int*   pos = (const int*)d_in[1];
  // d_in[2] = additive causal mask (we apply causal masking directly)
  const float* Wq  = (const float*)d_in[3];
  const float* Wk  = (const float*)d_in[4];
  const float* Wv  = (const float*)d_in[5];
  const float* Wo  = (const float*)d_in[6];

  char* ws = (char*)d_ws;
  u16* xbf = (u16*)ws;                        // 8 MB
  u16* Wt3 = (u16*)(ws + (size_t)( 8 << 20)); // 6 MB ([Wq|Wk|Wv]^T stacked)
  u16* Wto = (u16*)(ws + (size_t)(14 << 20)); // 2 MB
  u16* Qb  = (u16*)(ws + (size_t)(16 << 20)); // 8 MB each
  u16* Kb  = (u16*)(ws + (size_t)(24 << 20));
  u16* Vt  = (u16*)(ws + (size_t)(32 << 20)); // chunk-tiled
  u16* AO  = (u16*)(ws + (size_t)(40 << 20));
  float2* tab = (float2*)(ws + (size_t)(48 << 20)); // 512 KB

  cvt_bf16_k<<<2048, 256, 0, stream>>>(x, xbf, 4096 * 1024);
  transpose_bf_k<<<1024, 256, 0, stream>>>(Wq, Wt3);
  transpose_bf_k<<<1024, 256, 0, stream>>>(Wk, Wt3 + (size_t)1048576);
  transpose_bf_k<<<1024, 256, 0, stream>>>(Wv, Wt3 + (size_t)2097152);
  transpose_bf_k<<<1024, 256, 0, stream>>>(Wo, Wto);
  rope_tab_k<<<256, 256, 0, stream>>>(pos, tab);
  qkv_gemm_k<<<dim3(24, 32), 256, 0, stream>>>(xbf, Wt3, Qb, Kb, Vt, tab);
  attn_k<<<dim3(64, 32), 128, 0, stream>>>(Qb, Kb, Vt, AO);
  oproj_k<<<dim3(8, 64), 256, 0, stream>>>(AO, Wto, (float*)d_out);
}

// Round 10
// 186.863 us; speedup vs baseline: 1.8393x; 1.0085x over previous
//
#include <hip/hip_runtime.h>

typedef unsigned short u16;
typedef unsigned int u32;
typedef __attribute__((ext_vector_type(8))) short short8;
typedef __attribute__((ext_vector_type(4))) float f32x4;

#define H_ 16
#define L_ 2048
#define D_ 64
#define HID_ 1024

__device__ __forceinline__ u16 f2bf(float f) {
  union { float f; u32 u; } v; v.f = f;
  u32 r = v.u + 0x7FFFu + ((v.u >> 16) & 1u);
  return (u16)(r >> 16);
}

// async global->LDS, 16B per lane
__device__ __forceinline__ void gl16(const u16* g, u16* l) {
  __builtin_amdgcn_global_load_lds(
      (const __attribute__((address_space(1))) void*)g,
      (__attribute__((address_space(3))) void*)l, 16, 0, 0);
}

// ---------------- prep kernels ----------------

__global__ __launch_bounds__(256) void cvt_bf16_k(const float* __restrict__ in,
                                                  u16* __restrict__ out, int n) {
  int i = (blockIdx.x * 256 + threadIdx.x) * 8;
  if (i >= n) return;
  float4 a = *(const float4*)(in + i);
  float4 b = *(const float4*)(in + i + 4);
  u16 r[8] = { f2bf(a.x), f2bf(a.y), f2bf(a.z), f2bf(a.w),
               f2bf(b.x), f2bf(b.y), f2bf(b.z), f2bf(b.w) };
  *(uint4*)(out + i) = *(const uint4*)r;
}

// W [K=1024][N=1024] f32 -> Wt [N][K] bf16
__global__ __launch_bounds__(256) void transpose_bf_k(const float* __restrict__ in,
                                                      u16* __restrict__ out) {
  __shared__ float t[32][33];
  int bx = blockIdx.x & 31, by = blockIdx.x >> 5;
  int c = threadIdx.x & 31, r0 = threadIdx.x >> 5;
#pragma unroll
  for (int p = 0; p < 4; ++p) {
    int r = r0 + p * 8;
    t[r][c] = in[(size_t)(by * 32 + r) * 1024 + bx * 32 + c];
  }
  __syncthreads();
#pragma unroll
  for (int p = 0; p < 4; ++p) {
    int r = r0 + p * 8;
    out[(size_t)(bx * 32 + r) * 1024 + by * 32 + c] = f2bf(t[c][r]);
  }
}

// tab[l][i] = (cos, sin)(pos[l] * base^(-2i/64)),  l<2048, i<32
__global__ __launch_bounds__(256) void rope_tab_k(const int* __restrict__ pos,
                                                  float2* __restrict__ tab) {
  int gid = blockIdx.x * 256 + threadIdx.x;
  int l = gid >> 5, i = gid & 31;
  float p = (float)pos[l];
  float inv = expf(-((float)(2 * i) / 64.0f) * logf(10000.0f));
  float th = p * inv;
  tab[gid] = make_float2(cosf(th), sinf(th));
}

// ---------------- fused QKV GEMM: C = x[4096,1024] * [Wq|Wk|Wv] (N=3072) ----------------
// Counted-vmcnt pipeline (T4): 3-buffer LDS, stage(kt+2) post-barrier, vmcnt(4) not 0.

__global__ __launch_bounds__(256) void qkv_gemm_k(
    const u16* __restrict__ A, const u16* __restrict__ Bt,
    u16* __restrict__ Qo, u16* __restrict__ Ko, u16* __restrict__ Vo,
    const float2* __restrict__ rope)
{
  const int K = 1024;
  __shared__ alignas(16) u16 As[3][128][32];
  __shared__ alignas(16) u16 Bs[3][128][32];
  int tid = threadIdx.x;
  int tn = blockIdx.x, tm = blockIdx.y;
  int m0 = tm * 128, n0 = tn * 128;
  int lrow = tid >> 2, lk = (tid & 3) * 8;
  const u16* gA = A + (size_t)(m0 + lrow) * K + lk;
  const u16* gB = Bt + (size_t)(n0 + lrow) * K + lk;
  int wid = tid >> 6, lane = tid & 63, ln = lane & 15, kg = lane >> 4;
  int wm = (wid >> 1) * 64, wn = (wid & 1) * 64;
  f32x4 acc[4][4] = {};

  auto stage = [&](int kt, int buf) {
    const u16* ga = gA + kt * 32;
    gl16(ga, &As[buf][lrow][lk]);
    gl16(ga + 64 * K, &As[buf][lrow + 64][lk]);
    const u16* gb = gB + kt * 32;
    gl16(gb, &Bs[buf][lrow][lk]);
    gl16(gb + 64 * K, &Bs[buf][lrow + 64][lk]);
  };

  stage(0, 0);
  stage(1, 1);
  int cur = 0, nx2 = 2;
  for (int kt = 0; kt < 32; ++kt) {
    if (kt + 1 < 32) { asm volatile("s_waitcnt vmcnt(4)" ::: "memory"); }
    else             { asm volatile("s_waitcnt vmcnt(0)" ::: "memory"); }
    __builtin_amdgcn_s_barrier();
    __builtin_amdgcn_sched_barrier(0);
    if (kt + 2 < 32) stage(kt + 2, nx2);
    short8 af[4], bfr[4];
#pragma unroll
    for (int i = 0; i < 4; ++i) af[i] = *(const short8*)&As[cur][wm + i * 16 + ln][kg * 8];
#pragma unroll
    for (int i = 0; i < 4; ++i) bfr[i] = *(const short8*)&Bs[cur][wn + i * 16 + ln][kg * 8];
#pragma unroll
    for (int mi = 0; mi < 4; ++mi)
#pragma unroll
      for (int ni = 0; ni < 4; ++ni)
        acc[mi][ni] = __builtin_amdgcn_mfma_f32_16x16x32_bf16(af[mi], bfr[ni], acc[mi][ni], 0, 0, 0);
    cur = (cur == 2) ? 0 : cur + 1;
    nx2 = (nx2 == 2) ? 0 : nx2 + 1;
  }

  int sec = n0 >> 10;                 // 0=Q 1=K 2=V
  int col0 = (n0 & 1023) + wn;        // head-aligned 64-col wave
  int h = col0 >> 6;
  if (sec < 2) {
    u16* Out = (sec == 0) ? Qo : Ko;
    float sc = (sec == 0) ? 0.125f : 1.0f;
#pragma unroll
    for (int mi = 0; mi < 4; ++mi) {
#pragma unroll
      for (int j = 0; j < 4; ++j) {
        int mm = m0 + wm + mi * 16 + kg * 4 + j;
        int l = mm & (L_ - 1), b = mm >> 11;
        const float2* tl = rope + l * 32;
#pragma unroll
        for (int ni = 0; ni < 2; ++ni) {
          int dA = ni * 16 + ln;
          float xa = acc[mi][ni][j], xb = acc[mi][ni + 2][j];
          float2 fA = tl[dA >> 1];
          float2 fB = tl[16 + (dA >> 1)];
          float oA = (fA.x * xa - fA.y * xb) * sc;
          float oB = (fB.x * xb + fB.y * xa) * sc;
          size_t base = ((size_t)(b * H_ + h) * L_ + l) * D_;
          Out[base + dA] = f2bf(oA);
          Out[base + dA + 32] = f2bf(oB);
        }
      }
    }
  } else {
    // V -> chunk-tiled: Vo[bh][l>>5][d][l&31]
#pragma unroll
    for (int mi = 0; mi < 4; ++mi)
#pragma unroll
      for (int j = 0; j < 4; ++j) {
        int mm = m0 + wm + mi * 16 + kg * 4 + j;
        int l = mm & (L_ - 1), b = mm >> 11;
        size_t base = (size_t)(b * H_ + h) * (L_ * D_) + (size_t)(l >> 5) * 2048 + (l & 31);
#pragma unroll
        for (int ni = 0; ni < 4; ++ni) {
          int d = ni * 16 + ln;
          Vo[base + (size_t)d * 32] = f2bf(acc[mi][ni][j]);
        }
      }
  }
}

// ---------------- out-projection GEMM: 64x128 tiles, grid (8,64) = 512 blocks ----------------

__global__ __launch_bounds__(256) void oproj_k(
    const u16* __restrict__ A, const u16* __restrict__ Bt, float* __restrict__ Out)
{
  const int K = 1024;
  __shared__ alignas(16) u16 As[2][64][32];
  __shared__ alignas(16) u16 Bs[2][128][32];
  int tid = threadIdx.x;
  int tn = blockIdx.x, tm = blockIdx.y;
  int m0 = tm * 64, n0 = tn * 128;
  int lrow = tid >> 2, lk = (tid & 3) * 8;
  const u16* gA = A + (size_t)(m0 + lrow) * K + lk;
  const u16* gB = Bt + (size_t)(n0 + lrow) * K + lk;
  int wid = tid >> 6, lane = tid & 63, ln = lane & 15, kg = lane >> 4;
  int wm = (wid >> 1) * 32, wn = (wid & 1) * 64;
  f32x4 acc[2][4] = {};

  auto stage = [&](int buf, int kt) {
    gl16(gA + kt * 32, &As[buf][lrow][lk]);
    const u16* gb = gB + kt * 32;
    gl16(gb, &Bs[buf][lrow][lk]);
    gl16(gb + 64 * K, &Bs[buf][lrow + 64][lk]);
  };

  stage(0, 0);
  asm volatile("s_waitcnt vmcnt(0)" ::: "memory");
  __syncthreads();
  int cur = 0;
  for (int kt = 0; kt < 32; ++kt) {
    if (kt < 31) stage(cur ^ 1, kt + 1);
    short8 af[2], bfr[4];
#pragma unroll
    for (int i = 0; i < 2; ++i) af[i] = *(const short8*)&As[cur][wm + i * 16 + ln][kg * 8];
#pragma unroll
    for (int i = 0; i < 4; ++i) bfr[i] = *(const short8*)&Bs[cur][wn + i * 16 + ln][kg * 8];
#pragma unroll
    for (int mi = 0; mi < 2; ++mi)
#pragma unroll
      for (int ni = 0; ni < 4; ++ni)
        acc[mi][ni] = __builtin_amdgcn_mfma_f32_16x16x32_bf16(af[mi], bfr[ni], acc[mi][ni], 0, 0, 0);
    __syncthreads();
    cur ^= 1;
  }
#pragma unroll
  for (int mi = 0; mi < 2; ++mi)
#pragma unroll
    for (int j = 0; j < 4; ++j) {
      int mm = m0 + wm + mi * 16 + kg * 4 + j;
#pragma unroll
      for (int ni = 0; ni < 4; ++ni)
        Out[(size_t)mm * 1024 + n0 + wn + ni * 16 + ln] = acc[mi][ni][j];
    }
}

// ---------------- flash attention v7: counted-vmcnt 3-buffer pipeline ----------------
// Block = (bh, 32-q tile), 2 waves; grid (64,32). Per chunk: vmcnt(4) [stage(c) done,
// stage(c+1) stays in flight] + raw s_barrier + stage(c+2) post-barrier. No vmcnt(0)
// drain in the loop. Defer-max, lane-partial l, cvt_pk P-pack, setprio on MFMA.
__global__ __launch_bounds__(128) void attn_k(
    const u16* __restrict__ Q, const u16* __restrict__ K,
    const u16* __restrict__ V, u16* __restrict__ AO)
{
  __shared__ alignas(16) u16 Ks[3][2048];
  __shared__ alignas(16) u16 Vs[3][2048];
  int tid = threadIdx.x;
  int wid = tid >> 6, lane = tid & 63;
  int ln = lane & 15, kg = lane >> 4;
  int bh = blockIdx.y;
  int qt = 63 - blockIdx.x;            // heavy q-tiles dispatch first
  int q0 = qt * 32 + wid * 16;
  const u16* Qh = Q + (size_t)bh * L_ * D_;
  const u16* Kh = K + (size_t)bh * L_ * D_;
  const u16* Vt = V + (size_t)bh * L_ * D_;   // chunk-tiled [l/32][64][32]

  // staging sources (K pre-swizzled for conflict-free ds_read, linear LDS dest)
  int srow = tid >> 3, sblk = tid & 7;
  const u16* kb = Kh + (size_t)srow * 64 + ((sblk ^ (srow & 7)) << 3);
  const u16* vb = Vt + tid * 8;

  short8 qf0 = *(const short8*)(Qh + (size_t)(q0 + ln) * D_ + kg * 8);
  short8 qf1 = *(const short8*)(Qh + (size_t)(q0 + ln) * D_ + 32 + kg * 8);

  f32x4 o[4] = {};
  float m = -1e30f, lsum = 0.f;
  int srcA = ln + (((2 * kg) & 3) << 4);
  int srcB = ln + (((2 * kg + 1) & 3) << 4);
  bool thi = (kg >= 2);

  int nchunks = qt + 1;                // chunk qt is the diagonal chunk

  auto stage = [&](int c, int buf) {
    const u16* kc = kb + (size_t)c * 2048;
    const u16* vc = vb + (size_t)c * 2048;
    gl16(kc, &Ks[buf][tid * 8]);
    gl16(kc + 1024, &Ks[buf][1024 + tid * 8]);
    gl16(vc, &Vs[buf][tid * 8]);
    gl16(vc + 1024, &Vs[buf][1024 + tid * 8]);
  };

  stage(0, 0);
  if (nchunks > 1) stage(1, 1);
  int cur = 0, nx2 = 2;
  int sw0 = (kg ^ (ln & 7)) * 8;
  int sw1 = ((4 + kg) ^ (ln & 7)) * 8;

  for (int c = 0; c < nchunks; ++c) {
    if (c + 1 < nchunks) { asm volatile("s_waitcnt vmcnt(4)" ::: "memory"); }
    else                 { asm volatile("s_waitcnt vmcnt(0)" ::: "memory"); }
    __builtin_amdgcn_s_barrier();
    __builtin_amdgcn_sched_barrier(0);
    if (c + 2 < nchunks) stage(c + 2, nx2);

    short8 k0a = *(const short8*)&Ks[cur][ln * 64 + sw0];
    short8 k0b = *(const short8*)&Ks[cur][ln * 64 + sw1];
    short8 k1a = *(const short8*)&Ks[cur][(ln + 16) * 64 + sw0];
    short8 k1b = *(const short8*)&Ks[cur][(ln + 16) * 64 + sw1];
    f32x4 s0 = {}, s1 = {};
    __builtin_amdgcn_s_setprio(1);
    s0 = __builtin_amdgcn_mfma_f32_16x16x32_bf16(k0a, qf0, s0, 0, 0, 0);
    s0 = __builtin_amdgcn_mfma_f32_16x16x32_bf16(k0b, qf1, s0, 0, 0, 0);
    s1 = __builtin_amdgcn_mfma_f32_16x16x32_bf16(k1a, qf0, s1, 0, 0, 0);
    s1 = __builtin_amdgcn_mfma_f32_16x16x32_bf16(k1b, qf1, s1, 0, 0, 0);
    __builtin_amdgcn_s_setprio(0);
    short8 vf0 = *(const short8*)&Vs[cur][ln * 32 + kg * 8];
    short8 vf1 = *(const short8*)&Vs[cur][(16 + ln) * 32 + kg * 8];
    short8 vf2 = *(const short8*)&Vs[cur][(32 + ln) * 32 + kg * 8];
    short8 vf3 = *(const short8*)&Vs[cur][(48 + ln) * 32 + kg * 8];
    if (c == qt) {                     // diagonal chunk: mask kv > q
      int kvb = c * 32 + kg * 4;
      int q = q0 + ln;
#pragma unroll
      for (int r = 0; r < 4; ++r) {
        if (kvb + r > q) s0[r] = -1e30f;
        if (kvb + 16 + r > q) s1[r] = -1e30f;
      }
    }
    // ---- online softmax with defer-max ----
    float lc = fmaxf(fmaxf(fmaxf(s0[0], s0[1]), fmaxf(s0[2], s0[3])),
                     fmaxf(fmaxf(s1[0], s1[1]), fmaxf(s1[2], s1[3])));
    if (!__all(lc <= m + 8.f)) {
      float cmax = fmaxf(lc, __shfl_xor(lc, 16));
      cmax = fmaxf(cmax, __shfl_xor(cmax, 32));
      float mnew = fmaxf(m, cmax);
      float al = __expf(m - mnew);
      m = mnew;
      lsum *= al;
#pragma unroll
      for (int dt = 0; dt < 4; ++dt) o[dt] *= al;
    }
    float p0[4], p1[4];
    float ps = 0.f;
#pragma unroll
    for (int r = 0; r < 4; ++r) {
      p0[r] = __expf(s0[r] - m);
      p1[r] = __expf(s1[r] - m);
      ps += p0[r] + p1[r];
    }
    lsum += ps;                        // lane-partial; reduced once at end
    u32 wA0, wB0, wA1, wB1;
    asm("v_cvt_pk_bf16_f32 %0, %1, %2" : "=v"(wA0) : "v"(p0[0]), "v"(p0[1]));
    asm("v_cvt_pk_bf16_f32 %0, %1, %2" : "=v"(wB0) : "v"(p0[2]), "v"(p0[3]));
    asm("v_cvt_pk_bf16_f32 %0, %1, %2" : "=v"(wA1) : "v"(p1[0]), "v"(p1[1]));
    asm("v_cvt_pk_bf16_f32 %0, %1, %2" : "=v"(wB1) : "v"(p1[2]), "v"(p1[3]));
    u32 a0 = __shfl((int)wA0, srcA), a1 = __shfl((int)wA1, srcA);
    u32 b0 = __shfl((int)wB0, srcA), b1 = __shfl((int)wB1, srcA);
    u32 c0 = __shfl((int)wA0, srcB), c1 = __shfl((int)wA1, srcB);
    u32 e0 = __shfl((int)wB0, srcB), e1 = __shfl((int)wB1, srcB);
    union { u32 u[4]; short8 s8; } pu;
    pu.u[0] = thi ? a1 : a0;           // kv rows 8kg+0,1
    pu.u[1] = thi ? b1 : b0;           // kv rows 8kg+2,3
    pu.u[2] = thi ? c1 : c0;           // kv rows 8kg+4,5
    pu.u[3] = thi ? e1 : e0;           // kv rows 8kg+6,7
    __builtin_amdgcn_s_setprio(1);
    o[0] = __builtin_amdgcn_mfma_f32_16x16x32_bf16(vf0, pu.s8, o[0], 0, 0, 0);
    o[1] = __builtin_amdgcn_mfma_f32_16x16x32_bf16(vf1, pu.s8, o[1], 0, 0, 0);
    o[2] = __builtin_amdgcn_mfma_f32_16x16x32_bf16(vf2, pu.s8, o[2], 0, 0, 0);
    o[3] = __builtin_amdgcn_mfma_f32_16x16x32_bf16(vf3, pu.s8, o[3], 0, 0, 0);
    __builtin_amdgcn_s_setprio(0);
    cur = (cur == 2) ? 0 : cur + 1;
    nx2 = (nx2 == 2) ? 0 : nx2 + 1;
  }

  // ---- final l reduction (per q-column across the 4 lane-groups) ----
  lsum += __shfl_xor(lsum, 16);
  lsum += __shfl_xor(lsum, 32);
  float inv = 1.0f / lsum;
  int q = q0 + ln;
  int b = bh >> 4, h = bh & 15;
  u16* row = AO + ((size_t)(b * L_ + q) * H_ + h) * D_;
#pragma unroll
  for (int dt = 0; dt < 4; ++dt) {
    union { u16 pk[4]; uint2 v; } u;
#pragma unroll
    for (int r = 0; r < 4; ++r) u.pk[r] = f2bf(o[dt][r] * inv);
    *(uint2*)(row + dt * 16 + kg * 4) = u.v;
  }
}

// ---------------- launch ----------------

extern "C" void kernel_launch(void* const* d_in, const int* in_sizes, int n_in,
                              void* d_out, int out_size, void* d_ws, size_t ws_size,
                              hipStream_t stream) {
  (void)in_sizes; (void)n_in; (void)out_size; (void)ws_size;
  const float* x   = (const float*)d_in[0];
  const int*   pos = (const int*)d_in[1];
  // d_in[2] = additive causal mask (we apply causal masking directly)
  const float* Wq  = (const float*)d_in[3];
  const float* Wk  = (const float*)d_in[4];
  const float* Wv  = (const float*)d_in[5];
  const float* Wo  = (const float*)d_in[6];

  char* ws = (char*)d_ws;
  u16* xbf = (u16*)ws;                        // 8 MB
  u16* Wt3 = (u16*)(ws + (size_t)( 8 << 20)); // 6 MB ([Wq|Wk|Wv]^T stacked)
  u16* Wto = (u16*)(ws + (size_t)(14 << 20)); // 2 MB
  u16* Qb  = (u16*)(ws + (size_t)(16 << 20)); // 8 MB each
  u16* Kb  = (u16*)(ws + (size_t)(24 << 20));
  u16* Vt  = (u16*)(ws + (size_t)(32 << 20)); // chunk-tiled
  u16* AO  = (u16*)(ws + (size_t)(40 << 20));
  float2* tab = (float2*)(ws + (size_t)(48 << 20)); // 512 KB

  cvt_bf16_k<<<2048, 256, 0, stream>>>(x, xbf, 4096 * 1024);
  transpose_bf_k<<<1024, 256, 0, stream>>>(Wq, Wt3);
  transpose_bf_k<<<1024, 256, 0, stream>>>(Wk, Wt3 + (size_t)1048576);
  transpose_bf_k<<<1024, 256, 0, stream>>>(Wv, Wt3 + (size_t)2097152);
  transpose_bf_k<<<1024, 256, 0, stream>>>(Wo, Wto);
  rope_tab_k<<<256, 256, 0, stream>>>(pos, tab);
  qkv_gemm_k<<<dim3(24, 32), 256, 0, stream>>>(xbf, Wt3, Qb, Kb, Vt, tab);
  attn_k<<<dim3(64, 32), 128, 0, stream>>>(Qb, Kb, Vt, AO);
  oproj_k<<<dim3(8, 64), 256, 0, stream>>>(AO, Wto, (float*)d_out);
}

// Round 12
// 176.715 us; speedup vs baseline: 1.9449x; 1.0574x over previous
//
#include <hip/hip_runtime.h>

typedef unsigned short u16;
typedef unsigned int u32;
typedef __attribute__((ext_vector_type(8))) short short8;
typedef __attribute__((ext_vector_type(4))) float f32x4;

#define H_ 16
#define L_ 2048
#define D_ 64
#define HID_ 1024

__device__ __forceinline__ u16 f2bf(float f) {
  union { float f; u32 u; } v; v.f = f;
  u32 r = v.u + 0x7FFFu + ((v.u >> 16) & 1u);
  return (u16)(r >> 16);
}

// async global->LDS, 16B per lane
__device__ __forceinline__ void gl16(const u16* g, u16* l) {
  __builtin_amdgcn_global_load_lds(
      (const __attribute__((address_space(1))) void*)g,
      (__attribute__((address_space(3))) void*)l, 16, 0, 0);
}

// ---------------- prep kernels ----------------

__global__ __launch_bounds__(256) void cvt_bf16_k(const float* __restrict__ in,
                                                  u16* __restrict__ out, int n) {
  int i = (blockIdx.x * 256 + threadIdx.x) * 8;
  if (i >= n) return;
  float4 a = *(const float4*)(in + i);
  float4 b = *(const float4*)(in + i + 4);
  u16 r[8] = { f2bf(a.x), f2bf(a.y), f2bf(a.z), f2bf(a.w),
               f2bf(b.x), f2bf(b.y), f2bf(b.z), f2bf(b.w) };
  *(uint4*)(out + i) = *(const uint4*)r;
}

// W [K=1024][N=1024] f32 -> Wt [N][K] bf16
__global__ __launch_bounds__(256) void transpose_bf_k(const float* __restrict__ in,
                                                      u16* __restrict__ out) {
  __shared__ float t[32][33];
  int bx = blockIdx.x & 31, by = blockIdx.x >> 5;
  int c = threadIdx.x & 31, r0 = threadIdx.x >> 5;
#pragma unroll
  for (int p = 0; p < 4; ++p) {
    int r = r0 + p * 8;
    t[r][c] = in[(size_t)(by * 32 + r) * 1024 + bx * 32 + c];
  }
  __syncthreads();
#pragma unroll
  for (int p = 0; p < 4; ++p) {
    int r = r0 + p * 8;
    out[(size_t)(bx * 32 + r) * 1024 + by * 32 + c] = f2bf(t[c][r]);
  }
}

// tab[l][i] = (cos, sin)(pos[l] * base^(-2i/64)),  l<2048, i<32
__global__ __launch_bounds__(256) void rope_tab_k(const int* __restrict__ pos,
                                                  float2* __restrict__ tab) {
  int gid = blockIdx.x * 256 + threadIdx.x;
  int l = gid >> 5, i = gid & 31;
  float p = (float)pos[l];
  float inv = expf(-((float)(2 * i) / 64.0f) * logf(10000.0f));
  float th = p * inv;
  tab[gid] = make_float2(cosf(th), sinf(th));
}

// ---------------- fused QKV GEMM: C = x[4096,1024] * [Wq|Wk|Wv] (N=3072) ----------------
// Counted-vmcnt pipeline (T4): 3-buffer LDS, stage(kt+2) post-barrier, vmcnt(4) not 0.

__global__ __launch_bounds__(256) void qkv_gemm_k(
    const u16* __restrict__ A, const u16* __restrict__ Bt,
    u16* __restrict__ Qo, u16* __restrict__ Ko, u16* __restrict__ Vo,
    const float2* __restrict__ rope)
{
  const int K = 1024;
  __shared__ alignas(16) u16 As[3][128][32];
  __shared__ alignas(16) u16 Bs[3][128][32];
  int tid = threadIdx.x;
  int tn = blockIdx.x, tm = blockIdx.y;
  int m0 = tm * 128, n0 = tn * 128;
  int lrow = tid >> 2, lk = (tid & 3) * 8;
  const u16* gA = A + (size_t)(m0 + lrow) * K + lk;
  const u16* gB = Bt + (size_t)(n0 + lrow) * K + lk;
  int wid = tid >> 6, lane = tid & 63, ln = lane & 15, kg = lane >> 4;
  int wm = (wid >> 1) * 64, wn = (wid & 1) * 64;
  f32x4 acc[4][4] = {};

  auto stage = [&](int kt, int buf) {
    const u16* ga = gA + kt * 32;
    gl16(ga, &As[buf][lrow][lk]);
    gl16(ga + 64 * K, &As[buf][lrow + 64][lk]);
    const u16* gb = gB + kt * 32;
    gl16(gb, &Bs[buf][lrow][lk]);
    gl16(gb + 64 * K, &Bs[buf][lrow + 64][lk]);
  };

  stage(0, 0);
  stage(1, 1);
  int cur = 0, nx2 = 2;
  for (int kt = 0; kt < 32; ++kt) {
    if (kt + 1 < 32) { asm volatile("s_waitcnt vmcnt(4)" ::: "memory"); }
    else             { asm volatile("s_waitcnt vmcnt(0)" ::: "memory"); }
    __builtin_amdgcn_s_barrier();
    __builtin_amdgcn_sched_barrier(0);
    if (kt + 2 < 32) stage(kt + 2, nx2);
    short8 af[4], bfr[4];
#pragma unroll
    for (int i = 0; i < 4; ++i) af[i] = *(const short8*)&As[cur][wm + i * 16 + ln][kg * 8];
#pragma unroll
    for (int i = 0; i < 4; ++i) bfr[i] = *(const short8*)&Bs[cur][wn + i * 16 + ln][kg * 8];
#pragma unroll
    for (int mi = 0; mi < 4; ++mi)
#pragma unroll
      for (int ni = 0; ni < 4; ++ni)
        acc[mi][ni] = __builtin_amdgcn_mfma_f32_16x16x32_bf16(af[mi], bfr[ni], acc[mi][ni], 0, 0, 0);
    cur = (cur == 2) ? 0 : cur + 1;
    nx2 = (nx2 == 2) ? 0 : nx2 + 1;
  }

  int sec = n0 >> 10;                 // 0=Q 1=K 2=V
  int col0 = (n0 & 1023) + wn;        // head-aligned 64-col wave
  int h = col0 >> 6;
  if (sec < 2) {
    u16* Out = (sec == 0) ? Qo : Ko;
    float sc = (sec == 0) ? 0.125f : 1.0f;
#pragma unroll
    for (int mi = 0; mi < 4; ++mi) {
#pragma unroll
      for (int j = 0; j < 4; ++j) {
        int mm = m0 + wm + mi * 16 + kg * 4 + j;
        int l = mm & (L_ - 1), b = mm >> 11;
        const float2* tl = rope + l * 32;
#pragma unroll
        for (int ni = 0; ni < 2; ++ni) {
          int dA = ni * 16 + ln;
          float xa = acc[mi][ni][j], xb = acc[mi][ni + 2][j];
          float2 fA = tl[dA >> 1];
          float2 fB = tl[16 + (dA >> 1)];
          float oA = (fA.x * xa - fA.y * xb) * sc;
          float oB = (fB.x * xb + fB.y * xa) * sc;
          size_t base = ((size_t)(b * H_ + h) * L_ + l) * D_;
          Out[base + dA] = f2bf(oA);
          Out[base + dA + 32] = f2bf(oB);
        }
      }
    }
  } else {
    // V -> chunk-tiled: Vo[bh][l>>5][d][l&31]
#pragma unroll
    for (int mi = 0; mi < 4; ++mi)
#pragma unroll
      for (int j = 0; j < 4; ++j) {
        int mm = m0 + wm + mi * 16 + kg * 4 + j;
        int l = mm & (L_ - 1), b = mm >> 11;
        size_t base = (size_t)(b * H_ + h) * (L_ * D_) + (size_t)(l >> 5) * 2048 + (l & 31);
#pragma unroll
        for (int ni = 0; ni < 4; ++ni) {
          int d = ni * 16 + ln;
          Vo[base + (size_t)d * 32] = f2bf(acc[mi][ni][j]);
        }
      }
  }
}

// ---------------- out-projection GEMM: 64x128 tiles, grid (8,64) = 512 blocks ----------------

__global__ __launch_bounds__(256) void oproj_k(
    const u16* __restrict__ A, const u16* __restrict__ Bt, float* __restrict__ Out)
{
  const int K = 1024;
  __shared__ alignas(16) u16 As[2][64][32];
  __shared__ alignas(16) u16 Bs[2][128][32];
  int tid = threadIdx.x;
  int tn = blockIdx.x, tm = blockIdx.y;
  int m0 = tm * 64, n0 = tn * 128;
  int lrow = tid >> 2, lk = (tid & 3) * 8;
  const u16* gA = A + (size_t)(m0 + lrow) * K + lk;
  const u16* gB = Bt + (size_t)(n0 + lrow) * K + lk;
  int wid = tid >> 6, lane = tid & 63, ln = lane & 15, kg = lane >> 4;
  int wm = (wid >> 1) * 32, wn = (wid & 1) * 64;
  f32x4 acc[2][4] = {};

  auto stage = [&](int buf, int kt) {
    gl16(gA + kt * 32, &As[buf][lrow][lk]);
    const u16* gb = gB + kt * 32;
    gl16(gb, &Bs[buf][lrow][lk]);
    gl16(gb + 64 * K, &Bs[buf][lrow + 64][lk]);
  };

  stage(0, 0);
  asm volatile("s_waitcnt vmcnt(0)" ::: "memory");
  __syncthreads();
  int cur = 0;
  for (int kt = 0; kt < 32; ++kt) {
    if (kt < 31) stage(cur ^ 1, kt + 1);
    short8 af[2], bfr[4];
#pragma unroll
    for (int i = 0; i < 2; ++i) af[i] = *(const short8*)&As[cur][wm + i * 16 + ln][kg * 8];
#pragma unroll
    for (int i = 0; i < 4; ++i) bfr[i] = *(const short8*)&Bs[cur][wn + i * 16 + ln][kg * 8];
#pragma unroll
    for (int mi = 0; mi < 2; ++mi)
#pragma unroll
      for (int ni = 0; ni < 4; ++ni)
        acc[mi][ni] = __builtin_amdgcn_mfma_f32_16x16x32_bf16(af[mi], bfr[ni], acc[mi][ni], 0, 0, 0);
    __syncthreads();
    cur ^= 1;
  }
#pragma unroll
  for (int mi = 0; mi < 2; ++mi)
#pragma unroll
    for (int j = 0; j < 4; ++j) {
      int mm = m0 + wm + mi * 16 + kg * 4 + j;
#pragma unroll
      for (int ni = 0; ni < 4; ++ni)
        Out[(size_t)mm * 1024 + n0 + wn + ni * 16 + ln] = acc[mi][ni][j];
    }
}

// ---------------- flash attention v8: 4-wave/64-q blocks for TLP + staging share ----------------
// Block = (bh, 64-q tile), 4 waves x 16 q-rows; grid (32,32) = 1024 blocks.
// 3-buffer counted-vmcnt staging (1 gl16 K + 1 gl16 V per thread per chunk; vmcnt(2)).
// Waves past their diagonal chunk (own = 2qt + wid/2) skip compute, keep barriers.
// Defer-max, lane-partial l, cvt_pk P-pack, register P^T gather (verified math).
__global__ __launch_bounds__(256) void attn_k(
    const u16* __restrict__ Q, const u16* __restrict__ K,
    const u16* __restrict__ V, u16* __restrict__ AO)
{
  __shared__ alignas(16) u16 Ks[3][2048];
  __shared__ alignas(16) u16 Vs[3][2048];
  int tid = threadIdx.x;
  int wid = tid >> 6, lane = tid & 63;
  int ln = lane & 15, kg = lane >> 4;
  int bh = blockIdx.y;
  int qt = 31 - blockIdx.x;            // heavy q-tiles dispatch first
  int q0 = qt * 64 + wid * 16;
  const u16* Qh = Q + (size_t)bh * L_ * D_;
  const u16* Kh = K + (size_t)bh * L_ * D_;
  const u16* Vt = V + (size_t)bh * L_ * D_;   // chunk-tiled [l/32][64][32]

  // staging sources (256 threads; K pre-swizzled source, linear LDS dest)
  int srow = tid >> 3, sblk = tid & 7;
  const u16* kb = Kh + (size_t)srow * 64 + ((sblk ^ (srow & 7)) << 3);
  const u16* vb = Vt + tid * 8;

  short8 qf0 = *(const short8*)(Qh + (size_t)(q0 + ln) * D_ + kg * 8);
  short8 qf1 = *(const short8*)(Qh + (size_t)(q0 + ln) * D_ + 32 + kg * 8);

  f32x4 o[4] = {};
  float m = -1e30f, lsum = 0.f;
  int srcA = ln + (((2 * kg) & 3) << 4);
  int srcB = ln + (((2 * kg + 1) & 3) << 4);
  bool thi = (kg >= 2);

  int nchunks = 2 * qt + 2;            // block-uniform trip count
  int own = 2 * qt + (wid >> 1);       // this wave's diagonal chunk

  auto stage = [&](int c, int buf) {
    gl16(kb + (size_t)c * 2048, &Ks[buf][tid * 8]);
    gl16(vb + (size_t)c * 2048, &Vs[buf][tid * 8]);
  };

  stage(0, 0);
  stage(1, 1);
  int cur = 0, nx2 = 2;
  int sw0 = (kg ^ (ln & 7)) * 8;
  int sw1 = ((4 + kg) ^ (ln & 7)) * 8;

  for (int c = 0; c < nchunks; ++c) {
    if (c + 1 < nchunks) { asm volatile("s_waitcnt vmcnt(2)" ::: "memory"); }
    else                 { asm volatile("s_waitcnt vmcnt(0)" ::: "memory"); }
    __builtin_amdgcn_s_barrier();
    __builtin_amdgcn_sched_barrier(0);
    if (c + 2 < nchunks) stage(c + 2, nx2);

    if (c <= own) {
      short8 k0a = *(const short8*)&Ks[cur][ln * 64 + sw0];
      short8 k0b = *(const short8*)&Ks[cur][ln * 64 + sw1];
      short8 k1a = *(const short8*)&Ks[cur][(ln + 16) * 64 + sw0];
      short8 k1b = *(const short8*)&Ks[cur][(ln + 16) * 64 + sw1];
      f32x4 s0 = {}, s1 = {};
      __builtin_amdgcn_s_setprio(1);
      s0 = __builtin_amdgcn_mfma_f32_16x16x32_bf16(k0a, qf0, s0, 0, 0, 0);
      s0 = __builtin_amdgcn_mfma_f32_16x16x32_bf16(k0b, qf1, s0, 0, 0, 0);
      s1 = __builtin_amdgcn_mfma_f32_16x16x32_bf16(k1a, qf0, s1, 0, 0, 0);
      s1 = __builtin_amdgcn_mfma_f32_16x16x32_bf16(k1b, qf1, s1, 0, 0, 0);
      __builtin_amdgcn_s_setprio(0);
      short8 vf0 = *(const short8*)&Vs[cur][ln * 32 + kg * 8];
      short8 vf1 = *(const short8*)&Vs[cur][(16 + ln) * 32 + kg * 8];
      short8 vf2 = *(const short8*)&Vs[cur][(32 + ln) * 32 + kg * 8];
      short8 vf3 = *(const short8*)&Vs[cur][(48 + ln) * 32 + kg * 8];
      if (c == own) {                  // diagonal chunk: mask kv > q
        int kvb = c * 32 + kg * 4;
        int q = q0 + ln;
#pragma unroll
        for (int r = 0; r < 4; ++r) {
          if (kvb + r > q) s0[r] = -1e30f;
          if (kvb + 16 + r > q) s1[r] = -1e30f;
        }
      }
      // ---- online softmax with defer-max ----
      float lc = fmaxf(fmaxf(fmaxf(s0[0], s0[1]), fmaxf(s0[2], s0[3])),
                       fmaxf(fmaxf(s1[0], s1[1]), fmaxf(s1[2], s1[3])));
      if (!__all(lc <= m + 8.f)) {
        float cmax = fmaxf(lc, __shfl_xor(lc, 16));
        cmax = fmaxf(cmax, __shfl_xor(cmax, 32));
        float mnew = fmaxf(m, cmax);
        float al = __expf(m - mnew);
        m = mnew;
        lsum *= al;
#pragma unroll
        for (int dt = 0; dt < 4; ++dt) o[dt] *= al;
      }
      float p0[4], p1[4];
      float ps = 0.f;
#pragma unroll
      for (int r = 0; r < 4; ++r) {
        p0[r] = __expf(s0[r] - m);
        p1[r] = __expf(s1[r] - m);
        ps += p0[r] + p1[r];
      }
      lsum += ps;                      // lane-partial; reduced once at end
      u32 wA0, wB0, wA1, wB1;
      asm("v_cvt_pk_bf16_f32 %0, %1, %2" : "=v"(wA0) : "v"(p0[0]), "v"(p0[1]));
      asm("v_cvt_pk_bf16_f32 %0, %1, %2" : "=v"(wB0) : "v"(p0[2]), "v"(p0[3]));
      asm("v_cvt_pk_bf16_f32 %0, %1, %2" : "=v"(wA1) : "v"(p1[0]), "v"(p1[1]));
      asm("v_cvt_pk_bf16_f32 %0, %1, %2" : "=v"(wB1) : "v"(p1[2]), "v"(p1[3]));
      u32 a0 = __shfl((int)wA0, srcA), a1 = __shfl((int)wA1, srcA);
      u32 b0 = __shfl((int)wB0, srcA), b1 = __shfl((int)wB1, srcA);
      u32 c0 = __shfl((int)wA0, srcB), c1 = __shfl((int)wA1, srcB);
      u32 e0 = __shfl((int)wB0, srcB), e1 = __shfl((int)wB1, srcB);
      union { u32 u[4]; short8 s8; } pu;
      pu.u[0] = thi ? a1 : a0;         // kv rows 8kg+0,1
      pu.u[1] = thi ? b1 : b0;         // kv rows 8kg+2,3
      pu.u[2] = thi ? c1 : c0;         // kv rows 8kg+4,5
      pu.u[3] = thi ? e1 : e0;         // kv rows 8kg+6,7
      __builtin_amdgcn_s_setprio(1);
      o[0] = __builtin_amdgcn_mfma_f32_16x16x32_bf16(vf0, pu.s8, o[0], 0, 0, 0);
      o[1] = __builtin_amdgcn_mfma_f32_16x16x32_bf16(vf1, pu.s8, o[1], 0, 0, 0);
      o[2] = __builtin_amdgcn_mfma_f32_16x16x32_bf16(vf2, pu.s8, o[2], 0, 0, 0);
      o[3] = __builtin_amdgcn_mfma_f32_16x16x32_bf16(vf3, pu.s8, o[3], 0, 0, 0);
      __builtin_amdgcn_s_setprio(0);
    }
    cur = (cur == 2) ? 0 : cur + 1;
    nx2 = (nx2 == 2) ? 0 : nx2 + 1;
  }

  // ---- final l reduction (per q-column across the 4 lane-groups) ----
  lsum += __shfl_xor(lsum, 16);
  lsum += __shfl_xor(lsum, 32);
  float inv = 1.0f / lsum;
  int q = q0 + ln;
  int b = bh >> 4, h = bh & 15;
  u16* row = AO + ((size_t)(b * L_ + q) * H_ + h) * D_;
#pragma unroll
  for (int dt = 0; dt < 4; ++dt) {
    union { u16 pk[4]; uint2 v; } u;
#pragma unroll
    for (int r = 0; r < 4; ++r) u.pk[r] = f2bf(o[dt][r] * inv);
    *(uint2*)(row + dt * 16 + kg * 4) = u.v;
  }
}

// ---------------- launch ----------------

extern "C" void kernel_launch(void* const* d_in, const int* in_sizes, int n_in,
                              void* d_out, int out_size, void* d_ws, size_t ws_size,
                              hipStream_t stream) {
  (void)in_sizes; (void)n_in; (void)out_size; (void)ws_size;
  const float* x   = (const float*)d_in[0];
  const int*   pos = (const int*)d_in[1];
  // d_in[2] = additive causal mask (we apply causal masking directly)
  const float* Wq  = (const float*)d_in[3];
  const float* Wk  = (const float*)d_in[4];
  const float* Wv  = (const float*)d_in[5];
  const float* Wo  = (const float*)d_in[6];

  char* ws = (char*)d_ws;
  u16* xbf = (u16*)ws;                        // 8 MB
  u16* Wt3 = (u16*)(ws + (size_t)( 8 << 20)); // 6 MB ([Wq|Wk|Wv]^T stacked)
  u16* Wto = (u16*)(ws + (size_t)(14 << 20)); // 2 MB
  u16* Qb  = (u16*)(ws + (size_t)(16 << 20)); // 8 MB each
  u16* Kb  = (u16*)(ws + (size_t)(24 << 20));
  u16* Vt  = (u16*)(ws + (size_t)(32 << 20)); // chunk-tiled
  u16* AO  = (u16*)(ws + (size_t)(40 << 20));
  float2* tab = (float2*)(ws + (size_t)(48 << 20)); // 512 KB

  cvt_bf16_k<<<2048, 256, 0, stream>>>(x, xbf, 4096 * 1024);
  transpose_bf_k<<<1024, 256, 0, stream>>>(Wq, Wt3);
  transpose_bf_k<<<1024, 256, 0, stream>>>(Wk, Wt3 + (size_t)1048576);
  transpose_bf_k<<<1024, 256, 0, stream>>>(Wv, Wt3 + (size_t)2097152);
  transpose_bf_k<<<1024, 256, 0, stream>>>(Wo, Wto);
  rope_tab_k<<<256, 256, 0, stream>>>(pos, tab);
  qkv_gemm_k<<<dim3(24, 32), 256, 0, stream>>>(xbf, Wt3, Qb, Kb, Vt, tab);
  attn_k<<<dim3(32, 32), 256, 0, stream>>>(Qb, Kb, Vt, AO);
  oproj_k<<<dim3(8, 64), 256, 0, stream>>>(AO, Wto, (float*)d_out);
}

// Round 14
// 173.887 us; speedup vs baseline: 1.9765x; 1.0163x over previous
//
#include <hip/hip_runtime.h>

typedef unsigned short u16;
typedef unsigned int u32;
typedef __attribute__((ext_vector_type(8))) short short8;
typedef __attribute__((ext_vector_type(4))) float f32x4;

#define H_ 16
#define L_ 2048
#define D_ 64
#define HID_ 1024

__device__ __forceinline__ u16 f2bf(float f) {
  union { float f; u32 u; } v; v.f = f;
  u32 r = v.u + 0x7FFFu + ((v.u >> 16) & 1u);
  return (u16)(r >> 16);
}

// async global->LDS, 16B per lane
__device__ __forceinline__ void gl16(const u16* g, u16* l) {
  __builtin_amdgcn_global_load_lds(
      (const __attribute__((address_space(1))) void*)g,
      (__attribute__((address_space(3))) void*)l, 16, 0, 0);
}

// ---------------- prep kernels ----------------

__global__ __launch_bounds__(256) void cvt_bf16_k(const float* __restrict__ in,
                                                  u16* __restrict__ out, int n) {
  int i = (blockIdx.x * 256 + threadIdx.x) * 8;
  if (i >= n) return;
  float4 a = *(const float4*)(in + i);
  float4 b = *(const float4*)(in + i + 4);
  u16 r[8] = { f2bf(a.x), f2bf(a.y), f2bf(a.z), f2bf(a.w),
               f2bf(b.x), f2bf(b.y), f2bf(b.z), f2bf(b.w) };
  *(uint4*)(out + i) = *(const uint4*)r;
}

// W [K=1024][N=1024] f32 -> Wt [N][K] bf16
__global__ __launch_bounds__(256) void transpose_bf_k(const float* __restrict__ in,
                                                      u16* __restrict__ out) {
  __shared__ float t[32][33];
  int bx = blockIdx.x & 31, by = blockIdx.x >> 5;
  int c = threadIdx.x & 31, r0 = threadIdx.x >> 5;
#pragma unroll
  for (int p = 0; p < 4; ++p) {
    int r = r0 + p * 8;
    t[r][c] = in[(size_t)(by * 32 + r) * 1024 + bx * 32 + c];
  }
  __syncthreads();
#pragma unroll
  for (int p = 0; p < 4; ++p) {
    int r = r0 + p * 8;
    out[(size_t)(bx * 32 + r) * 1024 + by * 32 + c] = f2bf(t[c][r]);
  }
}

// tab[l][i] = (cos, sin)(pos[l] * base^(-2i/64)),  l<2048, i<32
__global__ __launch_bounds__(256) void rope_tab_k(const int* __restrict__ pos,
                                                  float2* __restrict__ tab) {
  int gid = blockIdx.x * 256 + threadIdx.x;
  int l = gid >> 5, i = gid & 31;
  float p = (float)pos[l];
  float inv = expf(-((float)(2 * i) / 64.0f) * logf(10000.0f));
  float th = p * inv;
  tab[gid] = make_float2(cosf(th), sinf(th));
}

// ---------------- fused QKV GEMM: C = x[4096,1024] * [Wq|Wk|Wv] (N=3072) ----------------
// Counted-vmcnt pipeline (T4): 3-buffer LDS, stage(kt+2) post-barrier, vmcnt(4) not 0.

__global__ __launch_bounds__(256) void qkv_gemm_k(
    const u16* __restrict__ A, const u16* __restrict__ Bt,
    u16* __restrict__ Qo, u16* __restrict__ Ko, u16* __restrict__ Vo,
    const float2* __restrict__ rope)
{
  const int K = 1024;
  __shared__ alignas(16) u16 As[3][128][32];
  __shared__ alignas(16) u16 Bs[3][128][32];
  int tid = threadIdx.x;
  int tn = blockIdx.x, tm = blockIdx.y;
  int m0 = tm * 128, n0 = tn * 128;
  int lrow = tid >> 2, lk = (tid & 3) * 8;
  const u16* gA = A + (size_t)(m0 + lrow) * K + lk;
  const u16* gB = Bt + (size_t)(n0 + lrow) * K + lk;
  int wid = tid >> 6, lane = tid & 63, ln = lane & 15, kg = lane >> 4;
  int wm = (wid >> 1) * 64, wn = (wid & 1) * 64;
  f32x4 acc[4][4] = {};

  auto stage = [&](int kt, int buf) {
    const u16* ga = gA + kt * 32;
    gl16(ga, &As[buf][lrow][lk]);
    gl16(ga + 64 * K, &As[buf][lrow + 64][lk]);
    const u16* gb = gB + kt * 32;
    gl16(gb, &Bs[buf][lrow][lk]);
    gl16(gb + 64 * K, &Bs[buf][lrow + 64][lk]);
  };

  stage(0, 0);
  stage(1, 1);
  int cur = 0, nx2 = 2;
  for (int kt = 0; kt < 32; ++kt) {
    if (kt + 1 < 32) { asm volatile("s_waitcnt vmcnt(4)" ::: "memory"); }
    else             { asm volatile("s_waitcnt vmcnt(0)" ::: "memory"); }
    __builtin_amdgcn_s_barrier();
    __builtin_amdgcn_sched_barrier(0);
    if (kt + 2 < 32) stage(kt + 2, nx2);
    short8 af[4], bfr[4];
#pragma unroll
    for (int i = 0; i < 4; ++i) af[i] = *(const short8*)&As[cur][wm + i * 16 + ln][kg * 8];
#pragma unroll
    for (int i = 0; i < 4; ++i) bfr[i] = *(const short8*)&Bs[cur][wn + i * 16 + ln][kg * 8];
#pragma unroll
    for (int mi = 0; mi < 4; ++mi)
#pragma unroll
      for (int ni = 0; ni < 4; ++ni)
        acc[mi][ni] = __builtin_amdgcn_mfma_f32_16x16x32_bf16(af[mi], bfr[ni], acc[mi][ni], 0, 0, 0);
    cur = (cur == 2) ? 0 : cur + 1;
    nx2 = (nx2 == 2) ? 0 : nx2 + 1;
  }

  int sec = n0 >> 10;                 // 0=Q 1=K 2=V
  int col0 = (n0 & 1023) + wn;        // head-aligned 64-col wave
  int h = col0 >> 6;
  if (sec < 2) {
    u16* Out = (sec == 0) ? Qo : Ko;
    float sc = (sec == 0) ? 0.125f : 1.0f;
#pragma unroll
    for (int mi = 0; mi < 4; ++mi) {
#pragma unroll
      for (int j = 0; j < 4; ++j) {
        int mm = m0 + wm + mi * 16 + kg * 4 + j;
        int l = mm & (L_ - 1), b = mm >> 11;
        const float2* tl = rope + l * 32;
#pragma unroll
        for (int ni = 0; ni < 2; ++ni) {
          int dA = ni * 16 + ln;
          float xa = acc[mi][ni][j], xb = acc[mi][ni + 2][j];
          float2 fA = tl[dA >> 1];
          float2 fB = tl[16 + (dA >> 1)];
          float oA = (fA.x * xa - fA.y * xb) * sc;
          float oB = (fB.x * xb + fB.y * xa) * sc;
          size_t base = ((size_t)(b * H_ + h) * L_ + l) * D_;
          Out[base + dA] = f2bf(oA);
          Out[base + dA + 32] = f2bf(oB);
        }
      }
    }
  } else {
    // V -> chunk-tiled: Vo[bh][l>>5][d][l&31]
#pragma unroll
    for (int mi = 0; mi < 4; ++mi)
#pragma unroll
      for (int j = 0; j < 4; ++j) {
        int mm = m0 + wm + mi * 16 + kg * 4 + j;
        int l = mm & (L_ - 1), b = mm >> 11;
        size_t base = (size_t)(b * H_ + h) * (L_ * D_) + (size_t)(l >> 5) * 2048 + (l & 31);
#pragma unroll
        for (int ni = 0; ni < 4; ++ni) {
          int d = ni * 16 + ln;
          Vo[base + (size_t)d * 32] = f2bf(acc[mi][ni][j]);
        }
      }
  }
}

// ---------------- out-projection GEMM: 64x128 tiles, grid (8,64) = 512 blocks ----------------

__global__ __launch_bounds__(256) void oproj_k(
    const u16* __restrict__ A, const u16* __restrict__ Bt, float* __restrict__ Out)
{
  const int K = 1024;
  __shared__ alignas(16) u16 As[2][64][32];
  __shared__ alignas(16) u16 Bs[2][128][32];
  int tid = threadIdx.x;
  int tn = blockIdx.x, tm = blockIdx.y;
  int m0 = tm * 64, n0 = tn * 128;
  int lrow = tid >> 2, lk = (tid & 3) * 8;
  const u16* gA = A + (size_t)(m0 + lrow) * K + lk;
  const u16* gB = Bt + (size_t)(n0 + lrow) * K + lk;
  int wid = tid >> 6, lane = tid & 63, ln = lane & 15, kg = lane >> 4;
  int wm = (wid >> 1) * 32, wn = (wid & 1) * 64;
  f32x4 acc[2][4] = {};

  auto stage = [&](int buf, int kt) {
    gl16(gA + kt * 32, &As[buf][lrow][lk]);
    const u16* gb = gB + kt * 32;
    gl16(gb, &Bs[buf][lrow][lk]);
    gl16(gb + 64 * K, &Bs[buf][lrow + 64][lk]);
  };

  stage(0, 0);
  asm volatile("s_waitcnt vmcnt(0)" ::: "memory");
  __syncthreads();
  int cur = 0;
  for (int kt = 0; kt < 32; ++kt) {
    if (kt < 31) stage(cur ^ 1, kt + 1);
    short8 af[2], bfr[4];
#pragma unroll
    for (int i = 0; i < 2; ++i) af[i] = *(const short8*)&As[cur][wm + i * 16 + ln][kg * 8];
#pragma unroll
    for (int i = 0; i < 4; ++i) bfr[i] = *(const short8*)&Bs[cur][wn + i * 16 + ln][kg * 8];
#pragma unroll
    for (int mi = 0; mi < 2; ++mi)
#pragma unroll
      for (int ni = 0; ni < 4; ++ni)
        acc[mi][ni] = __builtin_amdgcn_mfma_f32_16x16x32_bf16(af[mi], bfr[ni], acc[mi][ni], 0, 0, 0);
    __syncthreads();
    cur ^= 1;
  }
#pragma unroll
  for (int mi = 0; mi < 2; ++mi)
#pragma unroll
    for (int j = 0; j < 4; ++j) {
      int mm = m0 + wm + mi * 16 + kg * 4 + j;
#pragma unroll
      for (int ni = 0; ni < 4; ++ni)
        Out[(size_t)mm * 1024 + n0 + wn + ni * 16 + ln] = acc[mi][ni][j];
    }
}

// ---------------- flash attention v9: 32 q/wave (2 sub-tiles), 128 q/block ----------------
// Block = (bh, 128-q tile), 4 waves x 32 q-rows; grid (16,32) = 512 blocks (2/CU).
// Per chunk: shared K/V frags (8 ds_reads) feed BOTH sub-tiles -> 16 MFMA/chunk/wave;
// sub-tile softmax chains are independent (ILP). qt pairing (by&16 ? bx : 15-bx) makes
// the two blocks per CU complementary -> constant per-CU work. Counted-vmcnt staging.
__global__ __launch_bounds__(256) void attn_k(
    const u16* __restrict__ Q, const u16* __restrict__ K,
    const u16* __restrict__ V, u16* __restrict__ AO)
{
  __shared__ alignas(16) u16 Ks[3][2048];
  __shared__ alignas(16) u16 Vs[3][2048];
  int tid = threadIdx.x;
  int wid = tid >> 6, lane = tid & 63;
  int ln = lane & 15, kg = lane >> 4;
  int bh = blockIdx.y;
  int qt = (blockIdx.y & 16) ? blockIdx.x : (15 - blockIdx.x);
  int q0 = qt * 128 + wid * 32;
  const u16* Qh = Q + (size_t)bh * L_ * D_;
  const u16* Kh = K + (size_t)bh * L_ * D_;
  const u16* Vt = V + (size_t)bh * L_ * D_;   // chunk-tiled [l/32][64][32]

  // staging sources (256 threads; K pre-swizzled source, linear LDS dest)
  int srow = tid >> 3, sblk = tid & 7;
  const u16* kb = Kh + (size_t)srow * 64 + ((sblk ^ (srow & 7)) << 3);
  const u16* vb = Vt + tid * 8;

  short8 qfA0 = *(const short8*)(Qh + (size_t)(q0 + ln) * D_ + kg * 8);
  short8 qfA1 = *(const short8*)(Qh + (size_t)(q0 + ln) * D_ + 32 + kg * 8);
  short8 qfB0 = *(const short8*)(Qh + (size_t)(q0 + 16 + ln) * D_ + kg * 8);
  short8 qfB1 = *(const short8*)(Qh + (size_t)(q0 + 16 + ln) * D_ + 32 + kg * 8);

  f32x4 oA[4] = {}, oB[4] = {};
  float mA = -1e30f, lsA = 0.f, mB = -1e30f, lsB = 0.f;
  int srcA = ln + (((2 * kg) & 3) << 4);
  int srcB = ln + (((2 * kg + 1) & 3) << 4);
  bool thi = (kg >= 2);

  int nchunks = 4 * qt + 4;            // block-uniform trip count
  int own = 4 * qt + wid;              // this wave's (single) diagonal chunk

  auto stage = [&](int c, int buf) {
    gl16(kb + (size_t)c * 2048, &Ks[buf][tid * 8]);
    gl16(vb + (size_t)c * 2048, &Vs[buf][tid * 8]);
  };

  // softmax+pack+gather+PV for one 16-q sub-tile (verified math)
  auto soft_pv = [&](f32x4 s0, f32x4 s1, float& m, float& lsum, f32x4 (&o)[4],
                     short8 vf0, short8 vf1, short8 vf2, short8 vf3) {
    float lc = fmaxf(fmaxf(fmaxf(s0[0], s0[1]), fmaxf(s0[2], s0[3])),
                     fmaxf(fmaxf(s1[0], s1[1]), fmaxf(s1[2], s1[3])));
    if (!__all(lc <= m + 8.f)) {
      float cmax = fmaxf(lc, __shfl_xor(lc, 16));
      cmax = fmaxf(cmax, __shfl_xor(cmax, 32));
      float mnew = fmaxf(m, cmax);
      float al = __expf(m - mnew);
      m = mnew;
      lsum *= al;
#pragma unroll
      for (int dt = 0; dt < 4; ++dt) o[dt] *= al;
    }
    float p0[4], p1[4];
    float ps = 0.f;
#pragma unroll
    for (int r = 0; r < 4; ++r) {
      p0[r] = __expf(s0[r] - m);
      p1[r] = __expf(s1[r] - m);
      ps += p0[r] + p1[r];
    }
    lsum += ps;
    u32 wA0, wB0, wA1, wB1;
    asm("v_cvt_pk_bf16_f32 %0, %1, %2" : "=v"(wA0) : "v"(p0[0]), "v"(p0[1]));
    asm("v_cvt_pk_bf16_f32 %0, %1, %2" : "=v"(wB0) : "v"(p0[2]), "v"(p0[3]));
    asm("v_cvt_pk_bf16_f32 %0, %1, %2" : "=v"(wA1) : "v"(p1[0]), "v"(p1[1]));
    asm("v_cvt_pk_bf16_f32 %0, %1, %2" : "=v"(wB1) : "v"(p1[2]), "v"(p1[3]));
    u32 a0 = __shfl((int)wA0, srcA), a1 = __shfl((int)wA1, srcA);
    u32 b0 = __shfl((int)wB0, srcA), b1 = __shfl((int)wB1, srcA);
    u32 c0 = __shfl((int)wA0, srcB), c1 = __shfl((int)wA1, srcB);
    u32 e0 = __shfl((int)wB0, srcB), e1 = __shfl((int)wB1, srcB);
    union { u32 u[4]; short8 s8; } pu;
    pu.u[0] = thi ? a1 : a0;           // kv rows 8kg+0,1
    pu.u[1] = thi ? b1 : b0;           // kv rows 8kg+2,3
    pu.u[2] = thi ? c1 : c0;           // kv rows 8kg+4,5
    pu.u[3] = thi ? e1 : e0;           // kv rows 8kg+6,7
    __builtin_amdgcn_s_setprio(1);
    o[0] = __builtin_amdgcn_mfma_f32_16x16x32_bf16(vf0, pu.s8, o[0], 0, 0, 0);
    o[1] = __builtin_amdgcn_mfma_f32_16x16x32_bf16(vf1, pu.s8, o[1], 0, 0, 0);
    o[2] = __builtin_amdgcn_mfma_f32_16x16x32_bf16(vf2, pu.s8, o[2], 0, 0, 0);
    o[3] = __builtin_amdgcn_mfma_f32_16x16x32_bf16(vf3, pu.s8, o[3], 0, 0, 0);
    __builtin_amdgcn_s_setprio(0);
  };

  stage(0, 0);
  stage(1, 1);
  int cur = 0, nx2 = 2;
  int sw0 = (kg ^ (ln & 7)) * 8;
  int sw1 = ((4 + kg) ^ (ln & 7)) * 8;

  for (int c = 0; c < nchunks; ++c) {
    if (c + 1 < nchunks) { asm volatile("s_waitcnt vmcnt(2)" ::: "memory"); }
    else                 { asm volatile("s_waitcnt vmcnt(0)" ::: "memory"); }
    __builtin_amdgcn_s_barrier();
    __builtin_amdgcn_sched_barrier(0);
    if (c + 2 < nchunks) stage(c + 2, nx2);

    if (c <= own) {
      short8 k0a = *(const short8*)&Ks[cur][ln * 64 + sw0];
      short8 k0b = *(const short8*)&Ks[cur][ln * 64 + sw1];
      short8 k1a = *(const short8*)&Ks[cur][(ln + 16) * 64 + sw0];
      short8 k1b = *(const short8*)&Ks[cur][(ln + 16) * 64 + sw1];
      short8 vf0 = *(const short8*)&Vs[cur][ln * 32 + kg * 8];
      short8 vf1 = *(const short8*)&Vs[cur][(16 + ln) * 32 + kg * 8];
      short8 vf2 = *(const short8*)&Vs[cur][(32 + ln) * 32 + kg * 8];
      short8 vf3 = *(const short8*)&Vs[cur][(48 + ln) * 32 + kg * 8];
      f32x4 sA0 = {}, sA1 = {}, sB0 = {}, sB1 = {};
      __builtin_amdgcn_s_setprio(1);
      sA0 = __builtin_amdgcn_mfma_f32_16x16x32_bf16(k0a, qfA0, sA0, 0, 0, 0);
      sA0 = __builtin_amdgcn_mfma_f32_16x16x32_bf16(k0b, qfA1, sA0, 0, 0, 0);
      sA1 = __builtin_amdgcn_mfma_f32_16x16x32_bf16(k1a, qfA0, sA1, 0, 0, 0);
      sA1 = __builtin_amdgcn_mfma_f32_16x16x32_bf16(k1b, qfA1, sA1, 0, 0, 0);
      sB0 = __builtin_amdgcn_mfma_f32_16x16x32_bf16(k0a, qfB0, sB0, 0, 0, 0);
      sB0 = __builtin_amdgcn_mfma_f32_16x16x32_bf16(k0b, qfB1, sB0, 0, 0, 0);
      sB1 = __builtin_amdgcn_mfma_f32_16x16x32_bf16(k1a, qfB0, sB1, 0, 0, 0);
      sB1 = __builtin_amdgcn_mfma_f32_16x16x32_bf16(k1b, qfB1, sB1, 0, 0, 0);
      __builtin_amdgcn_s_setprio(0);
      if (c == own) {
        // sub A (q_local = ln): s0 diag, s1 all dead (kv 16..31 > q 0..15)
        // sub B (q_local = 16+ln): s0 full, s1 diag
#pragma unroll
        for (int r = 0; r < 4; ++r) {
          if (kg * 4 + r > ln) { sA0[r] = -1e30f; sB1[r] = -1e30f; }
          sA1[r] = -1e30f;
        }
      }
      soft_pv(sA0, sA1, mA, lsA, oA, vf0, vf1, vf2, vf3);
      soft_pv(sB0, sB1, mB, lsB, oB, vf0, vf1, vf2, vf3);
    }
    cur = (cur == 2) ? 0 : cur + 1;
    nx2 = (nx2 == 2) ? 0 : nx2 + 1;
  }

  // ---- final l reduction + store, both sub-tiles ----
  int b = bh >> 4, h = bh & 15;
  lsA += __shfl_xor(lsA, 16);
  lsA += __shfl_xor(lsA, 32);
  lsB += __shfl_xor(lsB, 16);
  lsB += __shfl_xor(lsB, 32);
  float invA = 1.0f / lsA, invB = 1.0f / lsB;
  u16* rowA = AO + ((size_t)(b * L_ + q0 + ln) * H_ + h) * D_;
  u16* rowB = AO + ((size_t)(b * L_ + q0 + 16 + ln) * H_ + h) * D_;
#pragma unroll
  for (int dt = 0; dt < 4; ++dt) {
    union { u16 pk[4]; uint2 v; } uA, uB;
#pragma unroll
    for (int r = 0; r < 4; ++r) {
      uA.pk[r] = f2bf(oA[dt][r] * invA);
      uB.pk[r] = f2bf(oB[dt][r] * invB);
    }
    *(uint2*)(rowA + dt * 16 + kg * 4) = uA.v;
    *(uint2*)(rowB + dt * 16 + kg * 4) = uB.v;
  }
}

// ---------------- launch ----------------

extern "C" void kernel_launch(void* const* d_in, const int* in_sizes, int n_in,
                              void* d_out, int out_size, void* d_ws, size_t ws_size,
                              hipStream_t stream) {
  (void)in_sizes; (void)n_in; (void)out_size; (void)ws_size;
  const float* x   = (const float*)d_in[0];
  const int*   pos = (const int*)d_in[1];
  // d_in[2] = additive causal mask (we apply causal masking directly)
  const float* Wq  = (const float*)d_in[3];
  const float* Wk  = (const float*)d_in[4];
  const float* Wv  = (const float*)d_in[5];
  const float* Wo  = (const float*)d_in[6];

  char* ws = (char*)d_ws;
  u16* xbf = (u16*)ws;                        // 8 MB
  u16* Wt3 = (u16*)(ws + (size_t)( 8 << 20)); // 6 MB ([Wq|Wk|Wv]^T stacked)
  u16* Wto = (u16*)(ws + (size_t)(14 << 20)); // 2 MB
  u16* Qb  = (u16*)(ws + (size_t)(16 << 20)); // 8 MB each
  u16* Kb  = (u16*)(ws + (size_t)(24 << 20));
  u16* Vt  = (u16*)(ws + (size_t)(32 << 20)); // chunk-tiled
  u16* AO  = (u16*)(ws + (size_t)(40 << 20));
  float2* tab = (float2*)(ws + (size_t)(48 << 20)); // 512 KB

  cvt_bf16_k<<<2048, 256, 0, stream>>>(x, xbf, 4096 * 1024);
  transpose_bf_k<<<1024, 256, 0, stream>>>(Wq, Wt3);
  transpose_bf_k<<<1024, 256, 0, stream>>>(Wk, Wt3 + (size_t)1048576);
  transpose_bf_k<<<1024, 256, 0, stream>>>(Wv, Wt3 + (size_t)2097152);
  transpose_bf_k<<<1024, 256, 0, stream>>>(Wo, Wto);
  rope_tab_k<<<256, 256, 0, stream>>>(pos, tab);
  qkv_gemm_k<<<dim3(24, 32), 256, 0, stream>>>(xbf, Wt3, Qb, Kb, Vt, tab);
  attn_k<<<dim3(16, 32), 256, 0, stream>>>(Qb, Kb, Vt, AO);
  oproj_k<<<dim3(8, 64), 256, 0, stream>>>(AO, Wto, (float*)d_out);
}

// Round 15
// 167.712 us; speedup vs baseline: 2.0493x; 1.0368x over previous
//
#include <hip/hip_runtime.h>

typedef unsigned short u16;
typedef unsigned int u32;
typedef __attribute__((ext_vector_type(8))) short short8;
typedef __attribute__((ext_vector_type(4))) float f32x4;

#define H_ 16
#define L_ 2048
#define D_ 64
#define HID_ 1024

__device__ __forceinline__ u16 f2bf(float f) {
  union { float f; u32 u; } v; v.f = f;
  u32 r = v.u + 0x7FFFu + ((v.u >> 16) & 1u);
  return (u16)(r >> 16);
}

// async global->LDS, 16B per lane
__device__ __forceinline__ void gl16(const u16* g, u16* l) {
  __builtin_amdgcn_global_load_lds(
      (const __attribute__((address_space(1))) void*)g,
      (__attribute__((address_space(3))) void*)l, 16, 0, 0);
}

// ---------------- prep kernels ----------------

__global__ __launch_bounds__(256) void cvt_bf16_k(const float* __restrict__ in,
                                                  u16* __restrict__ out, int n) {
  int i = (blockIdx.x * 256 + threadIdx.x) * 8;
  if (i >= n) return;
  float4 a = *(const float4*)(in + i);
  float4 b = *(const float4*)(in + i + 4);
  u16 r[8] = { f2bf(a.x), f2bf(a.y), f2bf(a.z), f2bf(a.w),
               f2bf(b.x), f2bf(b.y), f2bf(b.z), f2bf(b.w) };
  *(uint4*)(out + i) = *(const uint4*)r;
}

// 4x fused: W [K=1024][N=1024] f32 -> Wt [N][K] bf16
__global__ __launch_bounds__(256) void transpose4_bf_k(
    const float* __restrict__ s0, const float* __restrict__ s1,
    const float* __restrict__ s2, const float* __restrict__ s3,
    u16* __restrict__ d0, u16* __restrict__ d1,
    u16* __restrict__ d2, u16* __restrict__ d3)
{
  __shared__ float t[32][33];
  int w = blockIdx.y;
  const float* in = (w == 0) ? s0 : (w == 1) ? s1 : (w == 2) ? s2 : s3;
  u16* out = (w == 0) ? d0 : (w == 1) ? d1 : (w == 2) ? d2 : d3;
  int bx = blockIdx.x & 31, by = blockIdx.x >> 5;
  int c = threadIdx.x & 31, r0 = threadIdx.x >> 5;
#pragma unroll
  for (int p = 0; p < 4; ++p) {
    int r = r0 + p * 8;
    t[r][c] = in[(size_t)(by * 32 + r) * 1024 + bx * 32 + c];
  }
  __syncthreads();
#pragma unroll
  for (int p = 0; p < 4; ++p) {
    int r = r0 + p * 8;
    out[(size_t)(bx * 32 + r) * 1024 + by * 32 + c] = f2bf(t[c][r]);
  }
}

// tab[l][i] = (cos, sin)(pos[l] * base^(-2i/64)),  l<2048, i<32
__global__ __launch_bounds__(256) void rope_tab_k(const int* __restrict__ pos,
                                                  float2* __restrict__ tab) {
  int gid = blockIdx.x * 256 + threadIdx.x;
  int l = gid >> 5, i = gid & 31;
  float p = (float)pos[l];
  float inv = expf(-((float)(2 * i) / 64.0f) * logf(10000.0f));
  float th = p * inv;
  tab[gid] = make_float2(cosf(th), sinf(th));
}

// ---------------- fused QKV GEMM: C = x[4096,1024] * [Wq|Wk|Wv] (N=3072) ----------------
// Counted-vmcnt pipeline (T4): 3-buffer LDS, stage(kt+2) post-barrier, vmcnt(4) not 0.

__global__ __launch_bounds__(256) void qkv_gemm_k(
    const u16* __restrict__ A, const u16* __restrict__ Bt,
    u16* __restrict__ Qo, u16* __restrict__ Ko, u16* __restrict__ Vo,
    const float2* __restrict__ rope)
{
  const int K = 1024;
  __shared__ alignas(16) u16 As[3][128][32];
  __shared__ alignas(16) u16 Bs[3][128][32];
  int tid = threadIdx.x;
  int tn = blockIdx.x, tm = blockIdx.y;
  int m0 = tm * 128, n0 = tn * 128;
  int lrow = tid >> 2, lk = (tid & 3) * 8;
  const u16* gA = A + (size_t)(m0 + lrow) * K + lk;
  const u16* gB = Bt + (size_t)(n0 + lrow) * K + lk;
  int wid = tid >> 6, lane = tid & 63, ln = lane & 15, kg = lane >> 4;
  int wm = (wid >> 1) * 64, wn = (wid & 1) * 64;
  f32x4 acc[4][4] = {};

  auto stage = [&](int kt, int buf) {
    const u16* ga = gA + kt * 32;
    gl16(ga, &As[buf][lrow][lk]);
    gl16(ga + 64 * K, &As[buf][lrow + 64][lk]);
    const u16* gb = gB + kt * 32;
    gl16(gb, &Bs[buf][lrow][lk]);
    gl16(gb + 64 * K, &Bs[buf][lrow + 64][lk]);
  };

  stage(0, 0);
  stage(1, 1);
  int cur = 0, nx2 = 2;
  for (int kt = 0; kt < 32; ++kt) {
    if (kt + 1 < 32) { asm volatile("s_waitcnt vmcnt(4)" ::: "memory"); }
    else             { asm volatile("s_waitcnt vmcnt(0)" ::: "memory"); }
    __builtin_amdgcn_s_barrier();
    __builtin_amdgcn_sched_barrier(0);
    if (kt + 2 < 32) stage(kt + 2, nx2);
    short8 af[4], bfr[4];
#pragma unroll
    for (int i = 0; i < 4; ++i) af[i] = *(const short8*)&As[cur][wm + i * 16 + ln][kg * 8];
#pragma unroll
    for (int i = 0; i < 4; ++i) bfr[i] = *(const short8*)&Bs[cur][wn + i * 16 + ln][kg * 8];
#pragma unroll
    for (int mi = 0; mi < 4; ++mi)
#pragma unroll
      for (int ni = 0; ni < 4; ++ni)
        acc[mi][ni] = __builtin_amdgcn_mfma_f32_16x16x32_bf16(af[mi], bfr[ni], acc[mi][ni], 0, 0, 0);
    cur = (cur == 2) ? 0 : cur + 1;
    nx2 = (nx2 == 2) ? 0 : nx2 + 1;
  }

  int sec = n0 >> 10;                 // 0=Q 1=K 2=V
  int col0 = (n0 & 1023) + wn;        // head-aligned 64-col wave
  int h = col0 >> 6;
  if (sec < 2) {
    u16* Out = (sec == 0) ? Qo : Ko;
    float sc = (sec == 0) ? 0.125f : 1.0f;
#pragma unroll
    for (int mi = 0; mi < 4; ++mi) {
#pragma unroll
      for (int j = 0; j < 4; ++j) {
        int mm = m0 + wm + mi * 16 + kg * 4 + j;
        int l = mm & (L_ - 1), b = mm >> 11;
        const float2* tl = rope + l * 32;
#pragma unroll
        for (int ni = 0; ni < 2; ++ni) {
          int dA = ni * 16 + ln;
          float xa = acc[mi][ni][j], xb = acc[mi][ni + 2][j];
          float2 fA = tl[dA >> 1];
          float2 fB = tl[16 + (dA >> 1)];
          float oA = (fA.x * xa - fA.y * xb) * sc;
          float oB = (fB.x * xb + fB.y * xa) * sc;
          size_t base = ((size_t)(b * H_ + h) * L_ + l) * D_;
          Out[base + dA] = f2bf(oA);
          Out[base + dA + 32] = f2bf(oB);
        }
      }
    }
  } else {
    // V -> chunk-tiled: Vo[bh][l>>5][d][l&31]
#pragma unroll
    for (int mi = 0; mi < 4; ++mi)
#pragma unroll
      for (int j = 0; j < 4; ++j) {
        int mm = m0 + wm + mi * 16 + kg * 4 + j;
        int l = mm & (L_ - 1), b = mm >> 11;
        size_t base = (size_t)(b * H_ + h) * (L_ * D_) + (size_t)(l >> 5) * 2048 + (l & 31);
#pragma unroll
        for (int ni = 0; ni < 4; ++ni) {
          int d = ni * 16 + ln;
          Vo[base + (size_t)d * 32] = f2bf(acc[mi][ni][j]);
        }
      }
  }
}

// ---------------- out-projection GEMM: 64x128 tiles, grid (8,64) = 512 blocks ----------------

__global__ __launch_bounds__(256) void oproj_k(
    const u16* __restrict__ A, const u16* __restrict__ Bt, float* __restrict__ Out)
{
  const int K = 1024;
  __shared__ alignas(16) u16 As[2][64][32];
  __shared__ alignas(16) u16 Bs[2][128][32];
  int tid = threadIdx.x;
  int tn = blockIdx.x, tm = blockIdx.y;
  int m0 = tm * 64, n0 = tn * 128;
  int lrow = tid >> 2, lk = (tid & 3) * 8;
  const u16* gA = A + (size_t)(m0 + lrow) * K + lk;
  const u16* gB = Bt + (size_t)(n0 + lrow) * K + lk;
  int wid = tid >> 6, lane = tid & 63, ln = lane & 15, kg = lane >> 4;
  int wm = (wid >> 1) * 32, wn = (wid & 1) * 64;
  f32x4 acc[2][4] = {};

  auto stage = [&](int buf, int kt) {
    gl16(gA + kt * 32, &As[buf][lrow][lk]);
    const u16* gb = gB + kt * 32;
    gl16(gb, &Bs[buf][lrow][lk]);
    gl16(gb + 64 * K, &Bs[buf][lrow + 64][lk]);
  };

  stage(0, 0);
  asm volatile("s_waitcnt vmcnt(0)" ::: "memory");
  __syncthreads();
  int cur = 0;
  for (int kt = 0; kt < 32; ++kt) {
    if (kt < 31) stage(cur ^ 1, kt + 1);
    short8 af[2], bfr[4];
#pragma unroll
    for (int i = 0; i < 2; ++i) af[i] = *(const short8*)&As[cur][wm + i * 16 + ln][kg * 8];
#pragma unroll
    for (int i = 0; i < 4; ++i) bfr[i] = *(const short8*)&Bs[cur][wn + i * 16 + ln][kg * 8];
#pragma unroll
    for (int mi = 0; mi < 2; ++mi)
#pragma unroll
      for (int ni = 0; ni < 4; ++ni)
        acc[mi][ni] = __builtin_amdgcn_mfma_f32_16x16x32_bf16(af[mi], bfr[ni], acc[mi][ni], 0, 0, 0);
    __syncthreads();
    cur ^= 1;
  }
#pragma unroll
  for (int mi = 0; mi < 2; ++mi)
#pragma unroll
    for (int j = 0; j < 4; ++j) {
      int mm = m0 + wm + mi * 16 + kg * 4 + j;
#pragma unroll
      for (int ni = 0; ni < 4; ++ni)
        Out[(size_t)mm * 1024 + n0 + wn + ni * 16 + ln] = acc[mi][ni][j];
    }
}

// ---------------- flash attention v10: deep (4-chunk) prefetch pipeline ----------------
// Block = (bh, 128-q tile), 4 waves x 32 q-rows (2 sub-tiles); grid (16,32), 2 blocks/CU.
// 6 LDS buffers (48 KB); stage(c+4) issued post-barrier; steady-state vmcnt(6) keeps
// stages c+1..c+3 in flight -> covers L3/HBM staging latency (~900cy) with ~4 chunk-times.
// qt pairing keeps per-CU work constant. Verified softmax/P^T-gather/PV math unchanged.
__global__ __launch_bounds__(256) void attn_k(
    const u16* __restrict__ Q, const u16* __restrict__ K,
    const u16* __restrict__ V, u16* __restrict__ AO)
{
  __shared__ alignas(16) u16 Ks[6][2048];
  __shared__ alignas(16) u16 Vs[6][2048];
  int tid = threadIdx.x;
  int wid = tid >> 6, lane = tid & 63;
  int ln = lane & 15, kg = lane >> 4;
  int bh = blockIdx.y;
  int qt = (blockIdx.y & 16) ? blockIdx.x : (15 - blockIdx.x);
  int q0 = qt * 128 + wid * 32;
  const u16* Qh = Q + (size_t)bh * L_ * D_;
  const u16* Kh = K + (size_t)bh * L_ * D_;
  const u16* Vt = V + (size_t)bh * L_ * D_;   // chunk-tiled [l/32][64][32]

  // staging sources (256 threads; K pre-swizzled source, linear LDS dest)
  int srow = tid >> 3, sblk = tid & 7;
  const u16* kb = Kh + (size_t)srow * 64 + ((sblk ^ (srow & 7)) << 3);
  const u16* vb = Vt + tid * 8;

  short8 qfA0 = *(const short8*)(Qh + (size_t)(q0 + ln) * D_ + kg * 8);
  short8 qfA1 = *(const short8*)(Qh + (size_t)(q0 + ln) * D_ + 32 + kg * 8);
  short8 qfB0 = *(const short8*)(Qh + (size_t)(q0 + 16 + ln) * D_ + kg * 8);
  short8 qfB1 = *(const short8*)(Qh + (size_t)(q0 + 16 + ln) * D_ + 32 + kg * 8);

  f32x4 oA[4] = {}, oB[4] = {};
  float mA = -1e30f, lsA = 0.f, mB = -1e30f, lsB = 0.f;
  int srcA = ln + (((2 * kg) & 3) << 4);
  int srcB = ln + (((2 * kg + 1) & 3) << 4);
  bool thi = (kg >= 2);

  int nch = 4 * qt + 4;                // block-uniform trip count (>= 4)
  int own = 4 * qt + wid;              // this wave's (single) diagonal chunk

  auto stage = [&](int c, int buf) {
    gl16(kb + (size_t)c * 2048, &Ks[buf][tid * 8]);
    gl16(vb + (size_t)c * 2048, &Vs[buf][tid * 8]);
  };

  // softmax+pack+gather+PV for one 16-q sub-tile (verified math)
  auto soft_pv = [&](f32x4 s0, f32x4 s1, float& m, float& lsum, f32x4 (&o)[4],
                     short8 vf0, short8 vf1, short8 vf2, short8 vf3) {
    float lc = fmaxf(fmaxf(fmaxf(s0[0], s0[1]), fmaxf(s0[2], s0[3])),
                     fmaxf(fmaxf(s1[0], s1[1]), fmaxf(s1[2], s1[3])));
    if (!__all(lc <= m + 8.f)) {
      float cmax = fmaxf(lc, __shfl_xor(lc, 16));
      cmax = fmaxf(cmax, __shfl_xor(cmax, 32));
      float mnew = fmaxf(m, cmax);
      float al = __expf(m - mnew);
      m = mnew;
      lsum *= al;
#pragma unroll
      for (int dt = 0; dt < 4; ++dt) o[dt] *= al;
    }
    float p0[4], p1[4];
    float ps = 0.f;
#pragma unroll
    for (int r = 0; r < 4; ++r) {
      p0[r] = __expf(s0[r] - m);
      p1[r] = __expf(s1[r] - m);
      ps += p0[r] + p1[r];
    }
    lsum += ps;
    u32 wA0, wB0, wA1, wB1;
    asm("v_cvt_pk_bf16_f32 %0, %1, %2" : "=v"(wA0) : "v"(p0[0]), "v"(p0[1]));
    asm("v_cvt_pk_bf16_f32 %0, %1, %2" : "=v"(wB0) : "v"(p0[2]), "v"(p0[3]));
    asm("v_cvt_pk_bf16_f32 %0, %1, %2" : "=v"(wA1) : "v"(p1[0]), "v"(p1[1]));
    asm("v_cvt_pk_bf16_f32 %0, %1, %2" : "=v"(wB1) : "v"(p1[2]), "v"(p1[3]));
    u32 a0 = __shfl((int)wA0, srcA), a1 = __shfl((int)wA1, srcA);
    u32 b0 = __shfl((int)wB0, srcA), b1 = __shfl((int)wB1, srcA);
    u32 c0 = __shfl((int)wA0, srcB), c1 = __shfl((int)wA1, srcB);
    u32 e0 = __shfl((int)wB0, srcB), e1 = __shfl((int)wB1, srcB);
    union { u32 u[4]; short8 s8; } pu;
    pu.u[0] = thi ? a1 : a0;           // kv rows 8kg+0,1
    pu.u[1] = thi ? b1 : b0;           // kv rows 8kg+2,3
    pu.u[2] = thi ? c1 : c0;           // kv rows 8kg+4,5
    pu.u[3] = thi ? e1 : e0;           // kv rows 8kg+6,7
    __builtin_amdgcn_s_setprio(1);
    o[0] = __builtin_amdgcn_mfma_f32_16x16x32_bf16(vf0, pu.s8, o[0], 0, 0, 0);
    o[1] = __builtin_amdgcn_mfma_f32_16x16x32_bf16(vf1, pu.s8, o[1], 0, 0, 0);
    o[2] = __builtin_amdgcn_mfma_f32_16x16x32_bf16(vf2, pu.s8, o[2], 0, 0, 0);
    o[3] = __builtin_amdgcn_mfma_f32_16x16x32_bf16(vf3, pu.s8, o[3], 0, 0, 0);
    __builtin_amdgcn_s_setprio(0);
  };

  // prologue: 4 chunks in flight (nch >= 4 always)
  stage(0, 0); stage(1, 1); stage(2, 2); stage(3, 3);
  int cur = 0, nxt = 4;
  int sw0 = (kg ^ (ln & 7)) * 8;
  int sw1 = ((4 + kg) ^ (ln & 7)) * 8;

  for (int c = 0; c < nch; ++c) {
    if (c + 3 < nch)      { asm volatile("s_waitcnt vmcnt(6)" ::: "memory"); }
    else if (c + 2 < nch) { asm volatile("s_waitcnt vmcnt(4)" ::: "memory"); }
    else if (c + 1 < nch) { asm volatile("s_waitcnt vmcnt(2)" ::: "memory"); }
    else                  { asm volatile("s_waitcnt vmcnt(0)" ::: "memory"); }
    __builtin_amdgcn_s_barrier();
    __builtin_amdgcn_sched_barrier(0);
    if (c + 4 < nch) stage(c + 4, nxt);

    if (c <= own) {
      short8 k0a = *(const short8*)&Ks[cur][ln * 64 + sw0];
      short8 k0b = *(const short8*)&Ks[cur][ln * 64 + sw1];
      short8 k1a = *(const short8*)&Ks[cur][(ln + 16) * 64 + sw0];
      short8 k1b = *(const short8*)&Ks[cur][(ln + 16) * 64 + sw1];
      short8 vf0 = *(const short8*)&Vs[cur][ln * 32 + kg * 8];
      short8 vf1 = *(const short8*)&Vs[cur][(16 + ln) * 32 + kg * 8];
      short8 vf2 = *(const short8*)&Vs[cur][(32 + ln) * 32 + kg * 8];
      short8 vf3 = *(const short8*)&Vs[cur][(48 + ln) * 32 + kg * 8];
      f32x4 sA0 = {}, sA1 = {}, sB0 = {}, sB1 = {};
      __builtin_amdgcn_s_setprio(1);
      sA0 = __builtin_amdgcn_mfma_f32_16x16x32_bf16(k0a, qfA0, sA0, 0, 0, 0);
      sA0 = __builtin_amdgcn_mfma_f32_16x16x32_bf16(k0b, qfA1, sA0, 0, 0, 0);
      sA1 = __builtin_amdgcn_mfma_f32_16x16x32_bf16(k1a, qfA0, sA1, 0, 0, 0);
      sA1 = __builtin_amdgcn_mfma_f32_16x16x32_bf16(k1b, qfA1, sA1, 0, 0, 0);
      sB0 = __builtin_amdgcn_mfma_f32_16x16x32_bf16(k0a, qfB0, sB0, 0, 0, 0);
      sB0 = __builtin_amdgcn_mfma_f32_16x16x32_bf16(k0b, qfB1, sB0, 0, 0, 0);
      sB1 = __builtin_amdgcn_mfma_f32_16x16x32_bf16(k1a, qfB0, sB1, 0, 0, 0);
      sB1 = __builtin_amdgcn_mfma_f32_16x16x32_bf16(k1b, qfB1, sB1, 0, 0, 0);
      __builtin_amdgcn_s_setprio(0);
      if (c == own) {
        // sub A (q_local = ln): s0 diag, s1 all dead (kv 16..31 > q 0..15)
        // sub B (q_local = 16+ln): s0 full, s1 diag
#pragma unroll
        for (int r = 0; r < 4; ++r) {
          if (kg * 4 + r > ln) { sA0[r] = -1e30f; sB1[r] = -1e30f; }
          sA1[r] = -1e30f;
        }
      }
      soft_pv(sA0, sA1, mA, lsA, oA, vf0, vf1, vf2, vf3);
      soft_pv(sB0, sB1, mB, lsB, oB, vf0, vf1, vf2, vf3);
    }
    cur = (cur == 5) ? 0 : cur + 1;
    nxt = (nxt == 5) ? 0 : nxt + 1;
  }

  // ---- final l reduction + store, both sub-tiles ----
  int b = bh >> 4, h = bh & 15;
  lsA += __shfl_xor(lsA, 16);
  lsA += __shfl_xor(lsA, 32);
  lsB += __shfl_xor(lsB, 16);
  lsB += __shfl_xor(lsB, 32);
  float invA = 1.0f / lsA, invB = 1.0f / lsB;
  u16* rowA = AO + ((size_t)(b * L_ + q0 + ln) * H_ + h) * D_;
  u16* rowB = AO + ((size_t)(b * L_ + q0 + 16 + ln) * H_ + h) * D_;
#pragma unroll
  for (int dt = 0; dt < 4; ++dt) {
    union { u16 pk[4]; uint2 v; } uA, uB;
#pragma unroll
    for (int r = 0; r < 4; ++r) {
      uA.pk[r] = f2bf(oA[dt][r] * invA);
      uB.pk[r] = f2bf(oB[dt][r] * invB);
    }
    *(uint2*)(rowA + dt * 16 + kg * 4) = uA.v;
    *(uint2*)(rowB + dt * 16 + kg * 4) = uB.v;
  }
}

// ---------------- launch ----------------

extern "C" void kernel_launch(void* const* d_in, const int* in_sizes, int n_in,
                              void* d_out, int out_size, void* d_ws, size_t ws_size,
                              hipStream_t stream) {
  (void)in_sizes; (void)n_in; (void)out_size; (void)ws_size;
  const float* x   = (const float*)d_in[0];
  const int*   pos = (const int*)d_in[1];
  // d_in[2] = additive causal mask (we apply causal masking directly)
  const float* Wq  = (const float*)d_in[3];
  const float* Wk  = (const float*)d_in[4];
  const float* Wv  = (const float*)d_in[5];
  const float* Wo  = (const float*)d_in[6];

  char* ws = (char*)d_ws;
  u16* xbf = (u16*)ws;                        // 8 MB
  u16* Wt3 = (u16*)(ws + (size_t)( 8 << 20)); // 6 MB ([Wq|Wk|Wv]^T stacked)
  u16* Wto = (u16*)(ws + (size_t)(14 << 20)); // 2 MB
  u16* Qb  = (u16*)(ws + (size_t)(16 << 20)); // 8 MB each
  u16* Kb  = (u16*)(ws + (size_t)(24 << 20));
  u16* Vt  = (u16*)(ws + (size_t)(32 << 20)); // chunk-tiled
  u16* AO  = (u16*)(ws + (size_t)(40 << 20));
  float2* tab = (float2*)(ws + (size_t)(48 << 20)); // 512 KB

  cvt_bf16_k<<<2048, 256, 0, stream>>>(x, xbf, 4096 * 1024);
  transpose4_bf_k<<<dim3(1024, 4), 256, 0, stream>>>(
      Wq, Wk, Wv, Wo, Wt3, Wt3 + (size_t)1048576, Wt3 + (size_t)2097152, Wto);
  rope_tab_k<<<256, 256, 0, stream>>>(pos, tab);
  qkv_gemm_k<<<dim3(24, 32), 256, 0, stream>>>(xbf, Wt3, Qb, Kb, Vt, tab);
  attn_k<<<dim3(16, 32), 256, 0, stream>>>(Qb, Kb, Vt, AO);
  oproj_k<<<dim3(8, 64), 256, 0, stream>>>(AO, Wto, (float*)d_out);
}

// Round 16
// 164.282 us; speedup vs baseline: 2.0921x; 1.0209x over previous
//
#include <hip/hip_runtime.h>

typedef unsigned short u16;
typedef unsigned int u32;
typedef __attribute__((ext_vector_type(8))) short short8;
typedef __attribute__((ext_vector_type(4))) float f32x4;

#define H_ 16
#define L_ 2048
#define D_ 64
#define HID_ 1024

__device__ __forceinline__ u16 f2bf(float f) {
  union { float f; u32 u; } v; v.f = f;
  u32 r = v.u + 0x7FFFu + ((v.u >> 16) & 1u);
  return (u16)(r >> 16);
}

// async global->LDS, 16B per lane
__device__ __forceinline__ void gl16(const u16* g, u16* l) {
  __builtin_amdgcn_global_load_lds(
      (const __attribute__((address_space(1))) void*)g,
      (__attribute__((address_space(3))) void*)l, 16, 0, 0);
}

// ---------------- prep kernels ----------------

__global__ __launch_bounds__(256) void cvt_bf16_k(const float* __restrict__ in,
                                                  u16* __restrict__ out, int n) {
  int i = (blockIdx.x * 256 + threadIdx.x) * 8;
  if (i >= n) return;
  float4 a = *(const float4*)(in + i);
  float4 b = *(const float4*)(in + i + 4);
  u16 r[8] = { f2bf(a.x), f2bf(a.y), f2bf(a.z), f2bf(a.w),
               f2bf(b.x), f2bf(b.y), f2bf(b.z), f2bf(b.w) };
  *(uint4*)(out + i) = *(const uint4*)r;
}

// 4x fused: W [K=1024][N=1024] f32 -> Wt [N][K] bf16
__global__ __launch_bounds__(256) void transpose4_bf_k(
    const float* __restrict__ s0, const float* __restrict__ s1,
    const float* __restrict__ s2, const float* __restrict__ s3,
    u16* __restrict__ d0, u16* __restrict__ d1,
    u16* __restrict__ d2, u16* __restrict__ d3)
{
  __shared__ float t[32][33];
  int w = blockIdx.y;
  const float* in = (w == 0) ? s0 : (w == 1) ? s1 : (w == 2) ? s2 : s3;
  u16* out = (w == 0) ? d0 : (w == 1) ? d1 : (w == 2) ? d2 : d3;
  int bx = blockIdx.x & 31, by = blockIdx.x >> 5;
  int c = threadIdx.x & 31, r0 = threadIdx.x >> 5;
#pragma unroll
  for (int p = 0; p < 4; ++p) {
    int r = r0 + p * 8;
    t[r][c] = in[(size_t)(by * 32 + r) * 1024 + bx * 32 + c];
  }
  __syncthreads();
#pragma unroll
  for (int p = 0; p < 4; ++p) {
    int r = r0 + p * 8;
    out[(size_t)(bx * 32 + r) * 1024 + by * 32 + c] = f2bf(t[c][r]);
  }
}

// tab[l][i] = (cos, sin)(pos[l] * base^(-2i/64)),  l<2048, i<32
__global__ __launch_bounds__(256) void rope_tab_k(const int* __restrict__ pos,
                                                  float2* __restrict__ tab) {
  int gid = blockIdx.x * 256 + threadIdx.x;
  int l = gid >> 5, i = gid & 31;
  float p = (float)pos[l];
  float inv = expf(-((float)(2 * i) / 64.0f) * logf(10000.0f));
  float th = p * inv;
  tab[gid] = make_float2(cosf(th), sinf(th));
}

// ---------------- fused QKV GEMM: C = x[4096,1024] * [Wq|Wk|Wv] (N=3072) ----------------
// Counted-vmcnt pipeline (T4): 3-buffer LDS, stage(kt+2) post-barrier, vmcnt(4) not 0.

__global__ __launch_bounds__(256) void qkv_gemm_k(
    const u16* __restrict__ A, const u16* __restrict__ Bt,
    u16* __restrict__ Qo, u16* __restrict__ Ko, u16* __restrict__ Vo,
    const float2* __restrict__ rope)
{
  const int K = 1024;
  __shared__ alignas(16) u16 As[3][128][32];
  __shared__ alignas(16) u16 Bs[3][128][32];
  int tid = threadIdx.x;
  int tn = blockIdx.x, tm = blockIdx.y;
  int m0 = tm * 128, n0 = tn * 128;
  int lrow = tid >> 2, lk = (tid & 3) * 8;
  const u16* gA = A + (size_t)(m0 + lrow) * K + lk;
  const u16* gB = Bt + (size_t)(n0 + lrow) * K + lk;
  int wid = tid >> 6, lane = tid & 63, ln = lane & 15, kg = lane >> 4;
  int wm = (wid >> 1) * 64, wn = (wid & 1) * 64;
  f32x4 acc[4][4] = {};

  auto stage = [&](int kt, int buf) {
    const u16* ga = gA + kt * 32;
    gl16(ga, &As[buf][lrow][lk]);
    gl16(ga + 64 * K, &As[buf][lrow + 64][lk]);
    const u16* gb = gB + kt * 32;
    gl16(gb, &Bs[buf][lrow][lk]);
    gl16(gb + 64 * K, &Bs[buf][lrow + 64][lk]);
  };

  stage(0, 0);
  stage(1, 1);
  int cur = 0, nx2 = 2;
  for (int kt = 0; kt < 32; ++kt) {
    if (kt + 1 < 32) { asm volatile("s_waitcnt vmcnt(4)" ::: "memory"); }
    else             { asm volatile("s_waitcnt vmcnt(0)" ::: "memory"); }
    __builtin_amdgcn_s_barrier();
    __builtin_amdgcn_sched_barrier(0);
    if (kt + 2 < 32) stage(kt + 2, nx2);
    short8 af[4], bfr[4];
#pragma unroll
    for (int i = 0; i < 4; ++i) af[i] = *(const short8*)&As[cur][wm + i * 16 + ln][kg * 8];
#pragma unroll
    for (int i = 0; i < 4; ++i) bfr[i] = *(const short8*)&Bs[cur][wn + i * 16 + ln][kg * 8];
#pragma unroll
    for (int mi = 0; mi < 4; ++mi)
#pragma unroll
      for (int ni = 0; ni < 4; ++ni)
        acc[mi][ni] = __builtin_amdgcn_mfma_f32_16x16x32_bf16(af[mi], bfr[ni], acc[mi][ni], 0, 0, 0);
    cur = (cur == 2) ? 0 : cur + 1;
    nx2 = (nx2 == 2) ? 0 : nx2 + 1;
  }

  int sec = n0 >> 10;                 // 0=Q 1=K 2=V
  int col0 = (n0 & 1023) + wn;        // head-aligned 64-col wave
  int h = col0 >> 6;
  if (sec < 2) {
    u16* Out = (sec == 0) ? Qo : Ko;
    float sc = (sec == 0) ? 0.125f : 1.0f;
#pragma unroll
    for (int mi = 0; mi < 4; ++mi) {
#pragma unroll
      for (int j = 0; j < 4; ++j) {
        int mm = m0 + wm + mi * 16 + kg * 4 + j;
        int l = mm & (L_ - 1), b = mm >> 11;
        const float2* tl = rope + l * 32;
#pragma unroll
        for (int ni = 0; ni < 2; ++ni) {
          int dA = ni * 16 + ln;
          float xa = acc[mi][ni][j], xb = acc[mi][ni + 2][j];
          float2 fA = tl[dA >> 1];
          float2 fB = tl[16 + (dA >> 1)];
          float oA = (fA.x * xa - fA.y * xb) * sc;
          float oB = (fB.x * xb + fB.y * xa) * sc;
          size_t base = ((size_t)(b * H_ + h) * L_ + l) * D_;
          Out[base + dA] = f2bf(oA);
          Out[base + dA + 32] = f2bf(oB);
        }
      }
    }
  } else {
    // V -> chunk-tiled: Vo[bh][l>>5][d][l&31]
#pragma unroll
    for (int mi = 0; mi < 4; ++mi)
#pragma unroll
      for (int j = 0; j < 4; ++j) {
        int mm = m0 + wm + mi * 16 + kg * 4 + j;
        int l = mm & (L_ - 1), b = mm >> 11;
        size_t base = (size_t)(b * H_ + h) * (L_ * D_) + (size_t)(l >> 5) * 2048 + (l & 31);
#pragma unroll
        for (int ni = 0; ni < 4; ++ni) {
          int d = ni * 16 + ln;
          Vo[base + (size_t)d * 32] = f2bf(acc[mi][ni][j]);
        }
      }
  }
}

// ---------------- out-projection GEMM: 64x128 tiles, grid (8,64) = 512 blocks ----------------

__global__ __launch_bounds__(256) void oproj_k(
    const u16* __restrict__ A, const u16* __restrict__ Bt, float* __restrict__ Out)
{
  const int K = 1024;
  __shared__ alignas(16) u16 As[2][64][32];
  __shared__ alignas(16) u16 Bs[2][128][32];
  int tid = threadIdx.x;
  int tn = blockIdx.x, tm = blockIdx.y;
  int m0 = tm * 64, n0 = tn * 128;
  int lrow = tid >> 2, lk = (tid & 3) * 8;
  const u16* gA = A + (size_t)(m0 + lrow) * K + lk;
  const u16* gB = Bt + (size_t)(n0 + lrow) * K + lk;
  int wid = tid >> 6, lane = tid & 63, ln = lane & 15, kg = lane >> 4;
  int wm = (wid >> 1) * 32, wn = (wid & 1) * 64;
  f32x4 acc[2][4] = {};

  auto stage = [&](int buf, int kt) {
    gl16(gA + kt * 32, &As[buf][lrow][lk]);
    const u16* gb = gB + kt * 32;
    gl16(gb, &Bs[buf][lrow][lk]);
    gl16(gb + 64 * K, &Bs[buf][lrow + 64][lk]);
  };

  stage(0, 0);
  asm volatile("s_waitcnt vmcnt(0)" ::: "memory");
  __syncthreads();
  int cur = 0;
  for (int kt = 0; kt < 32; ++kt) {
    if (kt < 31) stage(cur ^ 1, kt + 1);
    short8 af[2], bfr[4];
#pragma unroll
    for (int i = 0; i < 2; ++i) af[i] = *(const short8*)&As[cur][wm + i * 16 + ln][kg * 8];
#pragma unroll
    for (int i = 0; i < 4; ++i) bfr[i] = *(const short8*)&Bs[cur][wn + i * 16 + ln][kg * 8];
#pragma unroll
    for (int mi = 0; mi < 2; ++mi)
#pragma unroll
      for (int ni = 0; ni < 4; ++ni)
        acc[mi][ni] = __builtin_amdgcn_mfma_f32_16x16x32_bf16(af[mi], bfr[ni], acc[mi][ni], 0, 0, 0);
    __syncthreads();
    cur ^= 1;
  }
#pragma unroll
  for (int mi = 0; mi < 2; ++mi)
#pragma unroll
    for (int j = 0; j < 4; ++j) {
      int mm = m0 + wm + mi * 16 + kg * 4 + j;
#pragma unroll
      for (int ni = 0; ni < 4; ++ni)
        Out[(size_t)mm * 1024 + n0 + wn + ni * 16 + ln] = acc[mi][ni][j];
    }
}

// ---------------- flash attention v11: uniform work via causal fold ----------------
// Block = (bh, i in [0,16)); processes q-tile i (64 rows) THEN q-tile 31-i.
// Trip count = (2i+2) + (64-2i) = 66 chunks for EVERY block -> balance is
// scheduler-independent (fixes the tail that capped v8-v10). 4 waves x 16 q per tile.
// Deep staging pipeline runs over the concatenated chunk sequence. Verified math.
__global__ __launch_bounds__(256) void attn_k(
    const u16* __restrict__ Q, const u16* __restrict__ K,
    const u16* __restrict__ V, u16* __restrict__ AO)
{
  __shared__ alignas(16) u16 Ks[6][2048];
  __shared__ alignas(16) u16 Vs[6][2048];
  int tid = threadIdx.x;
  int wid = tid >> 6, lane = tid & 63;
  int ln = lane & 15, kg = lane >> 4;
  int bh = blockIdx.y;
  int i = blockIdx.x;                  // 0..15
  int tA = i, tB = 31 - i;             // light tile, heavy tile
  int nA = 2 * i + 2;                  // chunks for tile A
  const int NCH = 66;                  // uniform total
  int q0A = tA * 64 + wid * 16;
  int q0B = tB * 64 + wid * 16;
  const u16* Qh = Q + (size_t)bh * L_ * D_;
  const u16* Kh = K + (size_t)bh * L_ * D_;
  const u16* Vt = V + (size_t)bh * L_ * D_;   // chunk-tiled [l/32][64][32]

  // staging sources (256 threads; K pre-swizzled source, linear LDS dest)
  int srow = tid >> 3, sblk = tid & 7;
  const u16* kb = Kh + (size_t)srow * 64 + ((sblk ^ (srow & 7)) << 3);
  const u16* vb = Vt + tid * 8;

  short8 qfA0 = *(const short8*)(Qh + (size_t)(q0A + ln) * D_ + kg * 8);
  short8 qfA1 = *(const short8*)(Qh + (size_t)(q0A + ln) * D_ + 32 + kg * 8);
  short8 qfB0 = *(const short8*)(Qh + (size_t)(q0B + ln) * D_ + kg * 8);
  short8 qfB1 = *(const short8*)(Qh + (size_t)(q0B + ln) * D_ + 32 + kg * 8);

  f32x4 oA[4] = {}, oB[4] = {};
  float mA = -1e30f, lsA = 0.f, mB = -1e30f, lsB = 0.f;
  int srcA = ln + (((2 * kg) & 3) << 4);
  int srcB = ln + (((2 * kg + 1) & 3) << 4);
  bool thi = (kg >= 2);

  int ownA = 2 * tA + (wid >> 1);      // wave's diagonal chunk (phase-local)
  int ownB = 2 * tB + (wid >> 1);

  auto stage = [&](int chunk, int buf) {
    gl16(kb + (size_t)chunk * 2048, &Ks[buf][tid * 8]);
    gl16(vb + (size_t)chunk * 2048, &Vs[buf][tid * 8]);
  };
  auto seq = [&](int c) { return (c < nA) ? c : c - nA; };

  // one chunk step for one 16-q tile (verified v8 math)
  auto step = [&](int cur, int cl, int own, int q0,
                  short8 qf0, short8 qf1,
                  float& m, float& lsum, f32x4 (&o)[4]) {
    int sw0 = (kg ^ (ln & 7)) * 8;
    int sw1 = ((4 + kg) ^ (ln & 7)) * 8;
    short8 k0a = *(const short8*)&Ks[cur][ln * 64 + sw0];
    short8 k0b = *(const short8*)&Ks[cur][ln * 64 + sw1];
    short8 k1a = *(const short8*)&Ks[cur][(ln + 16) * 64 + sw0];
    short8 k1b = *(const short8*)&Ks[cur][(ln + 16) * 64 + sw1];
    f32x4 s0 = {}, s1 = {};
    __builtin_amdgcn_s_setprio(1);
    s0 = __builtin_amdgcn_mfma_f32_16x16x32_bf16(k0a, qf0, s0, 0, 0, 0);
    s0 = __builtin_amdgcn_mfma_f32_16x16x32_bf16(k0b, qf1, s0, 0, 0, 0);
    s1 = __builtin_amdgcn_mfma_f32_16x16x32_bf16(k1a, qf0, s1, 0, 0, 0);
    s1 = __builtin_amdgcn_mfma_f32_16x16x32_bf16(k1b, qf1, s1, 0, 0, 0);
    __builtin_amdgcn_s_setprio(0);
    short8 vf0 = *(const short8*)&Vs[cur][ln * 32 + kg * 8];
    short8 vf1 = *(const short8*)&Vs[cur][(16 + ln) * 32 + kg * 8];
    short8 vf2 = *(const short8*)&Vs[cur][(32 + ln) * 32 + kg * 8];
    short8 vf3 = *(const short8*)&Vs[cur][(48 + ln) * 32 + kg * 8];
    if (cl == own) {                   // diagonal chunk: mask kv > q
      int kvb = cl * 32 + kg * 4;
      int q = q0 + ln;
#pragma unroll
      for (int r = 0; r < 4; ++r) {
        if (kvb + r > q) s0[r] = -1e30f;
        if (kvb + 16 + r > q) s1[r] = -1e30f;
      }
    }
    float lc = fmaxf(fmaxf(fmaxf(s0[0], s0[1]), fmaxf(s0[2], s0[3])),
                     fmaxf(fmaxf(s1[0], s1[1]), fmaxf(s1[2], s1[3])));
    if (!__all(lc <= m + 8.f)) {
      float cmax = fmaxf(lc, __shfl_xor(lc, 16));
      cmax = fmaxf(cmax, __shfl_xor(cmax, 32));
      float mnew = fmaxf(m, cmax);
      float al = __expf(m - mnew);
      m = mnew;
      lsum *= al;
#pragma unroll
      for (int dt = 0; dt < 4; ++dt) o[dt] *= al;
    }
    float p0[4], p1[4];
    float ps = 0.f;
#pragma unroll
    for (int r = 0; r < 4; ++r) {
      p0[r] = __expf(s0[r] - m);
      p1[r] = __expf(s1[r] - m);
      ps += p0[r] + p1[r];
    }
    lsum += ps;                        // lane-partial; reduced at end
    u32 wA0, wB0, wA1, wB1;
    asm("v_cvt_pk_bf16_f32 %0, %1, %2" : "=v"(wA0) : "v"(p0[0]), "v"(p0[1]));
    asm("v_cvt_pk_bf16_f32 %0, %1, %2" : "=v"(wB0) : "v"(p0[2]), "v"(p0[3]));
    asm("v_cvt_pk_bf16_f32 %0, %1, %2" : "=v"(wA1) : "v"(p1[0]), "v"(p1[1]));
    asm("v_cvt_pk_bf16_f32 %0, %1, %2" : "=v"(wB1) : "v"(p1[2]), "v"(p1[3]));
    u32 a0 = __shfl((int)wA0, srcA), a1 = __shfl((int)wA1, srcA);
    u32 b0 = __shfl((int)wB0, srcA), b1 = __shfl((int)wB1, srcA);
    u32 c0 = __shfl((int)wA0, srcB), c1 = __shfl((int)wA1, srcB);
    u32 e0 = __shfl((int)wB0, srcB), e1 = __shfl((int)wB1, srcB);
    union { u32 u[4]; short8 s8; } pu;
    pu.u[0] = thi ? a1 : a0;           // kv rows 8kg+0,1
    pu.u[1] = thi ? b1 : b0;           // kv rows 8kg+2,3
    pu.u[2] = thi ? c1 : c0;           // kv rows 8kg+4,5
    pu.u[3] = thi ? e1 : e0;           // kv rows 8kg+6,7
    __builtin_amdgcn_s_setprio(1);
    o[0] = __builtin_amdgcn_mfma_f32_16x16x32_bf16(vf0, pu.s8, o[0], 0, 0, 0);
    o[1] = __builtin_amdgcn_mfma_f32_16x16x32_bf16(vf1, pu.s8, o[1], 0, 0, 0);
    o[2] = __builtin_amdgcn_mfma_f32_16x16x32_bf16(vf2, pu.s8, o[2], 0, 0, 0);
    o[3] = __builtin_amdgcn_mfma_f32_16x16x32_bf16(vf3, pu.s8, o[3], 0, 0, 0);
    __builtin_amdgcn_s_setprio(0);
  };

  // prologue: 4 chunks in flight (NCH = 66 >= 4)
  stage(seq(0), 0); stage(seq(1), 1); stage(seq(2), 2); stage(seq(3), 3);
  int cur = 0, nxt = 4;

  for (int c = 0; c < NCH; ++c) {
    if (c + 3 < NCH)      { asm volatile("s_waitcnt vmcnt(6)" ::: "memory"); }
    else if (c + 2 < NCH) { asm volatile("s_waitcnt vmcnt(4)" ::: "memory"); }
    else if (c + 1 < NCH) { asm volatile("s_waitcnt vmcnt(2)" ::: "memory"); }
    else                  { asm volatile("s_waitcnt vmcnt(0)" ::: "memory"); }
    __builtin_amdgcn_s_barrier();
    __builtin_amdgcn_sched_barrier(0);
    if (c + 4 < NCH) stage(seq(c + 4), nxt);

    if (c < nA) {
      if (c <= ownA) step(cur, c, ownA, q0A, qfA0, qfA1, mA, lsA, oA);
    } else {
      int cl = c - nA;
      if (cl <= ownB) step(cur, cl, ownB, q0B, qfB0, qfB1, mB, lsB, oB);
    }
    cur = (cur == 5) ? 0 : cur + 1;
    nxt = (nxt == 5) ? 0 : nxt + 1;
  }

  // ---- final l reduction + store, both tiles ----
  int b = bh >> 4, h = bh & 15;
  lsA += __shfl_xor(lsA, 16);
  lsA += __shfl_xor(lsA, 32);
  lsB += __shfl_xor(lsB, 16);
  lsB += __shfl_xor(lsB, 32);
  float invA = 1.0f / lsA, invB = 1.0f / lsB;
  u16* rowA = AO + ((size_t)(b * L_ + q0A + ln) * H_ + h) * D_;
  u16* rowB = AO + ((size_t)(b * L_ + q0B + ln) * H_ + h) * D_;
#pragma unroll
  for (int dt = 0; dt < 4; ++dt) {
    union { u16 pk[4]; uint2 v; } uA, uB;
#pragma unroll
    for (int r = 0; r < 4; ++r) {
      uA.pk[r] = f2bf(oA[dt][r] * invA);
      uB.pk[r] = f2bf(oB[dt][r] * invB);
    }
    *(uint2*)(rowA + dt * 16 + kg * 4) = uA.v;
    *(uint2*)(rowB + dt * 16 + kg * 4) = uB.v;
  }
}

// ---------------- launch ----------------

extern "C" void kernel_launch(void* const* d_in, const int* in_sizes, int n_in,
                              void* d_out, int out_size, void* d_ws, size_t ws_size,
                              hipStream_t stream) {
  (void)in_sizes; (void)n_in; (void)out_size; (void)ws_size;
  const float* x   = (const float*)d_in[0];
  const int*   pos = (const int*)d_in[1];
  // d_in[2] = additive causal mask (we apply causal masking directly)
  const float* Wq  = (const float*)d_in[3];
  const float* Wk  = (const float*)d_in[4];
  const float* Wv  = (const float*)d_in[5];
  const float* Wo  = (const float*)d_in[6];

  char* ws = (char*)d_ws;
  u16* xbf = (u16*)ws;                        // 8 MB
  u16* Wt3 = (u16*)(ws + (size_t)( 8 << 20)); // 6 MB ([Wq|Wk|Wv]^T stacked)
  u16* Wto = (u16*)(ws + (size_t)(14 << 20)); // 2 MB
  u16* Qb  = (u16*)(ws + (size_t)(16 << 20)); // 8 MB each
  u16* Kb  = (u16*)(ws + (size_t)(24 << 20));
  u16* Vt  = (u16*)(ws + (size_t)(32 << 20)); // chunk-tiled
  u16* AO  = (u16*)(ws + (size_t)(40 << 20));
  float2* tab = (float2*)(ws + (size_t)(48 << 20)); // 512 KB

  cvt_bf16_k<<<2048, 256, 0, stream>>>(x, xbf, 4096 * 1024);
  transpose4_bf_k<<<dim3(1024, 4), 256, 0, stream>>>(
      Wq, Wk, Wv, Wo, Wt3, Wt3 + (size_t)1048576, Wt3 + (size_t)2097152, Wto);
  rope_tab_k<<<256, 256, 0, stream>>>(pos, tab);
  qkv_gemm_k<<<dim3(24, 32), 256, 0, stream>>>(xbf, Wt3, Qb, Kb, Vt, tab);
  attn_k<<<dim3(16, 32), 256, 0, stream>>>(Qb, Kb, Vt, AO);
  oproj_k<<<dim3(8, 64), 256, 0, stream>>>(AO, Wto, (float*)d_out);
}